// Round 1
// baseline (8694.247 us; speedup 1.0000x reference)
//
#include <hip/hip_runtime.h>

#define NN 100000   // nodes
#define NE 1600000  // edges
#define DD 128      // feature dim
#define NL 3        // layers
#define NG 64       // graphs
#define EPSBN 1e-5f

// ---- fp32 atomic add (HW global_atomic_add_f32, no CAS loop) ----
__device__ inline void atomAddF(float* p, float v) {
#if defined(__AMDGCN__)
    unsafeAtomicAdd(p, v);
#else
    atomicAdd(p, v);
#endif
}

// ---------------- degree / norm setup ----------------
__global__ __launch_bounds__(256) void k_deg_init(float* __restrict__ deg) {
    int i = blockIdx.x * 256 + threadIdx.x;
    if (i < NN) deg[i] = 1.0f;  // self-loop weight
}

__global__ __launch_bounds__(256) void k_deg_acc(const int* __restrict__ ei,
                                                 const float* __restrict__ ew,
                                                 float* __restrict__ deg) {
    int e = blockIdx.x * 256 + threadIdx.x;
    if (e < NE) atomAddF(&deg[ei[NE + e]], ew[e]);  // dst = ei[1][e]
}

__global__ __launch_bounds__(256) void k_dinv(const float* __restrict__ deg,
                                              float* __restrict__ dinv) {
    int i = blockIdx.x * 256 + threadIdx.x;
    if (i < NN) {
        float d = deg[i];
        dinv[i] = d > 0.f ? rsqrtf(fmaxf(d, 1e-12f)) : 0.f;
    }
}

__global__ __launch_bounds__(256) void k_norm(const int* __restrict__ ei,
                                              const float* __restrict__ ew,
                                              const float* __restrict__ dinv,
                                              float* __restrict__ nrm) {
    int e = blockIdx.x * 256 + threadIdx.x;
    if (e < NE) nrm[e] = dinv[ei[e]] * ew[e] * dinv[ei[NE + e]];
}

// ---------------- GEMM: H = X @ W ; A = dinv^2 * H (self-loop init) -------
// block: 256 threads, 64 rows x 128 cols per block, 4x8 per-thread microtile
__global__ __launch_bounds__(256) void k_gemm(const float* __restrict__ X,
                                              const float* __restrict__ Wl,
                                              const float* __restrict__ dinv,
                                              float* __restrict__ H,
                                              float* __restrict__ A) {
    __shared__ float ws[DD][DD];    // 64 KB, W row-major [k][c]
    __shared__ float xs[64][132];   // padded stride (132*4=528B, 16B-aligned rows)
    const int tid = threadIdx.x;
    const int row0 = blockIdx.x * 64;

    // load W (16384 floats, 16 float4 per thread)
    for (int i = tid * 4; i < DD * DD; i += 1024)
        *(float4*)&ws[0][i] = *(const float4*)&Wl[i];
    // load X tile (8192 floats, 8 float4 per thread)
    for (int i = tid * 4; i < 64 * DD; i += 1024) {
        int r = i >> 7, c = i & 127;
        int gr = row0 + r;
        float4 v = (gr < NN) ? *(const float4*)&X[(size_t)gr * DD + c]
                             : make_float4(0.f, 0.f, 0.f, 0.f);
        *(float4*)&xs[r][c] = v;
    }
    __syncthreads();

    const int ty = tid >> 4, tx = tid & 15;
    const int r0 = ty * 4, c0 = tx * 8;
    float acc[4][8];
#pragma unroll
    for (int i = 0; i < 4; ++i)
#pragma unroll
        for (int j = 0; j < 8; ++j) acc[i][j] = 0.f;

    for (int k = 0; k < DD; k += 4) {
        float4 a0 = *(float4*)&xs[r0 + 0][k];
        float4 a1 = *(float4*)&xs[r0 + 1][k];
        float4 a2 = *(float4*)&xs[r0 + 2][k];
        float4 a3 = *(float4*)&xs[r0 + 3][k];
#pragma unroll
        for (int kk = 0; kk < 4; ++kk) {
            float4 b0 = *(float4*)&ws[k + kk][c0];
            float4 b1 = *(float4*)&ws[k + kk][c0 + 4];
            float bv[8] = {b0.x, b0.y, b0.z, b0.w, b1.x, b1.y, b1.z, b1.w};
            float av[4] = {((const float*)&a0)[kk], ((const float*)&a1)[kk],
                           ((const float*)&a2)[kk], ((const float*)&a3)[kk]};
#pragma unroll
            for (int i = 0; i < 4; ++i)
#pragma unroll
                for (int j = 0; j < 8; ++j)
                    acc[i][j] = fmaf(av[i], bv[j], acc[i][j]);
        }
    }

#pragma unroll
    for (int i = 0; i < 4; ++i) {
        int gr = row0 + r0 + i;
        if (gr < NN) {
            float dv = dinv[gr];
            float sl = dv * dv;  // self-loop norm
            size_t base = (size_t)gr * DD + c0;
            float4 h0 = make_float4(acc[i][0], acc[i][1], acc[i][2], acc[i][3]);
            float4 h1 = make_float4(acc[i][4], acc[i][5], acc[i][6], acc[i][7]);
            *(float4*)&H[base] = h0;
            *(float4*)&H[base + 4] = h1;
            float4 s0 = make_float4(sl * h0.x, sl * h0.y, sl * h0.z, sl * h0.w);
            float4 s1 = make_float4(sl * h1.x, sl * h1.y, sl * h1.z, sl * h1.w);
            *(float4*)&A[base] = s0;
            *(float4*)&A[base + 4] = s1;
        }
    }
}

// ---------------- edge aggregation: A[dst] += norm_e * H[src] -------------
// 32 lanes per edge, 4 cols each (float4 gather + 4 scalar atomics)
__global__ __launch_bounds__(256) void k_agg(const int* __restrict__ ei,
                                             const float* __restrict__ nrm,
                                             const float* __restrict__ H,
                                             float* __restrict__ A) {
    int e = blockIdx.x * 8 + (threadIdx.x >> 5);
    if (e >= NE) return;
    int lane = threadIdx.x & 31;
    int s = ei[e], d = ei[NE + e];
    float w = nrm[e];
    const float4 h = *(const float4*)&H[(size_t)s * DD + lane * 4];
    float* base = &A[(size_t)d * DD + lane * 4];
    atomAddF(base + 0, w * h.x);
    atomAddF(base + 1, w * h.y);
    atomAddF(base + 2, w * h.z);
    atomAddF(base + 3, w * h.w);
}

// ---------------- batchnorm ----------------
__global__ __launch_bounds__(256) void k_zero_stats(float* __restrict__ stats) {
    stats[threadIdx.x] = 0.f;  // 256 entries: sum[128], sumsq[128]
}

__global__ __launch_bounds__(256) void k_bn_stat(const float* __restrict__ A,
                                                 float* __restrict__ stats) {
    const int tid = threadIdx.x;
    const int col = tid & 127, half = tid >> 7;
    int v0 = blockIdx.x * 196;
    int v1 = v0 + 196;
    if (v1 > NN) v1 = NN;
    float s = 0.f, ss = 0.f;
    for (int v = v0 + half; v < v1; v += 2) {
        float a = A[(size_t)v * DD + col];
        s += a;
        ss = fmaf(a, a, ss);
    }
    __shared__ float buf[256];
    buf[tid] = s;
    __syncthreads();
    float s2 = 0.f;
    if (tid < 128) s2 = buf[tid] + buf[tid + 128];
    __syncthreads();
    buf[tid] = ss;
    __syncthreads();
    if (tid < 128) {
        float ss2 = buf[tid] + buf[tid + 128];
        atomAddF(&stats[tid], s2);
        atomAddF(&stats[128 + tid], ss2);
    }
}

__global__ void k_bn_final(const float* __restrict__ stats,
                           const float* __restrict__ gamma,
                           const float* __restrict__ beta,
                           float* __restrict__ sc, float* __restrict__ sh) {
    int c = threadIdx.x;
    if (c < DD) {
        float mu = stats[c] * (1.0f / NN);
        float var = stats[DD + c] * (1.0f / NN) - mu * mu;
        float inv = rsqrtf(var + EPSBN);
        float s = gamma[c] * inv;
        sc[c] = s;
        sh[c] = beta[c] - mu * s;  // conv bias b cancels in BN exactly
    }
}

__global__ __launch_bounds__(256) void k_bn_relu(float* __restrict__ A,
                                                 const float* __restrict__ sc,
                                                 const float* __restrict__ sh) {
    size_t idx = (size_t)blockIdx.x * 256 + threadIdx.x;
    size_t v = idx >> 5;
    int c = (int)(idx & 31) * 4;
    if (v < NN) {
        float4 a = *(float4*)&A[v * DD + c];
        float4 s4 = *(const float4*)&sc[c];
        float4 h4 = *(const float4*)&sh[c];
        a.x = fmaxf(fmaf(a.x, s4.x, h4.x), 0.f);
        a.y = fmaxf(fmaf(a.y, s4.y, h4.y), 0.f);
        a.z = fmaxf(fmaf(a.z, s4.z, h4.z), 0.f);
        a.w = fmaxf(fmaf(a.w, s4.w, h4.w), 0.f);
        *(float4*)&A[v * DD + c] = a;
    }
}

// ---------------- pooling ----------------
__global__ __launch_bounds__(256) void k_zero_out(float* __restrict__ out) {
    int i = blockIdx.x * 256 + threadIdx.x;
    if (i < NG * DD) out[i] = 0.f;
}

// batch is sorted: run-length accumulate per thread, flush on graph change
__global__ __launch_bounds__(256) void k_pool(const float* __restrict__ X,
                                              const int* __restrict__ batch,
                                              float* __restrict__ out) {
    const int tid = threadIdx.x;
    const int col = tid & 127, half = tid >> 7;
    int v0 = blockIdx.x * 196;
    int v1 = v0 + 196;
    if (v1 > NN) v1 = NN;
    float acc = 0.f;
    int g = -1;
    for (int v = v0 + half; v < v1; v += 2) {
        int bg = batch[v];
        if (bg != g) {
            if (g >= 0) atomAddF(&out[(size_t)g * DD + col], acc);
            g = bg;
            acc = 0.f;
        }
        acc += X[(size_t)v * DD + col];
    }
    if (g >= 0) atomAddF(&out[(size_t)g * DD + col], acc);
}

extern "C" void kernel_launch(void* const* d_in, const int* in_sizes, int n_in,
                              void* d_out, int out_size, void* d_ws, size_t ws_size,
                              hipStream_t stream) {
    const float* x     = (const float*)d_in[0];
    const int*   ei    = (const int*)d_in[1];
    const float* ew    = (const float*)d_in[2];
    const int*   batch = (const int*)d_in[3];
    const float* W     = (const float*)d_in[4];
    // d_in[5] = b  — cancels exactly in training-mode BatchNorm, unused
    const float* gamma = (const float*)d_in[6];
    const float* beta  = (const float*)d_in[7];
    float* out = (float*)d_out;

    float* ws    = (float*)d_ws;
    float* deg   = ws;               // N
    float* dinv  = deg + NN;         // N
    float* nrm   = dinv + NN;        // E
    float* stats = nrm + NE;         // 256
    float* sc    = stats + 256;      // 128
    float* sh    = sc + DD;          // 128
    float* H     = sh + DD;          // N*D
    float* A     = H + (size_t)NN * DD;  // N*D
    // total: (2*NN + NE + 512 + 2*NN*DD)*4 B ~= 105 MiB

    k_deg_init<<<(NN + 255) / 256, 256, 0, stream>>>(deg);
    k_deg_acc<<<(NE + 255) / 256, 256, 0, stream>>>(ei, ew, deg);
    k_dinv<<<(NN + 255) / 256, 256, 0, stream>>>(deg, dinv);
    k_norm<<<(NE + 255) / 256, 256, 0, stream>>>(ei, ew, dinv, nrm);

    const float* xcur = x;
    for (int l = 0; l < NL; ++l) {
        k_gemm<<<(NN + 63) / 64, 256, 0, stream>>>(xcur, W + (size_t)l * DD * DD,
                                                   dinv, H, A);
        k_agg<<<(NE + 7) / 8, 256, 0, stream>>>(ei, nrm, H, A);
        k_zero_stats<<<1, 256, 0, stream>>>(stats);
        k_bn_stat<<<512, 256, 0, stream>>>(A, stats);
        k_bn_final<<<1, 128, 0, stream>>>(stats, gamma + (size_t)l * DD,
                                          beta + (size_t)l * DD, sc, sh);
        k_bn_relu<<<12500, 256, 0, stream>>>(A, sc, sh);
        xcur = A;
    }

    k_zero_out<<<32, 256, 0, stream>>>(out);
    k_pool<<<512, 256, 0, stream>>>(A, batch, out);
}

// Round 3
// 1139.634 us; speedup vs baseline: 7.6290x; 7.6290x over previous
//
#include <hip/hip_runtime.h>

#define NN 100000   // nodes
#define NE 1600000  // edges
#define DD 128      // feature dim
#define NL 3        // layers
#define NG 64       // graphs
#define EPSBN 1e-5f
#define NBLK ((NN + 255) / 256)   // 391 scan blocks

// ---- fp32 atomic add (HW global_atomic_add_f32, no CAS loop) ----
__device__ inline void atomAddF(float* p, float v) {
#if defined(__AMDGCN__)
    unsafeAtomicAdd(p, v);
#else
    atomicAdd(p, v);
#endif
}

// ---------------- degree / norm setup ----------------
__global__ __launch_bounds__(256) void k_deg_init(float* __restrict__ deg) {
    int i = blockIdx.x * 256 + threadIdx.x;
    if (i < NN) deg[i] = 1.0f;  // self-loop weight
}

__global__ __launch_bounds__(256) void k_deg_acc(const int* __restrict__ ei,
                                                 const float* __restrict__ ew,
                                                 float* __restrict__ deg) {
    int e = blockIdx.x * 256 + threadIdx.x;
    if (e < NE) atomAddF(&deg[ei[NE + e]], ew[e]);  // dst = ei[1][e]
}

__global__ __launch_bounds__(256) void k_dinv(const float* __restrict__ deg,
                                              float* __restrict__ dinv) {
    int i = blockIdx.x * 256 + threadIdx.x;
    if (i < NN) {
        float d = deg[i];
        dinv[i] = d > 0.f ? rsqrtf(fmaxf(d, 1e-12f)) : 0.f;
    }
}

__global__ __launch_bounds__(256) void k_norm(const int* __restrict__ ei,
                                              const float* __restrict__ ew,
                                              const float* __restrict__ dinv,
                                              float* __restrict__ nrm) {
    int e = blockIdx.x * 256 + threadIdx.x;
    if (e < NE) nrm[e] = dinv[ei[e]] * ew[e] * dinv[ei[NE + e]];
}

// ---------------- CSR-by-dst build ----------------
__global__ __launch_bounds__(256) void k_zero_ints(int* __restrict__ p, int n) {
    int i = blockIdx.x * 256 + threadIdx.x;
    if (i < n) p[i] = 0;
}

__global__ __launch_bounds__(256) void k_count(const int* __restrict__ ei,
                                               int* __restrict__ cnt) {
    int e = blockIdx.x * 256 + threadIdx.x;
    if (e < NE) atomicAdd(&cnt[ei[NE + e]], 1);
}

__global__ __launch_bounds__(256) void k_scan_block(const int* __restrict__ cnt,
                                                    int* __restrict__ bsum) {
    __shared__ int s[256];
    int i = blockIdx.x * 256 + threadIdx.x;
    s[threadIdx.x] = (i < NN) ? cnt[i] : 0;
    __syncthreads();
    for (int off = 128; off > 0; off >>= 1) {
        if (threadIdx.x < off) s[threadIdx.x] += s[threadIdx.x + off];
        __syncthreads();
    }
    if (threadIdx.x == 0) bsum[blockIdx.x] = s[0];
}

__global__ __launch_bounds__(512) void k_scan_top(int* __restrict__ bsum) {
    __shared__ int s[512];
    int t = threadIdx.x;
    int v = (t < NBLK) ? bsum[t] : 0;
    s[t] = v;
    __syncthreads();
    for (int off = 1; off < 512; off <<= 1) {
        int add = (t >= off) ? s[t - off] : 0;
        __syncthreads();
        s[t] += add;
        __syncthreads();
    }
    if (t < NBLK) bsum[t] = s[t] - v;  // exclusive
}

__global__ __launch_bounds__(256) void k_scan_out(const int* __restrict__ cnt,
                                                  const int* __restrict__ bsum,
                                                  int* __restrict__ row_off) {
    __shared__ int s[256];
    int t = threadIdx.x;
    int i = blockIdx.x * 256 + t;
    int v = (i < NN) ? cnt[i] : 0;
    s[t] = v;
    __syncthreads();
    for (int off = 1; off < 256; off <<= 1) {
        int add = (t >= off) ? s[t - off] : 0;
        __syncthreads();
        s[t] += add;
        __syncthreads();
    }
    if (i < NN) row_off[i] = bsum[blockIdx.x] + s[t] - v;  // exclusive
    if (i == NN - 1) row_off[NN] = NE;
}

__global__ __launch_bounds__(256) void k_fill(const int* __restrict__ ei,
                                              const float* __restrict__ nrm,
                                              const int* __restrict__ row_off,
                                              int* __restrict__ cursor,
                                              int2* __restrict__ csr) {
    int e = blockIdx.x * 256 + threadIdx.x;
    if (e < NE) {
        int d = ei[NE + e];
        int pos = row_off[d] + atomicAdd(&cursor[d], 1);
        int2 v;
        v.x = ei[e];                     // src
        v.y = __float_as_int(nrm[e]);    // edge norm
        csr[pos] = v;
    }
}

// ---------------- GEMM: H = X @ W ----------------
// block: 256 threads, 64 rows x 128 cols per block, 4x8 per-thread microtile
__global__ __launch_bounds__(256) void k_gemm(const float* __restrict__ X,
                                              const float* __restrict__ Wl,
                                              float* __restrict__ H) {
    __shared__ float ws[DD][DD];    // 64 KB, W row-major [k][c]
    __shared__ float xs[64][132];   // padded stride
    const int tid = threadIdx.x;
    const int row0 = blockIdx.x * 64;

    for (int i = tid * 4; i < DD * DD; i += 1024)
        *(float4*)&ws[0][i] = *(const float4*)&Wl[i];
    for (int i = tid * 4; i < 64 * DD; i += 1024) {
        int r = i >> 7, c = i & 127;
        int gr = row0 + r;
        float4 v = (gr < NN) ? *(const float4*)&X[(size_t)gr * DD + c]
                             : make_float4(0.f, 0.f, 0.f, 0.f);
        *(float4*)&xs[r][c] = v;
    }
    __syncthreads();

    const int ty = tid >> 4, tx = tid & 15;
    const int r0 = ty * 4, c0 = tx * 8;
    float acc[4][8];
#pragma unroll
    for (int i = 0; i < 4; ++i)
#pragma unroll
        for (int j = 0; j < 8; ++j) acc[i][j] = 0.f;

    for (int k = 0; k < DD; k += 4) {
        float4 a0 = *(float4*)&xs[r0 + 0][k];
        float4 a1 = *(float4*)&xs[r0 + 1][k];
        float4 a2 = *(float4*)&xs[r0 + 2][k];
        float4 a3 = *(float4*)&xs[r0 + 3][k];
#pragma unroll
        for (int kk = 0; kk < 4; ++kk) {
            float4 b0 = *(float4*)&ws[k + kk][c0];
            float4 b1 = *(float4*)&ws[k + kk][c0 + 4];
            float bv[8] = {b0.x, b0.y, b0.z, b0.w, b1.x, b1.y, b1.z, b1.w};
            float av[4] = {((const float*)&a0)[kk], ((const float*)&a1)[kk],
                           ((const float*)&a2)[kk], ((const float*)&a3)[kk]};
#pragma unroll
            for (int i = 0; i < 4; ++i)
#pragma unroll
                for (int j = 0; j < 8; ++j)
                    acc[i][j] = fmaf(av[i], bv[j], acc[i][j]);
        }
    }

#pragma unroll
    for (int i = 0; i < 4; ++i) {
        int gr = row0 + r0 + i;
        if (gr < NN) {
            size_t base = (size_t)gr * DD + c0;
            *(float4*)&H[base] = make_float4(acc[i][0], acc[i][1], acc[i][2], acc[i][3]);
            *(float4*)&H[base + 4] = make_float4(acc[i][4], acc[i][5], acc[i][6], acc[i][7]);
        }
    }
}

// ---------------- aggregation (gather-CSR): A[v] = dinv^2 H[v] + sum w*H[src]
// one 64-lane wave per node, 2 cols per lane, edge loop unrolled by 4
__global__ __launch_bounds__(256) void k_agg_csr(const int2* __restrict__ csr,
                                                 const int* __restrict__ row_off,
                                                 const float* __restrict__ dinv,
                                                 const float* __restrict__ H,
                                                 float* __restrict__ A) {
    int node = blockIdx.x * 4 + (threadIdx.x >> 6);
    if (node >= NN) return;
    int lane = threadIdx.x & 63;
    int beg = row_off[node], end = row_off[node + 1];
    float dv = dinv[node];
    size_t cbase = (size_t)node * DD + lane * 2;
    float2 hs = *(const float2*)&H[cbase];
    float ax = dv * dv * hs.x, ay = dv * dv * hs.y;

    int j = beg;
    for (; j + 4 <= end; j += 4) {
        int2 e0 = csr[j], e1 = csr[j + 1], e2 = csr[j + 2], e3 = csr[j + 3];
        float2 h0 = *(const float2*)&H[(size_t)e0.x * DD + lane * 2];
        float2 h1 = *(const float2*)&H[(size_t)e1.x * DD + lane * 2];
        float2 h2 = *(const float2*)&H[(size_t)e2.x * DD + lane * 2];
        float2 h3 = *(const float2*)&H[(size_t)e3.x * DD + lane * 2];
        float w0 = __int_as_float(e0.y), w1 = __int_as_float(e1.y);
        float w2 = __int_as_float(e2.y), w3 = __int_as_float(e3.y);
        ax = fmaf(w0, h0.x, ax); ay = fmaf(w0, h0.y, ay);
        ax = fmaf(w1, h1.x, ax); ay = fmaf(w1, h1.y, ay);
        ax = fmaf(w2, h2.x, ax); ay = fmaf(w2, h2.y, ay);
        ax = fmaf(w3, h3.x, ax); ay = fmaf(w3, h3.y, ay);
    }
    for (; j < end; ++j) {
        int2 e = csr[j];
        float w = __int_as_float(e.y);
        float2 h = *(const float2*)&H[(size_t)e.x * DD + lane * 2];
        ax = fmaf(w, h.x, ax); ay = fmaf(w, h.y, ay);
    }
    *(float2*)&A[cbase] = make_float2(ax, ay);
}

// ---------------- batchnorm ----------------
__global__ __launch_bounds__(256) void k_zero_stats(float* __restrict__ stats) {
    stats[threadIdx.x] = 0.f;  // sum[128], sumsq[128]
}

__global__ __launch_bounds__(256) void k_bn_stat(const float* __restrict__ A,
                                                 float* __restrict__ stats) {
    const int tid = threadIdx.x;
    const int col = tid & 127, half = tid >> 7;
    int v0 = blockIdx.x * 196;
    int v1 = v0 + 196;
    if (v1 > NN) v1 = NN;
    float s = 0.f, ss = 0.f;
    for (int v = v0 + half; v < v1; v += 2) {
        float a = A[(size_t)v * DD + col];
        s += a;
        ss = fmaf(a, a, ss);
    }
    __shared__ float buf[256];
    buf[tid] = s;
    __syncthreads();
    float s2 = 0.f;
    if (tid < 128) s2 = buf[tid] + buf[tid + 128];
    __syncthreads();
    buf[tid] = ss;
    __syncthreads();
    if (tid < 128) {
        float ss2 = buf[tid] + buf[tid + 128];
        atomAddF(&stats[tid], s2);
        atomAddF(&stats[128 + tid], ss2);
    }
}

__global__ void k_bn_final(const float* __restrict__ stats,
                           const float* __restrict__ gamma,
                           const float* __restrict__ beta,
                           float* __restrict__ sc, float* __restrict__ sh) {
    int c = threadIdx.x;
    if (c < DD) {
        float mu = stats[c] * (1.0f / NN);
        float var = stats[DD + c] * (1.0f / NN) - mu * mu;
        float inv = rsqrtf(var + EPSBN);
        float s = gamma[c] * inv;
        sc[c] = s;
        sh[c] = beta[c] - mu * s;  // conv bias b cancels in BN exactly
    }
}

__global__ __launch_bounds__(256) void k_bn_relu(float* __restrict__ A,
                                                 const float* __restrict__ sc,
                                                 const float* __restrict__ sh) {
    size_t idx = (size_t)blockIdx.x * 256 + threadIdx.x;
    size_t v = idx >> 5;
    int c = (int)(idx & 31) * 4;
    if (v < NN) {
        float4 a = *(float4*)&A[v * DD + c];
        float4 s4 = *(const float4*)&sc[c];
        float4 h4 = *(const float4*)&sh[c];
        a.x = fmaxf(fmaf(a.x, s4.x, h4.x), 0.f);
        a.y = fmaxf(fmaf(a.y, s4.y, h4.y), 0.f);
        a.z = fmaxf(fmaf(a.z, s4.z, h4.z), 0.f);
        a.w = fmaxf(fmaf(a.w, s4.w, h4.w), 0.f);
        *(float4*)&A[v * DD + c] = a;
    }
}

// ---------------- pooling ----------------
__global__ __launch_bounds__(256) void k_zero_out(float* __restrict__ out) {
    int i = blockIdx.x * 256 + threadIdx.x;
    if (i < NG * DD) out[i] = 0.f;
}

__global__ __launch_bounds__(256) void k_pool(const float* __restrict__ X,
                                              const int* __restrict__ batch,
                                              float* __restrict__ out) {
    const int tid = threadIdx.x;
    const int col = tid & 127, half = tid >> 7;
    int v0 = blockIdx.x * 196;
    int v1 = v0 + 196;
    if (v1 > NN) v1 = NN;
    float acc = 0.f;
    int g = -1;
    for (int v = v0 + half; v < v1; v += 2) {
        int bg = batch[v];
        if (bg != g) {
            if (g >= 0) atomAddF(&out[(size_t)g * DD + col], acc);
            g = bg;
            acc = 0.f;
        }
        acc += X[(size_t)v * DD + col];
    }
    if (g >= 0) atomAddF(&out[(size_t)g * DD + col], acc);
}

extern "C" void kernel_launch(void* const* d_in, const int* in_sizes, int n_in,
                              void* d_out, int out_size, void* d_ws, size_t ws_size,
                              hipStream_t stream) {
    const float* x     = (const float*)d_in[0];
    const int*   ei    = (const int*)d_in[1];
    const float* ew    = (const float*)d_in[2];
    const int*   batch = (const int*)d_in[3];
    const float* W     = (const float*)d_in[4];
    // d_in[5] = b — cancels exactly in training-mode BatchNorm, unused
    const float* gamma = (const float*)d_in[6];
    const float* beta  = (const float*)d_in[7];
    float* out = (float*)d_out;

    float* ws    = (float*)d_ws;
    float* deg   = ws;                   // N
    float* dinv  = deg + NN;             // N
    float* nrm   = dinv + NN;            // E
    float* stats = nrm + NE;             // 256
    float* sc    = stats + 256;          // 128
    float* sh    = sc + DD;              // 128
    float* H     = sh + DD;              // N*D
    float* A     = H + (size_t)NN * DD;  // N*D
    int*   cnt     = (int*)(A + (size_t)NN * DD);  // N  (cursor contiguous after)
    int*   cursor  = cnt + NN;           // N
    int*   row_off = cursor + NN;        // N+1
    int*   bsum    = row_off + NN + 1;   // 512
    int2*  csr     = (int2*)(bsum + 512);  // E * 8B
    // total ≈ 124 MiB

    k_deg_init<<<(NN + 255) / 256, 256, 0, stream>>>(deg);
    k_deg_acc<<<(NE + 255) / 256, 256, 0, stream>>>(ei, ew, deg);
    k_dinv<<<(NN + 255) / 256, 256, 0, stream>>>(deg, dinv);
    k_norm<<<(NE + 255) / 256, 256, 0, stream>>>(ei, ew, dinv, nrm);

    // CSR build (once; reused across layers)
    k_zero_ints<<<(2 * NN + 255) / 256, 256, 0, stream>>>(cnt, 2 * NN);
    k_count<<<(NE + 255) / 256, 256, 0, stream>>>(ei, cnt);
    k_scan_block<<<NBLK, 256, 0, stream>>>(cnt, bsum);
    k_scan_top<<<1, 512, 0, stream>>>(bsum);
    k_scan_out<<<NBLK, 256, 0, stream>>>(cnt, bsum, row_off);
    k_fill<<<(NE + 255) / 256, 256, 0, stream>>>(ei, nrm, row_off, cursor, csr);

    const float* xcur = x;
    for (int l = 0; l < NL; ++l) {
        k_gemm<<<(NN + 63) / 64, 256, 0, stream>>>(xcur, W + (size_t)l * DD * DD, H);
        k_agg_csr<<<(NN + 3) / 4, 256, 0, stream>>>(csr, row_off, dinv, H, A);
        k_zero_stats<<<1, 256, 0, stream>>>(stats);
        k_bn_stat<<<512, 256, 0, stream>>>(A, stats);
        k_bn_final<<<1, 128, 0, stream>>>(stats, gamma + (size_t)l * DD,
                                          beta + (size_t)l * DD, sc, sh);
        k_bn_relu<<<12500, 256, 0, stream>>>(A, sc, sh);
        xcur = A;
    }

    k_zero_out<<<32, 256, 0, stream>>>(out);
    k_pool<<<512, 256, 0, stream>>>(A, batch, out);
}

// Round 5
// 1012.925 us; speedup vs baseline: 8.5833x; 1.1251x over previous
//
#include <hip/hip_runtime.h>

#define NN 100000   // nodes
#define NE 1600000  // edges
#define DD 128      // feature dim
#define NL 3        // layers
#define NG 64       // graphs
#define EPSBN 1e-5f
#define NBLK ((NN + 255) / 256)   // 391 scan blocks

// ---- fp32 atomic add (HW global_atomic_add_f32, no CAS loop) ----
__device__ inline void atomAddF(float* p, float v) {
#if defined(__AMDGCN__)
    unsafeAtomicAdd(p, v);
#else
    atomicAdd(p, v);
#endif
}

// ---------------- degree / norm setup ----------------
__global__ __launch_bounds__(256) void k_deg_init(float* __restrict__ deg) {
    int i = blockIdx.x * 256 + threadIdx.x;
    if (i < NN) deg[i] = 1.0f;  // self-loop weight
}

__global__ __launch_bounds__(256) void k_deg_acc(const int* __restrict__ ei,
                                                 const float* __restrict__ ew,
                                                 float* __restrict__ deg) {
    int e = blockIdx.x * 256 + threadIdx.x;
    if (e < NE) atomAddF(&deg[ei[NE + e]], ew[e]);  // dst = ei[1][e]
}

__global__ __launch_bounds__(256) void k_dinv(const float* __restrict__ deg,
                                              float* __restrict__ dinv) {
    int i = blockIdx.x * 256 + threadIdx.x;
    if (i < NN) {
        float d = deg[i];
        dinv[i] = d > 0.f ? rsqrtf(fmaxf(d, 1e-12f)) : 0.f;
    }
}

__global__ __launch_bounds__(256) void k_norm(const int* __restrict__ ei,
                                              const float* __restrict__ ew,
                                              const float* __restrict__ dinv,
                                              float* __restrict__ nrm) {
    int e = blockIdx.x * 256 + threadIdx.x;
    if (e < NE) nrm[e] = dinv[ei[e]] * ew[e] * dinv[ei[NE + e]];
}

// ---------------- CSR-by-dst build ----------------
__global__ __launch_bounds__(256) void k_zero_ints(int* __restrict__ p, int n) {
    int i = blockIdx.x * 256 + threadIdx.x;
    if (i < n) p[i] = 0;
}

__global__ __launch_bounds__(256) void k_count(const int* __restrict__ ei,
                                               int* __restrict__ cnt) {
    int e = blockIdx.x * 256 + threadIdx.x;
    if (e < NE) atomicAdd(&cnt[ei[NE + e]], 1);
}

__global__ __launch_bounds__(256) void k_scan_block(const int* __restrict__ cnt,
                                                    int* __restrict__ bsum) {
    __shared__ int s[256];
    int i = blockIdx.x * 256 + threadIdx.x;
    s[threadIdx.x] = (i < NN) ? cnt[i] : 0;
    __syncthreads();
    for (int off = 128; off > 0; off >>= 1) {
        if (threadIdx.x < off) s[threadIdx.x] += s[threadIdx.x + off];
        __syncthreads();
    }
    if (threadIdx.x == 0) bsum[blockIdx.x] = s[0];
}

__global__ __launch_bounds__(512) void k_scan_top(int* __restrict__ bsum) {
    __shared__ int s[512];
    int t = threadIdx.x;
    int v = (t < NBLK) ? bsum[t] : 0;
    s[t] = v;
    __syncthreads();
    for (int off = 1; off < 512; off <<= 1) {
        int add = (t >= off) ? s[t - off] : 0;
        __syncthreads();
        s[t] += add;
        __syncthreads();
    }
    if (t < NBLK) bsum[t] = s[t] - v;  // exclusive
}

__global__ __launch_bounds__(256) void k_scan_out(const int* __restrict__ cnt,
                                                  const int* __restrict__ bsum,
                                                  int* __restrict__ row_off) {
    __shared__ int s[256];
    int t = threadIdx.x;
    int i = blockIdx.x * 256 + t;
    int v = (i < NN) ? cnt[i] : 0;
    s[t] = v;
    __syncthreads();
    for (int off = 1; off < 256; off <<= 1) {
        int add = (t >= off) ? s[t - off] : 0;
        __syncthreads();
        s[t] += add;
        __syncthreads();
    }
    if (i < NN) row_off[i] = bsum[blockIdx.x] + s[t] - v;  // exclusive
    if (i == NN - 1) row_off[NN] = NE;
}

__global__ __launch_bounds__(256) void k_fill(const int* __restrict__ ei,
                                              const float* __restrict__ nrm,
                                              const int* __restrict__ row_off,
                                              int* __restrict__ cursor,
                                              int2* __restrict__ csr) {
    int e = blockIdx.x * 256 + threadIdx.x;
    if (e < NE) {
        int d = ei[NE + e];
        int pos = row_off[d] + atomicAdd(&cursor[d], 1);
        int2 v;
        v.x = ei[e];                     // src
        v.y = __float_as_int(nrm[e]);    // edge norm
        csr[pos] = v;
    }
}

// ---------------- GEMM: H = act(X) @ W ----------------
// 128 rows x 128 cols per block, KT=32 K-tiles, 8x8 microtile, 4 blocks/CU.
// act = relu(x*sc+sh) (fused BN of previous layer) when applyBN != 0.
__global__ __launch_bounds__(256, 4) void k_gemm2(const float* __restrict__ X,
                                                  const float* __restrict__ Wl,
                                                  const float* __restrict__ sc,
                                                  const float* __restrict__ sh,
                                                  int applyBN,
                                                  float* __restrict__ H) {
    __shared__ float xs[128][33];   // [row][kk], pad 33 -> conflict-free bcast
    __shared__ float ws[32][128];   // [kk][col], 512B rows (float4-aligned)
    const int tid = threadIdx.x;
    const int row0 = blockIdx.x * 128;
    const int ty = tid >> 4, tx = tid & 15;
    const int r0 = ty * 8, c0 = tx * 8;

    float acc[8][8];
#pragma unroll
    for (int i = 0; i < 8; ++i)
#pragma unroll
        for (int j = 0; j < 8; ++j) acc[i][j] = 0.f;

    for (int kt = 0; kt < 4; ++kt) {
        // stage X strip: 128 rows x 32 k-cols (1024 float4 slots)
#pragma unroll
        for (int i = 0; i < 4; ++i) {
            int f = i * 256 + tid;          // 0..1023
            int r = f >> 3, c4 = (f & 7) * 4;
            int gr = row0 + r;
            float4 v = make_float4(0.f, 0.f, 0.f, 0.f);
            if (gr < NN) v = *(const float4*)&X[(size_t)gr * DD + kt * 32 + c4];
            if (applyBN) {
                int k = kt * 32 + c4;
                float4 s4 = *(const float4*)&sc[k];
                float4 h4 = *(const float4*)&sh[k];
                v.x = fmaxf(fmaf(v.x, s4.x, h4.x), 0.f);
                v.y = fmaxf(fmaf(v.y, s4.y, h4.y), 0.f);
                v.z = fmaxf(fmaf(v.z, s4.z, h4.z), 0.f);
                v.w = fmaxf(fmaf(v.w, s4.w, h4.w), 0.f);
            }
            xs[r][c4 + 0] = v.x;
            xs[r][c4 + 1] = v.y;
            xs[r][c4 + 2] = v.z;
            xs[r][c4 + 3] = v.w;
        }
        // stage W strip: 32 k-rows x 128 cols (1024 float4 slots)
#pragma unroll
        for (int i = 0; i < 4; ++i) {
            int f = i * 256 + tid;          // 0..1023  [BUGFIX: was i<2 / 0..511]
            int r = f >> 5, c4 = (f & 31) * 4;   // r 0..31, c4 0..124
            float4 w = *(const float4*)&Wl[(size_t)(kt * 32 + r) * DD + c4];
            *(float4*)&ws[r][c4] = w;
        }
        __syncthreads();

#pragma unroll 8
        for (int kk = 0; kk < 32; ++kk) {
            float a[8];
#pragma unroll
            for (int i = 0; i < 8; ++i) a[i] = xs[r0 + i][kk];
            float4 b0 = *(float4*)&ws[kk][c0];
            float4 b1 = *(float4*)&ws[kk][c0 + 4];
            float b[8] = {b0.x, b0.y, b0.z, b0.w, b1.x, b1.y, b1.z, b1.w};
#pragma unroll
            for (int i = 0; i < 8; ++i)
#pragma unroll
                for (int j = 0; j < 8; ++j)
                    acc[i][j] = fmaf(a[i], b[j], acc[i][j]);
        }
        __syncthreads();
    }

#pragma unroll
    for (int i = 0; i < 8; ++i) {
        int gr = row0 + r0 + i;
        if (gr < NN) {
            size_t base = (size_t)gr * DD + c0;
            *(float4*)&H[base] = make_float4(acc[i][0], acc[i][1], acc[i][2], acc[i][3]);
            *(float4*)&H[base + 4] = make_float4(acc[i][4], acc[i][5], acc[i][6], acc[i][7]);
        }
    }
}

// ---------------- aggregation: A[v] = dinv^2 H[v] + sum w*H[src] ----------
// 32 lanes per node (float4/lane), 2 nodes per wave, 8 nodes per block.
// NN % 8 == 0 -> no bounds guard.
__global__ __launch_bounds__(256) void k_agg2(const int2* __restrict__ csr,
                                              const int* __restrict__ row_off,
                                              const float* __restrict__ dinv,
                                              const float* __restrict__ H,
                                              float* __restrict__ A) {
    int node = blockIdx.x * 8 + (threadIdx.x >> 5);
    int h = threadIdx.x & 31;
    int beg = row_off[node], end = row_off[node + 1];
    float dv = dinv[node];
    size_t cbase = (size_t)node * DD + h * 4;
    float4 hs = *(const float4*)&H[cbase];
    float sl = dv * dv;
    float4 av = make_float4(sl * hs.x, sl * hs.y, sl * hs.z, sl * hs.w);

    int j = beg;
    for (; j + 4 <= end; j += 4) {
        int2 e0 = csr[j], e1 = csr[j + 1], e2 = csr[j + 2], e3 = csr[j + 3];
        float4 h0 = *(const float4*)&H[(size_t)e0.x * DD + h * 4];
        float4 h1 = *(const float4*)&H[(size_t)e1.x * DD + h * 4];
        float4 h2 = *(const float4*)&H[(size_t)e2.x * DD + h * 4];
        float4 h3 = *(const float4*)&H[(size_t)e3.x * DD + h * 4];
        float w0 = __int_as_float(e0.y), w1 = __int_as_float(e1.y);
        float w2 = __int_as_float(e2.y), w3 = __int_as_float(e3.y);
        av.x = fmaf(w0, h0.x, av.x); av.y = fmaf(w0, h0.y, av.y);
        av.z = fmaf(w0, h0.z, av.z); av.w = fmaf(w0, h0.w, av.w);
        av.x = fmaf(w1, h1.x, av.x); av.y = fmaf(w1, h1.y, av.y);
        av.z = fmaf(w1, h1.z, av.z); av.w = fmaf(w1, h1.w, av.w);
        av.x = fmaf(w2, h2.x, av.x); av.y = fmaf(w2, h2.y, av.y);
        av.z = fmaf(w2, h2.z, av.z); av.w = fmaf(w2, h2.w, av.w);
        av.x = fmaf(w3, h3.x, av.x); av.y = fmaf(w3, h3.y, av.y);
        av.z = fmaf(w3, h3.z, av.z); av.w = fmaf(w3, h3.w, av.w);
    }
    for (; j < end; ++j) {
        int2 e = csr[j];
        float w = __int_as_float(e.y);
        float4 hv = *(const float4*)&H[(size_t)e.x * DD + h * 4];
        av.x = fmaf(w, hv.x, av.x); av.y = fmaf(w, hv.y, av.y);
        av.z = fmaf(w, hv.z, av.z); av.w = fmaf(w, hv.w, av.w);
    }
    *(float4*)&A[cbase] = av;
}

// ---------------- batchnorm stats ----------------
__global__ __launch_bounds__(256) void k_bn_stat(const float* __restrict__ A,
                                                 float* __restrict__ stats) {
    const int tid = threadIdx.x;
    const int col = tid & 127, half = tid >> 7;
    int v0 = blockIdx.x * 196;
    int v1 = v0 + 196;
    if (v1 > NN) v1 = NN;
    float s = 0.f, ss = 0.f;
    for (int v = v0 + half; v < v1; v += 2) {
        float a = A[(size_t)v * DD + col];
        s += a;
        ss = fmaf(a, a, ss);
    }
    __shared__ float buf[256];
    buf[tid] = s;
    __syncthreads();
    float s2 = 0.f;
    if (tid < 128) s2 = buf[tid] + buf[tid + 128];
    __syncthreads();
    buf[tid] = ss;
    __syncthreads();
    if (tid < 128) {
        float ss2 = buf[tid] + buf[tid + 128];
        atomAddF(&stats[tid], s2);
        atomAddF(&stats[128 + tid], ss2);
    }
}

__global__ void k_bn_final(const float* __restrict__ stats,
                           const float* __restrict__ gamma,
                           const float* __restrict__ beta,
                           float* __restrict__ sc, float* __restrict__ sh) {
    int c = threadIdx.x;
    if (c < DD) {
        float mu = stats[c] * (1.0f / NN);
        float var = stats[DD + c] * (1.0f / NN) - mu * mu;
        float inv = rsqrtf(var + EPSBN);
        float s = gamma[c] * inv;
        sc[c] = s;
        sh[c] = beta[c] - mu * s;  // conv bias b cancels in BN exactly
    }
}

// ---------------- zero out + stats ----------------
__global__ __launch_bounds__(256) void k_zero_fo(float* __restrict__ out,
                                                 float* __restrict__ stats) {
    int i = blockIdx.x * 256 + threadIdx.x;
    if (i < NG * DD) out[i] = 0.f;
    int j = i - NG * DD;
    if (j >= 0 && j < 768) stats[j] = 0.f;
}

// ---------------- pooling (fused final BN+ReLU) ----------------
__global__ __launch_bounds__(256) void k_pool(const float* __restrict__ A,
                                              const int* __restrict__ batch,
                                              const float* __restrict__ sc,
                                              const float* __restrict__ sh,
                                              float* __restrict__ out) {
    const int tid = threadIdx.x;
    const int col = tid & 127, half = tid >> 7;
    const float s = sc[col], t = sh[col];
    int v0 = blockIdx.x * 196;
    int v1 = v0 + 196;
    if (v1 > NN) v1 = NN;
    float acc = 0.f;
    int g = -1;
    for (int v = v0 + half; v < v1; v += 2) {
        int bg = batch[v];
        if (bg != g) {
            if (g >= 0) atomAddF(&out[(size_t)g * DD + col], acc);
            g = bg;
            acc = 0.f;
        }
        acc += fmaxf(fmaf(A[(size_t)v * DD + col], s, t), 0.f);
    }
    if (g >= 0) atomAddF(&out[(size_t)g * DD + col], acc);
}

extern "C" void kernel_launch(void* const* d_in, const int* in_sizes, int n_in,
                              void* d_out, int out_size, void* d_ws, size_t ws_size,
                              hipStream_t stream) {
    const float* x     = (const float*)d_in[0];
    const int*   ei    = (const int*)d_in[1];
    const float* ew    = (const float*)d_in[2];
    const int*   batch = (const int*)d_in[3];
    const float* W     = (const float*)d_in[4];
    // d_in[5] = b — cancels exactly in training-mode BatchNorm, unused
    const float* gamma = (const float*)d_in[6];
    const float* beta  = (const float*)d_in[7];
    float* out = (float*)d_out;

    float* wsp   = (float*)d_ws;
    float* deg   = wsp;                  // N
    float* dinv  = deg + NN;             // N
    float* nrm   = dinv + NN;            // E
    float* stats = nrm + NE;             // 768 (3 layers x 256)
    float* scl   = stats + 768;          // 3 x 128
    float* shl   = scl + 3 * DD;         // 3 x 128
    float* H     = shl + 3 * DD;         // N*D
    float* A     = H + (size_t)NN * DD;  // N*D
    int*   cnt     = (int*)(A + (size_t)NN * DD);  // N
    int*   cursor  = cnt + NN;           // N
    int*   row_off = cursor + NN;        // N+1
    int*   bsum    = row_off + NN + 1;   // 512
    int2*  csr     = (int2*)(bsum + 512);  // E * 8B
    // total ≈ 124 MiB

    k_deg_init<<<(NN + 255) / 256, 256, 0, stream>>>(deg);
    k_deg_acc<<<(NE + 255) / 256, 256, 0, stream>>>(ei, ew, deg);
    k_dinv<<<(NN + 255) / 256, 256, 0, stream>>>(deg, dinv);
    k_norm<<<(NE + 255) / 256, 256, 0, stream>>>(ei, ew, dinv, nrm);

    // CSR build (reused across layers)
    k_zero_ints<<<(2 * NN + 255) / 256, 256, 0, stream>>>(cnt, 2 * NN);
    k_count<<<(NE + 255) / 256, 256, 0, stream>>>(ei, cnt);
    k_scan_block<<<NBLK, 256, 0, stream>>>(cnt, bsum);
    k_scan_top<<<1, 512, 0, stream>>>(bsum);
    k_scan_out<<<NBLK, 256, 0, stream>>>(cnt, bsum, row_off);
    k_fill<<<(NE + 255) / 256, 256, 0, stream>>>(ei, nrm, row_off, cursor, csr);

    k_zero_fo<<<(NG * DD + 768 + 255) / 256, 256, 0, stream>>>(out, stats);

    const float* xcur = x;
    for (int l = 0; l < NL; ++l) {
        const float* sc_prev = (l > 0) ? scl + (l - 1) * DD : scl;
        const float* sh_prev = (l > 0) ? shl + (l - 1) * DD : shl;
        k_gemm2<<<(NN + 127) / 128, 256, 0, stream>>>(
            xcur, W + (size_t)l * DD * DD, sc_prev, sh_prev, l > 0 ? 1 : 0, H);
        k_agg2<<<NN / 8, 256, 0, stream>>>(csr, row_off, dinv, H, A);
        k_bn_stat<<<512, 256, 0, stream>>>(A, stats + l * 256);
        k_bn_final<<<1, 128, 0, stream>>>(stats + l * 256, gamma + (size_t)l * DD,
                                          beta + (size_t)l * DD,
                                          scl + l * DD, shl + l * DD);
        xcur = A;
    }

    k_pool<<<512, 256, 0, stream>>>(A, batch, scl + 2 * DD, shl + 2 * DD, out);
}

// Round 7
// 835.739 us; speedup vs baseline: 10.4031x; 1.2120x over previous
//
#include <hip/hip_runtime.h>

#define NN 100000   // nodes
#define NE 1600000  // edges
#define DD 128      // feature dim
#define NL 3        // layers
#define NG 64       // graphs
#define EPSBN 1e-5f
#define NBLK ((NN + 255) / 256)   // 391 scan blocks

// ---- fp32 atomic add (HW global_atomic_add_f32, no CAS loop) ----
__device__ inline void atomAddF(float* p, float v) {
#if defined(__AMDGCN__)
    unsafeAtomicAdd(p, v);
#else
    atomicAdd(p, v);
#endif
}

// ---- fp32 -> bf16 round-to-nearest-even ----
__device__ inline ushort f2bf(float f) {
    uint u = __float_as_uint(f);
    uint r = ((u >> 16) & 1u) + 0x7fffu;
    return (ushort)((u + r) >> 16);
}

// ---- accumulate 8 bf16 lanes (packed in uint4) scaled by w into acc[8] ----
__device__ inline void acc8(float (&acc)[8], uint4 g, float wgt) {
    acc[0] = fmaf(wgt, __uint_as_float(g.x << 16), acc[0]);
    acc[1] = fmaf(wgt, __uint_as_float(g.x & 0xffff0000u), acc[1]);
    acc[2] = fmaf(wgt, __uint_as_float(g.y << 16), acc[2]);
    acc[3] = fmaf(wgt, __uint_as_float(g.y & 0xffff0000u), acc[3]);
    acc[4] = fmaf(wgt, __uint_as_float(g.z << 16), acc[4]);
    acc[5] = fmaf(wgt, __uint_as_float(g.z & 0xffff0000u), acc[5]);
    acc[6] = fmaf(wgt, __uint_as_float(g.w << 16), acc[6]);
    acc[7] = fmaf(wgt, __uint_as_float(g.w & 0xffff0000u), acc[7]);
}

// ---------------- degree / norm setup ----------------
__global__ __launch_bounds__(256) void k_deg_init(float* __restrict__ deg) {
    int i = blockIdx.x * 256 + threadIdx.x;
    if (i < NN) deg[i] = 1.0f;  // self-loop weight
}

// fused: weighted degree + in-degree count (one pass over dst)
__global__ __launch_bounds__(256) void k_deg_cnt(const int* __restrict__ ei,
                                                 const float* __restrict__ ew,
                                                 float* __restrict__ deg,
                                                 int* __restrict__ cnt) {
    int e = blockIdx.x * 256 + threadIdx.x;
    if (e < NE) {
        int d = ei[NE + e];
        atomAddF(&deg[d], ew[e]);
        atomicAdd(&cnt[d], 1);
    }
}

__global__ __launch_bounds__(256) void k_dinv(const float* __restrict__ deg,
                                              float* __restrict__ dinv) {
    int i = blockIdx.x * 256 + threadIdx.x;
    if (i < NN) {
        float d = deg[i];
        dinv[i] = d > 0.f ? rsqrtf(fmaxf(d, 1e-12f)) : 0.f;
    }
}

__global__ __launch_bounds__(256) void k_norm(const int* __restrict__ ei,
                                              const float* __restrict__ ew,
                                              const float* __restrict__ dinv,
                                              float* __restrict__ nrm) {
    int e = blockIdx.x * 256 + threadIdx.x;
    if (e < NE) nrm[e] = dinv[ei[e]] * ew[e] * dinv[ei[NE + e]];
}

// ---------------- CSR-by-dst build ----------------
__global__ __launch_bounds__(256) void k_zero_ints(int* __restrict__ p, int n) {
    int i = blockIdx.x * 256 + threadIdx.x;
    if (i < n) p[i] = 0;
}

__global__ __launch_bounds__(256) void k_scan_block(const int* __restrict__ cnt,
                                                    int* __restrict__ bsum) {
    __shared__ int s[256];
    int i = blockIdx.x * 256 + threadIdx.x;
    s[threadIdx.x] = (i < NN) ? cnt[i] : 0;
    __syncthreads();
    for (int off = 128; off > 0; off >>= 1) {
        if (threadIdx.x < off) s[threadIdx.x] += s[threadIdx.x + off];
        __syncthreads();
    }
    if (threadIdx.x == 0) bsum[blockIdx.x] = s[0];
}

__global__ __launch_bounds__(512) void k_scan_top(int* __restrict__ bsum) {
    __shared__ int s[512];
    int t = threadIdx.x;
    int v = (t < NBLK) ? bsum[t] : 0;
    s[t] = v;
    __syncthreads();
    for (int off = 1; off < 512; off <<= 1) {
        int add = (t >= off) ? s[t - off] : 0;
        __syncthreads();
        s[t] += add;
        __syncthreads();
    }
    if (t < NBLK) bsum[t] = s[t] - v;  // exclusive
}

__global__ __launch_bounds__(256) void k_scan_out(const int* __restrict__ cnt,
                                                  const int* __restrict__ bsum,
                                                  int* __restrict__ row_off) {
    __shared__ int s[256];
    int t = threadIdx.x;
    int i = blockIdx.x * 256 + t;
    int v = (i < NN) ? cnt[i] : 0;
    s[t] = v;
    __syncthreads();
    for (int off = 1; off < 256; off <<= 1) {
        int add = (t >= off) ? s[t - off] : 0;
        __syncthreads();
        s[t] += add;
        __syncthreads();
    }
    if (i < NN) row_off[i] = bsum[blockIdx.x] + s[t] - v;  // exclusive
    if (i == NN - 1) row_off[NN] = NE;
}

__global__ __launch_bounds__(256) void k_fill(const int* __restrict__ ei,
                                              const float* __restrict__ nrm,
                                              const int* __restrict__ row_off,
                                              int* __restrict__ cursor,
                                              int2* __restrict__ csr) {
    int e = blockIdx.x * 256 + threadIdx.x;
    if (e < NE) {
        int d = ei[NE + e];
        int pos = row_off[d] + atomicAdd(&cursor[d], 1);
        int2 v;
        v.x = ei[e];                     // src
        v.y = __float_as_int(nrm[e]);    // edge norm
        csr[pos] = v;
    }
}

// ---------------- GEMM: H = act(X) @ W, H stored bf16 ----------------
// 128 rows x 128 cols per block, KT=32 K-tiles, 8x8 microtile, 4 blocks/CU.
// act = relu(x*sc+sh) (fused BN of previous layer) when applyBN != 0.
__global__ __launch_bounds__(256, 4) void k_gemm2(const float* __restrict__ X,
                                                  const float* __restrict__ Wl,
                                                  const float* __restrict__ sc,
                                                  const float* __restrict__ sh,
                                                  int applyBN,
                                                  ushort* __restrict__ H) {
    __shared__ float xs[128][33];   // [row][kk], pad 33 -> conflict-free bcast
    __shared__ float ws[32][128];   // [kk][col], 512B rows (float4-aligned)
    const int tid = threadIdx.x;
    const int row0 = blockIdx.x * 128;
    const int ty = tid >> 4, tx = tid & 15;
    const int r0 = ty * 8, c0 = tx * 8;

    float acc[8][8];
#pragma unroll
    for (int i = 0; i < 8; ++i)
#pragma unroll
        for (int j = 0; j < 8; ++j) acc[i][j] = 0.f;

    for (int kt = 0; kt < 4; ++kt) {
        // stage X strip: 128 rows x 32 k-cols (1024 float4 slots)
#pragma unroll
        for (int i = 0; i < 4; ++i) {
            int f = i * 256 + tid;          // 0..1023
            int r = f >> 3, c4 = (f & 7) * 4;
            int gr = row0 + r;
            float4 v = make_float4(0.f, 0.f, 0.f, 0.f);
            if (gr < NN) v = *(const float4*)&X[(size_t)gr * DD + kt * 32 + c4];
            if (applyBN) {
                int k = kt * 32 + c4;
                float4 s4 = *(const float4*)&sc[k];
                float4 h4 = *(const float4*)&sh[k];
                v.x = fmaxf(fmaf(v.x, s4.x, h4.x), 0.f);
                v.y = fmaxf(fmaf(v.y, s4.y, h4.y), 0.f);
                v.z = fmaxf(fmaf(v.z, s4.z, h4.z), 0.f);
                v.w = fmaxf(fmaf(v.w, s4.w, h4.w), 0.f);
            }
            xs[r][c4 + 0] = v.x;
            xs[r][c4 + 1] = v.y;
            xs[r][c4 + 2] = v.z;
            xs[r][c4 + 3] = v.w;
        }
        // stage W strip: 32 k-rows x 128 cols (1024 float4 slots)
#pragma unroll
        for (int i = 0; i < 4; ++i) {
            int f = i * 256 + tid;          // 0..1023
            int r = f >> 5, c4 = (f & 31) * 4;   // r 0..31
            float4 w = *(const float4*)&Wl[(size_t)(kt * 32 + r) * DD + c4];
            *(float4*)&ws[r][c4] = w;
        }
        __syncthreads();

#pragma unroll 8
        for (int kk = 0; kk < 32; ++kk) {
            float a[8];
#pragma unroll
            for (int i = 0; i < 8; ++i) a[i] = xs[r0 + i][kk];
            float4 b0 = *(float4*)&ws[kk][c0];
            float4 b1 = *(float4*)&ws[kk][c0 + 4];
            float b[8] = {b0.x, b0.y, b0.z, b0.w, b1.x, b1.y, b1.z, b1.w};
#pragma unroll
            for (int i = 0; i < 8; ++i)
#pragma unroll
                for (int j = 0; j < 8; ++j)
                    acc[i][j] = fmaf(a[i], b[j], acc[i][j]);
        }
        __syncthreads();
    }

#pragma unroll
    for (int i = 0; i < 8; ++i) {
        int gr = row0 + r0 + i;
        if (gr < NN) {
            size_t base = (size_t)gr * DD + c0;   // in ushorts
            uint4 st;
            st.x = (uint)f2bf(acc[i][0]) | ((uint)f2bf(acc[i][1]) << 16);
            st.y = (uint)f2bf(acc[i][2]) | ((uint)f2bf(acc[i][3]) << 16);
            st.z = (uint)f2bf(acc[i][4]) | ((uint)f2bf(acc[i][5]) << 16);
            st.w = (uint)f2bf(acc[i][6]) | ((uint)f2bf(acc[i][7]) << 16);
            *(uint4*)&H[base] = st;
        }
    }
}

// ---------------- aggregation: A[v] = dinv^2 H[v] + sum w*H[src] ----------
// bf16 H: 16 lanes per node, 8 cols per lane (one uint4 = 8 bf16 per gather).
// NN % 16 == 0 -> no bounds guard.
__global__ __launch_bounds__(256) void k_agg3(const int2* __restrict__ csr,
                                              const int* __restrict__ row_off,
                                              const float* __restrict__ dinv,
                                              const ushort* __restrict__ H,
                                              float* __restrict__ A) {
    int node = blockIdx.x * 16 + (threadIdx.x >> 4);
    int h = threadIdx.x & 15;
    int beg = row_off[node], end = row_off[node + 1];
    float dv = dinv[node];
    size_t cb = (size_t)node * DD + h * 8;   // ushort index
    float acc[8];
    {
        uint4 v = *(const uint4*)&H[cb];
        float sl = dv * dv;
        acc[0] = sl * __uint_as_float(v.x << 16);
        acc[1] = sl * __uint_as_float(v.x & 0xffff0000u);
        acc[2] = sl * __uint_as_float(v.y << 16);
        acc[3] = sl * __uint_as_float(v.y & 0xffff0000u);
        acc[4] = sl * __uint_as_float(v.z << 16);
        acc[5] = sl * __uint_as_float(v.z & 0xffff0000u);
        acc[6] = sl * __uint_as_float(v.w << 16);
        acc[7] = sl * __uint_as_float(v.w & 0xffff0000u);
    }

    int j = beg;
    for (; j + 4 <= end; j += 4) {
        int2 e0 = csr[j], e1 = csr[j + 1], e2 = csr[j + 2], e3 = csr[j + 3];
        uint4 g0 = *(const uint4*)&H[(size_t)e0.x * DD + h * 8];
        uint4 g1 = *(const uint4*)&H[(size_t)e1.x * DD + h * 8];
        uint4 g2 = *(const uint4*)&H[(size_t)e2.x * DD + h * 8];
        uint4 g3 = *(const uint4*)&H[(size_t)e3.x * DD + h * 8];
        acc8(acc, g0, __int_as_float(e0.y));
        acc8(acc, g1, __int_as_float(e1.y));
        acc8(acc, g2, __int_as_float(e2.y));
        acc8(acc, g3, __int_as_float(e3.y));
    }
    for (; j < end; ++j) {
        int2 e = csr[j];
        uint4 g = *(const uint4*)&H[(size_t)e.x * DD + h * 8];
        acc8(acc, g, __int_as_float(e.y));
    }

    size_t ab = (size_t)node * DD + h * 8;
    *(float4*)&A[ab] = make_float4(acc[0], acc[1], acc[2], acc[3]);
    *(float4*)&A[ab + 4] = make_float4(acc[4], acc[5], acc[6], acc[7]);
}

// ---------------- batchnorm stats ----------------
__global__ __launch_bounds__(256) void k_bn_stat(const float* __restrict__ A,
                                                 float* __restrict__ stats) {
    const int tid = threadIdx.x;
    const int col = tid & 127, half = tid >> 7;
    int v0 = blockIdx.x * 196;
    int v1 = v0 + 196;
    if (v1 > NN) v1 = NN;
    float s = 0.f, ss = 0.f;
    for (int v = v0 + half; v < v1; v += 2) {
        float a = A[(size_t)v * DD + col];
        s += a;
        ss = fmaf(a, a, ss);
    }
    __shared__ float buf[256];
    buf[tid] = s;
    __syncthreads();
    float s2 = 0.f;
    if (tid < 128) s2 = buf[tid] + buf[tid + 128];
    __syncthreads();
    buf[tid] = ss;
    __syncthreads();
    if (tid < 128) {
        float ss2 = buf[tid] + buf[tid + 128];
        atomAddF(&stats[tid], s2);
        atomAddF(&stats[128 + tid], ss2);
    }
}

__global__ void k_bn_final(const float* __restrict__ stats,
                           const float* __restrict__ gamma,
                           const float* __restrict__ beta,
                           float* __restrict__ sc, float* __restrict__ sh) {
    int c = threadIdx.x;
    if (c < DD) {
        float mu = stats[c] * (1.0f / NN);
        float var = stats[DD + c] * (1.0f / NN) - mu * mu;
        float inv = rsqrtf(var + EPSBN);
        float s = gamma[c] * inv;
        sc[c] = s;
        sh[c] = beta[c] - mu * s;  // conv bias b cancels in BN exactly
    }
}

// ---------------- zero out + stats ----------------
__global__ __launch_bounds__(256) void k_zero_fo(float* __restrict__ out,
                                                 float* __restrict__ stats) {
    int i = blockIdx.x * 256 + threadIdx.x;
    if (i < NG * DD) out[i] = 0.f;
    int j = i - NG * DD;
    if (j >= 0 && j < 768) stats[j] = 0.f;
}

// ---------------- pooling (fused final BN+ReLU) ----------------
__global__ __launch_bounds__(256) void k_pool(const float* __restrict__ A,
                                              const int* __restrict__ batch,
                                              const float* __restrict__ sc,
                                              const float* __restrict__ sh,
                                              float* __restrict__ out) {
    const int tid = threadIdx.x;
    const int col = tid & 127, half = tid >> 7;
    const float s = sc[col], t = sh[col];
    int v0 = blockIdx.x * 196;
    int v1 = v0 + 196;
    if (v1 > NN) v1 = NN;
    float acc = 0.f;
    int g = -1;
    for (int v = v0 + half; v < v1; v += 2) {
        int bg = batch[v];
        if (bg != g) {
            if (g >= 0) atomAddF(&out[(size_t)g * DD + col], acc);
            g = bg;
            acc = 0.f;
        }
        acc += fmaxf(fmaf(A[(size_t)v * DD + col], s, t), 0.f);
    }
    if (g >= 0) atomAddF(&out[(size_t)g * DD + col], acc);
}

extern "C" void kernel_launch(void* const* d_in, const int* in_sizes, int n_in,
                              void* d_out, int out_size, void* d_ws, size_t ws_size,
                              hipStream_t stream) {
    const float* x     = (const float*)d_in[0];
    const int*   ei    = (const int*)d_in[1];
    const float* ew    = (const float*)d_in[2];
    const int*   batch = (const int*)d_in[3];
    const float* W     = (const float*)d_in[4];
    // d_in[5] = b — cancels exactly in training-mode BatchNorm, unused
    const float* gamma = (const float*)d_in[6];
    const float* beta  = (const float*)d_in[7];
    float* out = (float*)d_out;

    float* wsp   = (float*)d_ws;
    float* deg   = wsp;                  // N
    float* dinv  = deg + NN;             // N
    float* nrm   = dinv + NN;            // E
    float* stats = nrm + NE;             // 768 (3 layers x 256)
    float* scl   = stats + 768;          // 3 x 128
    float* shl   = scl + 3 * DD;         // 3 x 128
    ushort* H    = (ushort*)(shl + 3 * DD);        // N*D bf16 (16B-aligned)
    float* A     = (float*)(H + (size_t)NN * DD);  // N*D fp32 (16B-aligned)
    int*   cnt     = (int*)(A + (size_t)NN * DD);  // N
    int*   cursor  = cnt + NN;           // N
    int*   row_off = cursor + NN;        // N+1
    int*   bsum    = row_off + NN + 1;   // 512
    int2*  csr     = (int2*)(bsum + 512);  // E * 8B
    // total ≈ 98 MiB

    k_deg_init<<<(NN + 255) / 256, 256, 0, stream>>>(deg);
    k_zero_ints<<<(2 * NN + 255) / 256, 256, 0, stream>>>(cnt, 2 * NN);
    k_deg_cnt<<<(NE + 255) / 256, 256, 0, stream>>>(ei, ew, deg, cnt);
    k_dinv<<<(NN + 255) / 256, 256, 0, stream>>>(deg, dinv);
    k_norm<<<(NE + 255) / 256, 256, 0, stream>>>(ei, ew, dinv, nrm);

    // CSR build (reused across layers)
    k_scan_block<<<NBLK, 256, 0, stream>>>(cnt, bsum);
    k_scan_top<<<1, 512, 0, stream>>>(bsum);
    k_scan_out<<<NBLK, 256, 0, stream>>>(cnt, bsum, row_off);
    k_fill<<<(NE + 255) / 256, 256, 0, stream>>>(ei, nrm, row_off, cursor, csr);

    k_zero_fo<<<(NG * DD + 768 + 255) / 256, 256, 0, stream>>>(out, stats);

    const float* xcur = x;
    for (int l = 0; l < NL; ++l) {
        const float* sc_prev = (l > 0) ? scl + (l - 1) * DD : scl;
        const float* sh_prev = (l > 0) ? shl + (l - 1) * DD : shl;
        k_gemm2<<<(NN + 127) / 128, 256, 0, stream>>>(
            xcur, W + (size_t)l * DD * DD, sc_prev, sh_prev, l > 0 ? 1 : 0, H);
        k_agg3<<<NN / 16, 256, 0, stream>>>(csr, row_off, dinv, H, A);
        k_bn_stat<<<512, 256, 0, stream>>>(A, stats + l * 256);
        k_bn_final<<<1, 128, 0, stream>>>(stats + l * 256, gamma + (size_t)l * DD,
                                          beta + (size_t)l * DD,
                                          scl + l * DD, shl + l * DD);
        xcur = A;
    }

    k_pool<<<512, 256, 0, stream>>>(A, batch, scl + 2 * DD, shl + 2 * DD, out);
}

// Round 9
// 631.517 us; speedup vs baseline: 13.7672x; 1.3234x over previous
//
#include <hip/hip_runtime.h>

#define NN 100000   // nodes
#define NE 1600000  // edges
#define DD 128      // feature dim
#define NL 3        // layers
#define NG 64       // graphs
#define EPSBN 1e-5f
#define NBLK ((NN + 255) / 256)   // 391 scan blocks

typedef __attribute__((ext_vector_type(8))) short short8v;   // 8 bf16 (4 VGPR)
typedef __attribute__((ext_vector_type(4))) float float4v;   // MFMA C/D

// ---- fp32 atomic add (HW global_atomic_add_f32, no CAS loop) ----
__device__ inline void atomAddF(float* p, float v) {
#if defined(__AMDGCN__)
    unsafeAtomicAdd(p, v);
#else
    atomicAdd(p, v);
#endif
}

// ---- fp32 -> bf16 round-to-nearest-even ----
__device__ inline ushort f2bf(float f) {
    uint u = __float_as_uint(f);
    uint r = ((u >> 16) & 1u) + 0x7fffu;
    return (ushort)((u + r) >> 16);
}

// ---- accumulate 8 bf16 lanes (packed in uint4) scaled by w into acc[8] ----
__device__ inline void acc8(float (&acc)[8], uint4 g, float wgt) {
    acc[0] = fmaf(wgt, __uint_as_float(g.x << 16), acc[0]);
    acc[1] = fmaf(wgt, __uint_as_float(g.x & 0xffff0000u), acc[1]);
    acc[2] = fmaf(wgt, __uint_as_float(g.y << 16), acc[2]);
    acc[3] = fmaf(wgt, __uint_as_float(g.y & 0xffff0000u), acc[3]);
    acc[4] = fmaf(wgt, __uint_as_float(g.z << 16), acc[4]);
    acc[5] = fmaf(wgt, __uint_as_float(g.z & 0xffff0000u), acc[5]);
    acc[6] = fmaf(wgt, __uint_as_float(g.w << 16), acc[6]);
    acc[7] = fmaf(wgt, __uint_as_float(g.w & 0xffff0000u), acc[7]);
}

// ---------------- CSR-by-dst build ----------------
__global__ __launch_bounds__(256) void k_zero_ints(int* __restrict__ p, int n) {
    int i = blockIdx.x * 256 + threadIdx.x;
    if (i < n) p[i] = 0;
}

__global__ __launch_bounds__(256) void k_count(const int* __restrict__ ei,
                                               int* __restrict__ cnt) {
    int e = blockIdx.x * 256 + threadIdx.x;
    if (e < NE) atomicAdd(&cnt[ei[NE + e]], 1);
}

__global__ __launch_bounds__(256) void k_scan_block(const int* __restrict__ cnt,
                                                    int* __restrict__ bsum) {
    __shared__ int s[256];
    int i = blockIdx.x * 256 + threadIdx.x;
    s[threadIdx.x] = (i < NN) ? cnt[i] : 0;
    __syncthreads();
    for (int off = 128; off > 0; off >>= 1) {
        if (threadIdx.x < off) s[threadIdx.x] += s[threadIdx.x + off];
        __syncthreads();
    }
    if (threadIdx.x == 0) bsum[blockIdx.x] = s[0];
}

__global__ __launch_bounds__(512) void k_scan_top(int* __restrict__ bsum) {
    __shared__ int s[512];
    int t = threadIdx.x;
    int v = (t < NBLK) ? bsum[t] : 0;
    s[t] = v;
    __syncthreads();
    for (int off = 1; off < 512; off <<= 1) {
        int add = (t >= off) ? s[t - off] : 0;
        __syncthreads();
        s[t] += add;
        __syncthreads();
    }
    if (t < NBLK) bsum[t] = s[t] - v;  // exclusive
}

__global__ __launch_bounds__(256) void k_scan_out(const int* __restrict__ cnt,
                                                  const int* __restrict__ bsum,
                                                  int* __restrict__ row_off) {
    __shared__ int s[256];
    int t = threadIdx.x;
    int i = blockIdx.x * 256 + t;
    int v = (i < NN) ? cnt[i] : 0;
    s[t] = v;
    __syncthreads();
    for (int off = 1; off < 256; off <<= 1) {
        int add = (t >= off) ? s[t - off] : 0;
        __syncthreads();
        s[t] += add;
        __syncthreads();
    }
    if (i < NN) row_off[i] = bsum[blockIdx.x] + s[t] - v;  // exclusive
    if (i == NN - 1) row_off[NN] = NE;
}

// fill CSR with {src, raw edge weight}; norms computed later in place
__global__ __launch_bounds__(256) void k_fill(const int* __restrict__ ei,
                                              const float* __restrict__ ew,
                                              const int* __restrict__ row_off,
                                              int* __restrict__ cursor,
                                              int2* __restrict__ csr) {
    int e = blockIdx.x * 256 + threadIdx.x;
    if (e < NE) {
        int d = ei[NE + e];
        int pos = row_off[d] + atomicAdd(&cursor[d], 1);
        int2 v;
        v.x = ei[e];                    // src
        v.y = __float_as_int(ew[e]);    // raw weight
        csr[pos] = v;
    }
}

// deg[node] = 1 + sum of row's ew (contiguous, no atomics); dinv = rsqrt
__global__ __launch_bounds__(256) void k_degdinv(const int2* __restrict__ csr,
                                                 const int* __restrict__ row_off,
                                                 float* __restrict__ dinv) {
    int node = blockIdx.x * 256 + threadIdx.x;
    if (node >= NN) return;
    int beg = row_off[node], end = row_off[node + 1];
    float s = 1.0f;  // self-loop
    for (int j = beg; j < end; ++j) s += __int_as_float(csr[j].y);
    dinv[node] = rsqrtf(s);  // s >= 1 > 0 always
}

// csr[j].y <- dinv[dst] * ew * dinv[src]  (in place)
__global__ __launch_bounds__(256) void k_nrm2(int2* __restrict__ csr,
                                              const int* __restrict__ row_off,
                                              const float* __restrict__ dinv) {
    int node = blockIdx.x * 256 + threadIdx.x;
    if (node >= NN) return;
    int beg = row_off[node], end = row_off[node + 1];
    float dv = dinv[node];
    int* y = (int*)csr;
    for (int j = beg; j < end; ++j) {
        int2 e = csr[j];
        float nw = dv * __int_as_float(e.y) * dinv[e.x];
        y[2 * (size_t)j + 1] = __float_as_int(nw);
    }
}

// ---------------- W prep: fp32 [k][n] -> bf16 [n][k], all 3 layers ----------
__global__ __launch_bounds__(256) void k_wprep(const float* __restrict__ W,
                                               ushort* __restrict__ Wt) {
    int idx = blockIdx.x * 256 + threadIdx.x;   // 0 .. 3*16384
    if (idx < NL * DD * DD) {
        int l = idx >> 14, i = idx & 16383;
        int k = i >> 7, n = i & 127;
        Wt[(size_t)l * DD * DD + n * DD + k] = f2bf(W[idx]);
    }
}

// ---------------- MFMA GEMM: H = act(X) @ W, bf16 in/out, fp32 accum -------
// 128x128 block, 4 waves (2x2 of 64x64), mfma_f32_16x16x32_bf16.
// LDS 64 KB (X tile + Wt tile, XOR-swizzled) -> 2 blocks/CU.
// act = relu(x*sc+sh) (prev layer's BN) when applyBN != 0.
__global__ __launch_bounds__(256, 2) void k_gemm3(const float* __restrict__ X,
                                                  const ushort* __restrict__ Wt,
                                                  const float* __restrict__ sc,
                                                  const float* __restrict__ sh,
                                                  int applyBN,
                                                  ushort* __restrict__ H) {
    __shared__ ushort xs[128 * 128];   // [row][k] bf16, swizzled
    __shared__ ushort ws[128 * 128];   // [n][k]  bf16, swizzled
    const int tid = threadIdx.x;
    const int row0 = blockIdx.x * 128;

    // stage X: 2048 chunks of 8 bf16 (rows x 16 chunks)
    for (int c = tid; c < 2048; c += 256) {
        int r = c >> 4, k8 = (c & 15) * 8;
        int gr = row0 + r;
        float v[8];
        if (gr < NN) {
            float4 a = *(const float4*)&X[(size_t)gr * DD + k8];
            float4 b = *(const float4*)&X[(size_t)gr * DD + k8 + 4];
            v[0] = a.x; v[1] = a.y; v[2] = a.z; v[3] = a.w;
            v[4] = b.x; v[5] = b.y; v[6] = b.z; v[7] = b.w;
        } else {
#pragma unroll
            for (int i = 0; i < 8; ++i) v[i] = 0.f;
        }
        if (applyBN) {
#pragma unroll
            for (int i = 0; i < 8; ++i)
                v[i] = fmaxf(fmaf(v[i], sc[k8 + i], sh[k8 + i]), 0.f);
        }
        uint4 st;
        st.x = (uint)f2bf(v[0]) | ((uint)f2bf(v[1]) << 16);
        st.y = (uint)f2bf(v[2]) | ((uint)f2bf(v[3]) << 16);
        st.z = (uint)f2bf(v[4]) | ((uint)f2bf(v[5]) << 16);
        st.w = (uint)f2bf(v[6]) | ((uint)f2bf(v[7]) << 16);
        int idx = r * 128 + (((k8 * 2) ^ ((r & 7) << 4)) >> 1);
        *(uint4*)&xs[idx] = st;
    }
    // stage Wt (already bf16 [n][k])
    for (int c = tid; c < 2048; c += 256) {
        int n = c >> 4, k8 = (c & 15) * 8;
        uint4 w = *(const uint4*)&Wt[n * DD + k8];
        int idx = n * 128 + (((k8 * 2) ^ ((n & 7) << 4)) >> 1);
        *(uint4*)&ws[idx] = w;
    }
    __syncthreads();

    const int wid = tid >> 6, lane = tid & 63;
    const int wm = wid >> 1, wn = wid & 1;       // 2x2 waves of 64x64
    const int lrow = lane & 15, lk = lane >> 4;  // A/B: row/col = lane&15, k-chunk = lane>>4
    float4v acc[4][4];
#pragma unroll
    for (int i = 0; i < 4; ++i)
#pragma unroll
        for (int j = 0; j < 4; ++j) acc[i][j] = (float4v){0.f, 0.f, 0.f, 0.f};

#pragma unroll
    for (int ks = 0; ks < 4; ++ks) {             // K window of 32
        int kbyte = ks * 64 + lk * 16;
        short8v a[4], b[4];
#pragma unroll
        for (int mg = 0; mg < 4; ++mg) {
            int r = wm * 64 + mg * 16 + lrow;
            a[mg] = *(const short8v*)&xs[r * 128 + ((kbyte ^ ((r & 7) << 4)) >> 1)];
        }
#pragma unroll
        for (int ng = 0; ng < 4; ++ng) {
            int n = wn * 64 + ng * 16 + lrow;
            b[ng] = *(const short8v*)&ws[n * 128 + ((kbyte ^ ((n & 7) << 4)) >> 1)];
        }
#pragma unroll
        for (int mg = 0; mg < 4; ++mg)
#pragma unroll
            for (int ng = 0; ng < 4; ++ng)
                acc[mg][ng] = __builtin_amdgcn_mfma_f32_16x16x32_bf16(
                    a[mg], b[ng], acc[mg][ng], 0, 0, 0);
    }

    // C/D layout: col = lane&15, row = (lane>>4)*4 + reg  [m89]
#pragma unroll
    for (int mg = 0; mg < 4; ++mg) {
        int rbase = row0 + wm * 64 + mg * 16 + lk * 4;
#pragma unroll
        for (int j = 0; j < 4; ++j) {
            int gr = rbase + j;
            if (gr < NN) {
#pragma unroll
                for (int ng = 0; ng < 4; ++ng) {
                    int col = wn * 64 + ng * 16 + lrow;
                    H[(size_t)gr * DD + col] = f2bf(acc[mg][ng][j]);
                }
            }
        }
    }
}

// ---------------- aggregation: A[v] = dinv^2 H[v] + sum w*H[src] ----------
// bf16 H: 16 lanes per node, 8 cols per lane (one uint4 = 8 bf16 per gather).
__global__ __launch_bounds__(256) void k_agg3(const int2* __restrict__ csr,
                                              const int* __restrict__ row_off,
                                              const float* __restrict__ dinv,
                                              const ushort* __restrict__ H,
                                              float* __restrict__ A) {
    int node = blockIdx.x * 16 + (threadIdx.x >> 4);
    int h = threadIdx.x & 15;
    int beg = row_off[node], end = row_off[node + 1];
    float dv = dinv[node];
    size_t cb = (size_t)node * DD + h * 8;   // ushort index
    float acc[8];
    {
        uint4 v = *(const uint4*)&H[cb];
        float sl = dv * dv;
        acc[0] = sl * __uint_as_float(v.x << 16);
        acc[1] = sl * __uint_as_float(v.x & 0xffff0000u);
        acc[2] = sl * __uint_as_float(v.y << 16);
        acc[3] = sl * __uint_as_float(v.y & 0xffff0000u);
        acc[4] = sl * __uint_as_float(v.z << 16);
        acc[5] = sl * __uint_as_float(v.z & 0xffff0000u);
        acc[6] = sl * __uint_as_float(v.w << 16);
        acc[7] = sl * __uint_as_float(v.w & 0xffff0000u);
    }

    int j = beg;
    for (; j + 4 <= end; j += 4) {
        int2 e0 = csr[j], e1 = csr[j + 1], e2 = csr[j + 2], e3 = csr[j + 3];
        uint4 g0 = *(const uint4*)&H[(size_t)e0.x * DD + h * 8];
        uint4 g1 = *(const uint4*)&H[(size_t)e1.x * DD + h * 8];
        uint4 g2 = *(const uint4*)&H[(size_t)e2.x * DD + h * 8];
        uint4 g3 = *(const uint4*)&H[(size_t)e3.x * DD + h * 8];
        acc8(acc, g0, __int_as_float(e0.y));
        acc8(acc, g1, __int_as_float(e1.y));
        acc8(acc, g2, __int_as_float(e2.y));
        acc8(acc, g3, __int_as_float(e3.y));
    }
    for (; j < end; ++j) {
        int2 e = csr[j];
        uint4 g = *(const uint4*)&H[(size_t)e.x * DD + h * 8];
        acc8(acc, g, __int_as_float(e.y));
    }

    size_t ab = (size_t)node * DD + h * 8;
    *(float4*)&A[ab] = make_float4(acc[0], acc[1], acc[2], acc[3]);
    *(float4*)&A[ab + 4] = make_float4(acc[4], acc[5], acc[6], acc[7]);
}

// ---------------- batchnorm stats ----------------
__global__ __launch_bounds__(256) void k_bn_stat(const float* __restrict__ A,
                                                 float* __restrict__ stats) {
    const int tid = threadIdx.x;
    const int col = tid & 127, half = tid >> 7;
    int v0 = blockIdx.x * 196;
    int v1 = v0 + 196;
    if (v1 > NN) v1 = NN;
    float s = 0.f, ss = 0.f;
    for (int v = v0 + half; v < v1; v += 2) {
        float a = A[(size_t)v * DD + col];
        s += a;
        ss = fmaf(a, a, ss);
    }
    __shared__ float buf[256];
    buf[tid] = s;
    __syncthreads();
    float s2 = 0.f;
    if (tid < 128) s2 = buf[tid] + buf[tid + 128];
    __syncthreads();
    buf[tid] = ss;
    __syncthreads();
    if (tid < 128) {
        float ss2 = buf[tid] + buf[tid + 128];
        atomAddF(&stats[tid], s2);
        atomAddF(&stats[128 + tid], ss2);
    }
}

__global__ void k_bn_final(const float* __restrict__ stats,
                           const float* __restrict__ gamma,
                           const float* __restrict__ beta,
                           float* __restrict__ sc, float* __restrict__ sh) {
    int c = threadIdx.x;
    if (c < DD) {
        float mu = stats[c] * (1.0f / NN);
        float var = stats[DD + c] * (1.0f / NN) - mu * mu;
        float inv = rsqrtf(var + EPSBN);
        float s = gamma[c] * inv;
        sc[c] = s;
        sh[c] = beta[c] - mu * s;  // conv bias b cancels in BN exactly
    }
}

// ---------------- zero out + stats ----------------
__global__ __launch_bounds__(256) void k_zero_fo(float* __restrict__ out,
                                                 float* __restrict__ stats) {
    int i = blockIdx.x * 256 + threadIdx.x;
    if (i < NG * DD) out[i] = 0.f;
    int j = i - NG * DD;
    if (j >= 0 && j < 768) stats[j] = 0.f;
}

// ---------------- pooling (fused final BN+ReLU) ----------------
__global__ __launch_bounds__(256) void k_pool(const float* __restrict__ A,
                                              const int* __restrict__ batch,
                                              const float* __restrict__ sc,
                                              const float* __restrict__ sh,
                                              float* __restrict__ out) {
    const int tid = threadIdx.x;
    const int col = tid & 127, half = tid >> 7;
    const float s = sc[col], t = sh[col];
    int v0 = blockIdx.x * 196;
    int v1 = v0 + 196;
    if (v1 > NN) v1 = NN;
    float acc = 0.f;
    int g = -1;
    for (int v = v0 + half; v < v1; v += 2) {
        int bg = batch[v];
        if (bg != g) {
            if (g >= 0) atomAddF(&out[(size_t)g * DD + col], acc);
            g = bg;
            acc = 0.f;
        }
        acc += fmaxf(fmaf(A[(size_t)v * DD + col], s, t), 0.f);
    }
    if (g >= 0) atomAddF(&out[(size_t)g * DD + col], acc);
}

extern "C" void kernel_launch(void* const* d_in, const int* in_sizes, int n_in,
                              void* d_out, int out_size, void* d_ws, size_t ws_size,
                              hipStream_t stream) {
    const float* x     = (const float*)d_in[0];
    const int*   ei    = (const int*)d_in[1];
    const float* ew    = (const float*)d_in[2];
    const int*   batch = (const int*)d_in[3];
    const float* W     = (const float*)d_in[4];
    // d_in[5] = b — cancels exactly in training-mode BatchNorm, unused
    const float* gamma = (const float*)d_in[6];
    const float* beta  = (const float*)d_in[7];
    float* out = (float*)d_out;

    float* wsp   = (float*)d_ws;
    float* dinv  = wsp;                  // N
    float* stats = dinv + NN;            // 768 (3 layers x 256)
    float* scl   = stats + 768;          // 3 x 128
    float* shl   = scl + 3 * DD;         // 3 x 128
    ushort* Wt   = (ushort*)(shl + 3 * DD);        // 3 x D x D bf16
    ushort* H    = Wt + (size_t)NL * DD * DD;      // N*D bf16
    float* A     = (float*)(H + (size_t)NN * DD);  // N*D fp32
    int*   cnt     = (int*)(A + (size_t)NN * DD);  // N
    int*   cursor  = cnt + NN;           // N
    int*   row_off = cursor + NN;        // N+4 (padded for alignment)
    int*   bsum    = row_off + NN + 4;   // 512
    int2*  csr     = (int2*)(bsum + 512);  // E * 8B
    // total ≈ 92 MiB

    // CSR build (structure only; weights raw)
    k_zero_ints<<<(2 * NN + 255) / 256, 256, 0, stream>>>(cnt, 2 * NN);
    k_count<<<(NE + 255) / 256, 256, 0, stream>>>(ei, cnt);
    k_scan_block<<<NBLK, 256, 0, stream>>>(cnt, bsum);
    k_scan_top<<<1, 512, 0, stream>>>(bsum);
    k_scan_out<<<NBLK, 256, 0, stream>>>(cnt, bsum, row_off);
    k_fill<<<(NE + 255) / 256, 256, 0, stream>>>(ei, ew, row_off, cursor, csr);

    // degrees + norms from CSR (atomic-free)
    k_degdinv<<<NBLK, 256, 0, stream>>>(csr, row_off, dinv);
    k_nrm2<<<NBLK, 256, 0, stream>>>(csr, row_off, dinv);

    // W -> bf16 transposed [n][k]
    k_wprep<<<(NL * DD * DD + 255) / 256, 256, 0, stream>>>(W, Wt);

    k_zero_fo<<<(NG * DD + 768 + 255) / 256, 256, 0, stream>>>(out, stats);

    const float* xcur = x;
    for (int l = 0; l < NL; ++l) {
        const float* sc_prev = (l > 0) ? scl + (l - 1) * DD : scl;
        const float* sh_prev = (l > 0) ? shl + (l - 1) * DD : shl;
        k_gemm3<<<(NN + 127) / 128, 256, 0, stream>>>(
            xcur, Wt + (size_t)l * DD * DD, sc_prev, sh_prev, l > 0 ? 1 : 0, H);
        k_agg3<<<NN / 16, 256, 0, stream>>>(csr, row_off, dinv, H, A);
        k_bn_stat<<<512, 256, 0, stream>>>(A, stats + l * 256);
        k_bn_final<<<1, 128, 0, stream>>>(stats + l * 256, gamma + (size_t)l * DD,
                                          beta + (size_t)l * DD,
                                          scl + l * DD, shl + l * DD);
        xcur = A;
    }

    k_pool<<<512, 256, 0, stream>>>(A, batch, scl + 2 * DD, shl + 2 * DD, out);
}

// Round 10
// 458.261 us; speedup vs baseline: 18.9723x; 1.3781x over previous
//
#include <hip/hip_runtime.h>

#define NN 100000   // nodes
#define NE 1600000  // edges
#define DD 128      // feature dim
#define NL 3        // layers
#define NG 64       // graphs
#define EPSBN 1e-5f
#define NBUCK 196               // ceil(NN/512) buckets of 512 nodes
#define NAGG (NN / 16)          // 6250 agg blocks (16 nodes each)

typedef __attribute__((ext_vector_type(8))) short short8v;   // 8 bf16 (4 VGPR)
typedef __attribute__((ext_vector_type(4))) float float4v;   // MFMA C/D

// ---- fp32 atomic add (HW global_atomic_add_f32, no CAS loop) ----
__device__ inline void atomAddF(float* p, float v) {
#if defined(__AMDGCN__)
    unsafeAtomicAdd(p, v);
#else
    atomicAdd(p, v);
#endif
}

// ---- fp32 -> bf16 round-to-nearest-even ----
__device__ inline ushort f2bf(float f) {
    uint u = __float_as_uint(f);
    uint r = ((u >> 16) & 1u) + 0x7fffu;
    return (ushort)((u + r) >> 16);
}

// ---- accumulate 8 bf16 lanes (packed in uint4) scaled by w into acc[8] ----
__device__ inline void acc8(float (&acc)[8], uint4 g, float wgt) {
    acc[0] = fmaf(wgt, __uint_as_float(g.x << 16), acc[0]);
    acc[1] = fmaf(wgt, __uint_as_float(g.x & 0xffff0000u), acc[1]);
    acc[2] = fmaf(wgt, __uint_as_float(g.y << 16), acc[2]);
    acc[3] = fmaf(wgt, __uint_as_float(g.y & 0xffff0000u), acc[3]);
    acc[4] = fmaf(wgt, __uint_as_float(g.z << 16), acc[4]);
    acc[5] = fmaf(wgt, __uint_as_float(g.z & 0xffff0000u), acc[5]);
    acc[6] = fmaf(wgt, __uint_as_float(g.w << 16), acc[6]);
    acc[7] = fmaf(wgt, __uint_as_float(g.w & 0xffff0000u), acc[7]);
}

// ---------------- init: out, stats, bucket counters ----------------
__global__ __launch_bounds__(256) void k_zero_fo(float* __restrict__ out,
                                                 float* __restrict__ stats,
                                                 int* __restrict__ gbcnt) {
    int i = blockIdx.x * 256 + threadIdx.x;
    if (i < NG * DD) out[i] = 0.f;
    int j = i - NG * DD;
    if (j >= 0 && j < 768) stats[j] = 0.f;
    int k = j - 768;
    if (k >= 0 && k < NBUCK) gbcnt[k] = 0;
}

// ---------------- bucket histogram over dst ----------------
__global__ __launch_bounds__(256) void k_bcnt(const int* __restrict__ ei,
                                              int* __restrict__ gbcnt) {
    __shared__ int lh[NBUCK];
    int tid = threadIdx.x;
    if (tid < NBUCK) lh[tid] = 0;
    __syncthreads();
    for (int e = blockIdx.x * 256 + tid; e < NE; e += 256 * 256)
        atomicAdd(&lh[ei[NE + e] >> 9], 1);
    __syncthreads();
    if (tid < NBUCK) atomicAdd(&gbcnt[tid], lh[tid]);
}

// ---------------- bucket scan: boff (exclusive) + cursor init -------------
__global__ __launch_bounds__(256) void k_bscan(const int* __restrict__ gbcnt,
                                               int* __restrict__ boff,
                                               int* __restrict__ gcur) {
    __shared__ int s[256];
    int t = threadIdx.x;
    int v = (t < NBUCK) ? gbcnt[t] : 0;
    s[t] = v;
    __syncthreads();
    for (int off = 1; off < 256; off <<= 1) {
        int add = (t >= off) ? s[t - off] : 0;
        __syncthreads();
        s[t] += add;
        __syncthreads();
    }
    if (t < NBUCK) {
        int ex = s[t] - v;
        boff[t] = ex;
        gcur[t] = ex;
    }
    if (t == NBUCK - 1) boff[NBUCK] = s[t];  // = NE
}

// ---------------- scatter edges into bucket regions (run-staged) ----------
// 256 blocks x 6250 edges (NE = 256*6250 exactly)
__global__ __launch_bounds__(256) void k_bscatter(const int* __restrict__ ei,
                                                  const float* __restrict__ ew,
                                                  int* __restrict__ gcur,
                                                  int2* __restrict__ srcw,
                                                  int* __restrict__ dstb) {
    __shared__ int hist[NBUCK], base[NBUCK], cur[NBUCK];
    const int tid = threadIdx.x;
    const int e0 = blockIdx.x * 6250, e1 = e0 + 6250;
    if (tid < NBUCK) hist[tid] = 0;
    __syncthreads();
    for (int e = e0 + tid; e < e1; e += 256)
        atomicAdd(&hist[ei[NE + e] >> 9], 1);
    __syncthreads();
    if (tid < NBUCK) {
        base[tid] = atomicAdd(&gcur[tid], hist[tid]);
        cur[tid] = 0;
    }
    __syncthreads();
    for (int e = e0 + tid; e < e1; e += 256) {
        int d = ei[NE + e];
        int b = d >> 9;
        int p = base[b] + atomicAdd(&cur[b], 1);
        int2 sw;
        sw.x = ei[e];
        sw.y = __float_as_int(ew[e]);
        srcw[p] = sw;
        dstb[p] = d;
    }
}

// ---------------- per-bucket counting sort -> CSR + row_off ---------------
// one block per bucket; all position atomics in LDS; CSR writes L2-local
__global__ __launch_bounds__(256) void k_bsort(const int2* __restrict__ srcw,
                                               const int* __restrict__ dstb,
                                               const int* __restrict__ boff,
                                               int* __restrict__ row_off,
                                               int2* __restrict__ csr) {
    __shared__ int h0[512], h1[512], exc[512], cur[512];
    const int tid = threadIdx.x;
    const int b = blockIdx.x;
    const int p0 = boff[b], p1 = boff[b + 1];
    const int nbn = min(512, NN - (b << 9));

    for (int i = tid; i < 512; i += 256) h0[i] = 0;
    __syncthreads();
    for (int p = p0 + tid; p < p1; p += 256)
        atomicAdd(&h0[dstb[p] & 511], 1);
    __syncthreads();

    int* sA = h0;
    int* sB = h1;
    for (int off = 1; off < 512; off <<= 1) {
        for (int i = tid; i < 512; i += 256) {
            int v = sA[i];
            if (i >= off) v += sA[i - off];
            sB[i] = v;
        }
        __syncthreads();
        int* tp = sA; sA = sB; sB = tp;
    }
    // sA = inclusive scan
    for (int i = tid; i < 512; i += 256) {
        exc[i] = (i == 0) ? 0 : sA[i - 1];
        cur[i] = 0;
    }
    __syncthreads();

    for (int n = tid; n < nbn; n += 256)
        row_off[(b << 9) + n] = p0 + exc[n];
    if (b == NBUCK - 1 && tid == 0) row_off[NN] = NE;

    for (int p = p0 + tid; p < p1; p += 256) {
        int dl = dstb[p] & 511;
        int2 sw = srcw[p];
        int q = p0 + exc[dl] + atomicAdd(&cur[dl], 1);
        csr[q] = sw;
    }
}

// deg[node] = 1 + sum of row's ew (contiguous, no atomics); dinv = rsqrt
__global__ __launch_bounds__(256) void k_degdinv(const int2* __restrict__ csr,
                                                 const int* __restrict__ row_off,
                                                 float* __restrict__ dinv) {
    int node = blockIdx.x * 256 + threadIdx.x;
    if (node >= NN) return;
    int beg = row_off[node], end = row_off[node + 1];
    float s = 1.0f;  // self-loop
    for (int j = beg; j < end; ++j) s += __int_as_float(csr[j].y);
    dinv[node] = rsqrtf(s);  // s >= 1 > 0 always
}

// csr[j].y <- dinv[dst] * ew * dinv[src]  (in place)
__global__ __launch_bounds__(256) void k_nrm2(int2* __restrict__ csr,
                                              const int* __restrict__ row_off,
                                              const float* __restrict__ dinv) {
    int node = blockIdx.x * 256 + threadIdx.x;
    if (node >= NN) return;
    int beg = row_off[node], end = row_off[node + 1];
    float dv = dinv[node];
    int* y = (int*)csr;
    for (int j = beg; j < end; ++j) {
        int2 e = csr[j];
        float nw = dv * __int_as_float(e.y) * dinv[e.x];
        y[2 * (size_t)j + 1] = __float_as_int(nw);
    }
}

// ---------------- W prep: fp32 [k][n] -> bf16 [n][k], all 3 layers ----------
__global__ __launch_bounds__(256) void k_wprep(const float* __restrict__ W,
                                               ushort* __restrict__ Wt) {
    int idx = blockIdx.x * 256 + threadIdx.x;   // 0 .. 3*16384
    if (idx < NL * DD * DD) {
        int l = idx >> 14, i = idx & 16383;
        int k = i >> 7, n = i & 127;
        Wt[(size_t)l * DD * DD + n * DD + k] = f2bf(W[idx]);
    }
}

// ---------------- MFMA GEMM: H = act(X) @ W, bf16 in/out, fp32 accum -------
__global__ __launch_bounds__(256, 2) void k_gemm3(const float* __restrict__ X,
                                                  const ushort* __restrict__ Wt,
                                                  const float* __restrict__ sc,
                                                  const float* __restrict__ sh,
                                                  int applyBN,
                                                  ushort* __restrict__ H) {
    __shared__ ushort xs[128 * 128];   // [row][k] bf16, swizzled
    __shared__ ushort ws[128 * 128];   // [n][k]  bf16, swizzled
    const int tid = threadIdx.x;
    const int row0 = blockIdx.x * 128;

    for (int c = tid; c < 2048; c += 256) {
        int r = c >> 4, k8 = (c & 15) * 8;
        int gr = row0 + r;
        float v[8];
        if (gr < NN) {
            float4 a = *(const float4*)&X[(size_t)gr * DD + k8];
            float4 b = *(const float4*)&X[(size_t)gr * DD + k8 + 4];
            v[0] = a.x; v[1] = a.y; v[2] = a.z; v[3] = a.w;
            v[4] = b.x; v[5] = b.y; v[6] = b.z; v[7] = b.w;
        } else {
#pragma unroll
            for (int i = 0; i < 8; ++i) v[i] = 0.f;
        }
        if (applyBN) {
#pragma unroll
            for (int i = 0; i < 8; ++i)
                v[i] = fmaxf(fmaf(v[i], sc[k8 + i], sh[k8 + i]), 0.f);
        }
        uint4 st;
        st.x = (uint)f2bf(v[0]) | ((uint)f2bf(v[1]) << 16);
        st.y = (uint)f2bf(v[2]) | ((uint)f2bf(v[3]) << 16);
        st.z = (uint)f2bf(v[4]) | ((uint)f2bf(v[5]) << 16);
        st.w = (uint)f2bf(v[6]) | ((uint)f2bf(v[7]) << 16);
        int idx = r * 128 + (((k8 * 2) ^ ((r & 7) << 4)) >> 1);
        *(uint4*)&xs[idx] = st;
    }
    for (int c = tid; c < 2048; c += 256) {
        int n = c >> 4, k8 = (c & 15) * 8;
        uint4 w = *(const uint4*)&Wt[n * DD + k8];
        int idx = n * 128 + (((k8 * 2) ^ ((n & 7) << 4)) >> 1);
        *(uint4*)&ws[idx] = w;
    }
    __syncthreads();

    const int wid = tid >> 6, lane = tid & 63;
    const int wm = wid >> 1, wn = wid & 1;       // 2x2 waves of 64x64
    const int lrow = lane & 15, lk = lane >> 4;
    float4v acc[4][4];
#pragma unroll
    for (int i = 0; i < 4; ++i)
#pragma unroll
        for (int j = 0; j < 4; ++j) acc[i][j] = (float4v){0.f, 0.f, 0.f, 0.f};

#pragma unroll
    for (int ks = 0; ks < 4; ++ks) {
        int kbyte = ks * 64 + lk * 16;
        short8v a[4], b[4];
#pragma unroll
        for (int mg = 0; mg < 4; ++mg) {
            int r = wm * 64 + mg * 16 + lrow;
            a[mg] = *(const short8v*)&xs[r * 128 + ((kbyte ^ ((r & 7) << 4)) >> 1)];
        }
#pragma unroll
        for (int ng = 0; ng < 4; ++ng) {
            int n = wn * 64 + ng * 16 + lrow;
            b[ng] = *(const short8v*)&ws[n * 128 + ((kbyte ^ ((n & 7) << 4)) >> 1)];
        }
#pragma unroll
        for (int mg = 0; mg < 4; ++mg)
#pragma unroll
            for (int ng = 0; ng < 4; ++ng)
                acc[mg][ng] = __builtin_amdgcn_mfma_f32_16x16x32_bf16(
                    a[mg], b[ng], acc[mg][ng], 0, 0, 0);
    }

    // C/D layout: col = lane&15, row = (lane>>4)*4 + reg  [m89]
#pragma unroll
    for (int mg = 0; mg < 4; ++mg) {
        int rbase = row0 + wm * 64 + mg * 16 + lk * 4;
#pragma unroll
        for (int j = 0; j < 4; ++j) {
            int gr = rbase + j;
            if (gr < NN) {
#pragma unroll
                for (int ng = 0; ng < 4; ++ng) {
                    int col = wn * 64 + ng * 16 + lrow;
                    H[(size_t)gr * DD + col] = f2bf(acc[mg][ng][j]);
                }
            }
        }
    }
}

// ---------------- aggregation + fused BN partial stats --------------------
// 16 lanes/node, 8 cols/lane; epilogue reduces block's 16 nodes -> partial
__global__ __launch_bounds__(256) void k_agg3(const int2* __restrict__ csr,
                                              const int* __restrict__ row_off,
                                              const float* __restrict__ dinv,
                                              const ushort* __restrict__ H,
                                              float* __restrict__ A,
                                              float* __restrict__ partial) {
    __shared__ float sbv[16][128];
    __shared__ float sbq[16][128];
    const int tid = threadIdx.x;
    int node = blockIdx.x * 16 + (tid >> 4);
    int h = tid & 15;
    int beg = row_off[node], end = row_off[node + 1];
    float dv = dinv[node];
    size_t cb = (size_t)node * DD + h * 8;   // ushort index
    float acc[8];
    {
        uint4 v = *(const uint4*)&H[cb];
        float sl = dv * dv;
        acc[0] = sl * __uint_as_float(v.x << 16);
        acc[1] = sl * __uint_as_float(v.x & 0xffff0000u);
        acc[2] = sl * __uint_as_float(v.y << 16);
        acc[3] = sl * __uint_as_float(v.y & 0xffff0000u);
        acc[4] = sl * __uint_as_float(v.z << 16);
        acc[5] = sl * __uint_as_float(v.z & 0xffff0000u);
        acc[6] = sl * __uint_as_float(v.w << 16);
        acc[7] = sl * __uint_as_float(v.w & 0xffff0000u);
    }

    int j = beg;
    for (; j + 4 <= end; j += 4) {
        int2 e0 = csr[j], e1 = csr[j + 1], e2 = csr[j + 2], e3 = csr[j + 3];
        uint4 g0 = *(const uint4*)&H[(size_t)e0.x * DD + h * 8];
        uint4 g1 = *(const uint4*)&H[(size_t)e1.x * DD + h * 8];
        uint4 g2 = *(const uint4*)&H[(size_t)e2.x * DD + h * 8];
        uint4 g3 = *(const uint4*)&H[(size_t)e3.x * DD + h * 8];
        acc8(acc, g0, __int_as_float(e0.y));
        acc8(acc, g1, __int_as_float(e1.y));
        acc8(acc, g2, __int_as_float(e2.y));
        acc8(acc, g3, __int_as_float(e3.y));
    }
    for (; j < end; ++j) {
        int2 e = csr[j];
        uint4 g = *(const uint4*)&H[(size_t)e.x * DD + h * 8];
        acc8(acc, g, __int_as_float(e.y));
    }

    size_t ab = (size_t)node * DD + h * 8;
    *(float4*)&A[ab] = make_float4(acc[0], acc[1], acc[2], acc[3]);
    *(float4*)&A[ab + 4] = make_float4(acc[4], acc[5], acc[6], acc[7]);

    // fused BN partial stats: block-level column sums of value and square
    int n = tid >> 4, c0 = h * 8;
#pragma unroll
    for (int i = 0; i < 8; ++i) {
        float a = acc[i];
        sbv[n][c0 + i] = a;
        sbq[n][c0 + i] = a * a;
    }
    __syncthreads();
    float s = 0.f;
    if (tid < 128) {
#pragma unroll
        for (int k = 0; k < 16; ++k) s += sbv[k][tid];
    } else {
        int c = tid - 128;
#pragma unroll
        for (int k = 0; k < 16; ++k) s += sbq[k][c];
    }
    partial[(size_t)blockIdx.x * 256 + tid] = s;
}

// ---------------- reduce partials -> stats (low-contention atomics) -------
__global__ __launch_bounds__(256) void k_bn_red(const float* __restrict__ partial,
                                                float* __restrict__ stats) {
    int r0 = blockIdx.x * 25;
    int r1 = min(r0 + 25, NAGG);
    int t = threadIdx.x;
    float s = 0.f;
    for (int r = r0; r < r1; ++r) s += partial[(size_t)r * 256 + t];
    atomAddF(&stats[t], s);
}

__global__ void k_bn_final(const float* __restrict__ stats,
                           const float* __restrict__ gamma,
                           const float* __restrict__ beta,
                           float* __restrict__ sc, float* __restrict__ sh) {
    int c = threadIdx.x;
    if (c < DD) {
        float mu = stats[c] * (1.0f / NN);
        float var = stats[DD + c] * (1.0f / NN) - mu * mu;
        float inv = rsqrtf(var + EPSBN);
        float s = gamma[c] * inv;
        sc[c] = s;
        sh[c] = beta[c] - mu * s;  // conv bias b cancels in BN exactly
    }
}

// ---------------- pooling (fused final BN+ReLU) ----------------
__global__ __launch_bounds__(256) void k_pool(const float* __restrict__ A,
                                              const int* __restrict__ batch,
                                              const float* __restrict__ sc,
                                              const float* __restrict__ sh,
                                              float* __restrict__ out) {
    const int tid = threadIdx.x;
    const int col = tid & 127, half = tid >> 7;
    const float s = sc[col], t = sh[col];
    int v0 = blockIdx.x * 196;
    int v1 = v0 + 196;
    if (v1 > NN) v1 = NN;
    float acc = 0.f;
    int g = -1;
    for (int v = v0 + half; v < v1; v += 2) {
        int bg = batch[v];
        if (bg != g) {
            if (g >= 0) atomAddF(&out[(size_t)g * DD + col], acc);
            g = bg;
            acc = 0.f;
        }
        acc += fmaxf(fmaf(A[(size_t)v * DD + col], s, t), 0.f);
    }
    if (g >= 0) atomAddF(&out[(size_t)g * DD + col], acc);
}

extern "C" void kernel_launch(void* const* d_in, const int* in_sizes, int n_in,
                              void* d_out, int out_size, void* d_ws, size_t ws_size,
                              hipStream_t stream) {
    const float* x     = (const float*)d_in[0];
    const int*   ei    = (const int*)d_in[1];
    const float* ew    = (const float*)d_in[2];
    const int*   batch = (const int*)d_in[3];
    const float* W     = (const float*)d_in[4];
    // d_in[5] = b — cancels exactly in training-mode BatchNorm, unused
    const float* gamma = (const float*)d_in[6];
    const float* beta  = (const float*)d_in[7];
    float* out = (float*)d_out;

    float* wsp   = (float*)d_ws;
    float* dinv  = wsp;                            // N
    float* stats = dinv + NN;                      // 768
    float* scl   = stats + 768;                    // 3 x 128
    float* shl   = scl + 3 * DD;                   // 3 x 128
    ushort* Wt   = (ushort*)(shl + 3 * DD);        // 3 x D x D bf16
    ushort* H    = Wt + (size_t)NL * DD * DD;      // N*D bf16
    float* A     = (float*)(H + (size_t)NN * DD);  // N*D fp32
    int2*  srcw  = (int2*)(A + (size_t)NN * DD);   // E records {src, ew}
    int*   dstb  = (int*)(srcw + NE);              // E dst
    float* partial = (float*)(dstb + NE);          // NAGG x 256
    int*   row_off = (int*)(partial + (size_t)NAGG * 256);  // N+4
    int*   gbcnt = row_off + NN + 4;               // NBUCK
    int*   boff  = gbcnt + NBUCK;                  // NBUCK+1 (+pad)
    int*   gcur  = boff + NBUCK + 3;               // NBUCK (keeps csr 8B-aligned)
    int2*  csr   = (int2*)(gcur + NBUCK);          // E * 8B
    // total ≈ 116 MiB

    k_zero_fo<<<(NG * DD + 768 + NBUCK + 255) / 256, 256, 0, stream>>>(out, stats, gbcnt);

    // bucket-staged CSR build
    k_bcnt<<<256, 256, 0, stream>>>(ei, gbcnt);
    k_bscan<<<1, 256, 0, stream>>>(gbcnt, boff, gcur);
    k_bscatter<<<256, 256, 0, stream>>>(ei, ew, gcur, srcw, dstb);
    k_bsort<<<NBUCK, 256, 0, stream>>>(srcw, dstb, boff, row_off, csr);

    // degrees + norms from CSR (atomic-free)
    k_degdinv<<<(NN + 255) / 256, 256, 0, stream>>>(csr, row_off, dinv);
    k_nrm2<<<(NN + 255) / 256, 256, 0, stream>>>(csr, row_off, dinv);

    // W -> bf16 transposed [n][k]
    k_wprep<<<(NL * DD * DD + 255) / 256, 256, 0, stream>>>(W, Wt);

    const float* xcur = x;
    for (int l = 0; l < NL; ++l) {
        const float* sc_prev = (l > 0) ? scl + (l - 1) * DD : scl;
        const float* sh_prev = (l > 0) ? shl + (l - 1) * DD : shl;
        k_gemm3<<<(NN + 127) / 128, 256, 0, stream>>>(
            xcur, Wt + (size_t)l * DD * DD, sc_prev, sh_prev, l > 0 ? 1 : 0, H);
        k_agg3<<<NAGG, 256, 0, stream>>>(csr, row_off, dinv, H, A, partial);
        k_bn_red<<<(NAGG + 24) / 25, 256, 0, stream>>>(partial, stats + l * 256);
        k_bn_final<<<1, 128, 0, stream>>>(stats + l * 256, gamma + (size_t)l * DD,
                                          beta + (size_t)l * DD,
                                          scl + l * DD, shl + l * DD);
        xcur = A;
    }

    k_pool<<<512, 256, 0, stream>>>(A, batch, scl + 2 * DD, shl + 2 * DD, out);
}

// Round 11
// 444.094 us; speedup vs baseline: 19.5775x; 1.0319x over previous
//
#include <hip/hip_runtime.h>

#define NN 100000   // nodes
#define NE 1600000  // edges
#define DD 128      // feature dim
#define NL 3        // layers
#define NG 64       // graphs
#define EPSBN 1e-5f
#define NBUCK 196               // ceil(NN/512) buckets of 512 nodes
#define NAGG (NN / 16)          // 6250 agg blocks (16 nodes each)

typedef __attribute__((ext_vector_type(8))) short short8v;   // 8 bf16 (4 VGPR)
typedef __attribute__((ext_vector_type(4))) float float4v;   // MFMA C/D

// ---- fp32 atomic add (HW global_atomic_add_f32, no CAS loop) ----
__device__ inline void atomAddF(float* p, float v) {
#if defined(__AMDGCN__)
    unsafeAtomicAdd(p, v);
#else
    atomicAdd(p, v);
#endif
}

// ---- fp32 -> bf16 round-to-nearest-even ----
__device__ inline ushort f2bf(float f) {
    uint u = __float_as_uint(f);
    uint r = ((u >> 16) & 1u) + 0x7fffu;
    return (ushort)((u + r) >> 16);
}

// ---- accumulate 8 bf16 lanes (packed in uint4) scaled by w into acc[8] ----
__device__ inline void acc8(float (&acc)[8], uint4 g, float wgt) {
    acc[0] = fmaf(wgt, __uint_as_float(g.x << 16), acc[0]);
    acc[1] = fmaf(wgt, __uint_as_float(g.x & 0xffff0000u), acc[1]);
    acc[2] = fmaf(wgt, __uint_as_float(g.y << 16), acc[2]);
    acc[3] = fmaf(wgt, __uint_as_float(g.y & 0xffff0000u), acc[3]);
    acc[4] = fmaf(wgt, __uint_as_float(g.z << 16), acc[4]);
    acc[5] = fmaf(wgt, __uint_as_float(g.z & 0xffff0000u), acc[5]);
    acc[6] = fmaf(wgt, __uint_as_float(g.w << 16), acc[6]);
    acc[7] = fmaf(wgt, __uint_as_float(g.w & 0xffff0000u), acc[7]);
}

// ---------------- init: out, stats, bucket counters ----------------
__global__ __launch_bounds__(256) void k_zero_fo(float* __restrict__ out,
                                                 float* __restrict__ stats,
                                                 int* __restrict__ gbcnt) {
    int i = blockIdx.x * 256 + threadIdx.x;
    if (i < NG * DD) out[i] = 0.f;
    int j = i - NG * DD;
    if (j >= 0 && j < 768) stats[j] = 0.f;
    int k = j - 768;
    if (k >= 0 && k < NBUCK) gbcnt[k] = 0;
}

// ---------------- bucket histogram over dst ----------------
__global__ __launch_bounds__(256) void k_bcnt(const int* __restrict__ ei,
                                              int* __restrict__ gbcnt) {
    __shared__ int lh[NBUCK];
    int tid = threadIdx.x;
    if (tid < NBUCK) lh[tid] = 0;
    __syncthreads();
    for (int e = blockIdx.x * 256 + tid; e < NE; e += 256 * 256)
        atomicAdd(&lh[ei[NE + e] >> 9], 1);
    __syncthreads();
    if (tid < NBUCK) atomicAdd(&gbcnt[tid], lh[tid]);
}

// ---------------- bucket scan: boff (exclusive) + cursor init -------------
__global__ __launch_bounds__(256) void k_bscan(const int* __restrict__ gbcnt,
                                               int* __restrict__ boff,
                                               int* __restrict__ gcur) {
    __shared__ int s[256];
    int t = threadIdx.x;
    int v = (t < NBUCK) ? gbcnt[t] : 0;
    s[t] = v;
    __syncthreads();
    for (int off = 1; off < 256; off <<= 1) {
        int add = (t >= off) ? s[t - off] : 0;
        __syncthreads();
        s[t] += add;
        __syncthreads();
    }
    if (t < NBUCK) {
        int ex = s[t] - v;
        boff[t] = ex;
        gcur[t] = ex;
    }
    if (t == NBUCK - 1) boff[NBUCK] = s[t];  // = NE
}

// ---------------- scatter edges into bucket regions (run-staged) ----------
// 256 blocks x 6250 edges; record packs src (17b) | dst-local (9b) + ew
__global__ __launch_bounds__(256) void k_bscatter(const int* __restrict__ ei,
                                                  const float* __restrict__ ew,
                                                  int* __restrict__ gcur,
                                                  int2* __restrict__ srcw) {
    __shared__ int hist[NBUCK], base[NBUCK], cur[NBUCK];
    const int tid = threadIdx.x;
    const int e0 = blockIdx.x * 6250, e1 = e0 + 6250;
    if (tid < NBUCK) hist[tid] = 0;
    __syncthreads();
    for (int e = e0 + tid; e < e1; e += 256)
        atomicAdd(&hist[ei[NE + e] >> 9], 1);
    __syncthreads();
    if (tid < NBUCK) {
        base[tid] = atomicAdd(&gcur[tid], hist[tid]);
        cur[tid] = 0;
    }
    __syncthreads();
    for (int e = e0 + tid; e < e1; e += 256) {
        int d = ei[NE + e];
        int b = d >> 9;
        int p = base[b] + atomicAdd(&cur[b], 1);
        int2 sw;
        sw.x = ei[e] | ((d & 511) << 17);
        sw.y = __float_as_int(ew[e]);
        srcw[p] = sw;
    }
}

// ---------------- per-bucket counting sort -> CSR + row_off ---------------
__global__ __launch_bounds__(256) void k_bsort(const int2* __restrict__ srcw,
                                               const int* __restrict__ boff,
                                               int* __restrict__ row_off,
                                               int2* __restrict__ csr) {
    __shared__ int h0[512], h1[512], exc[512], cur[512];
    const int tid = threadIdx.x;
    const int b = blockIdx.x;
    const int p0 = boff[b], p1 = boff[b + 1];
    const int nbn = min(512, NN - (b << 9));

    for (int i = tid; i < 512; i += 256) h0[i] = 0;
    __syncthreads();
    for (int p = p0 + tid; p < p1; p += 256)
        atomicAdd(&h0[(srcw[p].x >> 17) & 511], 1);
    __syncthreads();

    int* sA = h0;
    int* sB = h1;
    for (int off = 1; off < 512; off <<= 1) {
        for (int i = tid; i < 512; i += 256) {
            int v = sA[i];
            if (i >= off) v += sA[i - off];
            sB[i] = v;
        }
        __syncthreads();
        int* tp = sA; sA = sB; sB = tp;
    }
    for (int i = tid; i < 512; i += 256) {
        exc[i] = (i == 0) ? 0 : sA[i - 1];
        cur[i] = 0;
    }
    __syncthreads();

    for (int n = tid; n < nbn; n += 256)
        row_off[(b << 9) + n] = p0 + exc[n];
    if (b == NBUCK - 1 && tid == 0) row_off[NN] = NE;

    for (int p = p0 + tid; p < p1; p += 256) {
        int2 sw = srcw[p];
        int dl = (sw.x >> 17) & 511;
        int q = p0 + exc[dl] + atomicAdd(&cur[dl], 1);
        int2 outv;
        outv.x = sw.x & 0x1FFFF;   // clean src
        outv.y = sw.y;             // raw ew
        csr[q] = outv;
    }
}

// deg[node] = 1 + sum of row's ew (contiguous, no atomics); dinv = rsqrt
__global__ __launch_bounds__(256) void k_degdinv(const int2* __restrict__ csr,
                                                 const int* __restrict__ row_off,
                                                 float* __restrict__ dinv) {
    int node = blockIdx.x * 256 + threadIdx.x;
    if (node >= NN) return;
    int beg = row_off[node], end = row_off[node + 1];
    float s = 1.0f;  // self-loop
    for (int j = beg; j < end; ++j) s += __int_as_float(csr[j].y);
    dinv[node] = rsqrtf(s);  // s >= 1 > 0 always
}

// csr[j].y <- dinv[dst] * ew * dinv[src]  (in place)
__global__ __launch_bounds__(256) void k_nrm2(int2* __restrict__ csr,
                                              const int* __restrict__ row_off,
                                              const float* __restrict__ dinv) {
    int node = blockIdx.x * 256 + threadIdx.x;
    if (node >= NN) return;
    int beg = row_off[node], end = row_off[node + 1];
    float dv = dinv[node];
    int* y = (int*)csr;
    for (int j = beg; j < end; ++j) {
        int2 e = csr[j];
        float nw = dv * __int_as_float(e.y) * dinv[e.x];
        y[2 * (size_t)j + 1] = __float_as_int(nw);
    }
}

// ---------------- W prep: fp32 [k][n] -> bf16 [n][k], all 3 layers ----------
__global__ __launch_bounds__(256) void k_wprep(const float* __restrict__ W,
                                               ushort* __restrict__ Wt) {
    int idx = blockIdx.x * 256 + threadIdx.x;   // 0 .. 3*16384
    if (idx < NL * DD * DD) {
        int l = idx >> 14, i = idx & 16383;
        int k = i >> 7, n = i & 127;
        Wt[(size_t)l * DD * DD + n * DD + k] = f2bf(W[idx]);
    }
}

// ---------------- MFMA GEMM: H = act(X) @ W, bf16 in/out, fp32 accum -------
// Layer 0: X fp32, no BN. Layers 1+: Xb bf16 with fused BN+ReLU.
__global__ __launch_bounds__(256, 2) void k_gemm3(const float* __restrict__ X,
                                                  const ushort* __restrict__ Xb,
                                                  const ushort* __restrict__ Wt,
                                                  const float* __restrict__ sc,
                                                  const float* __restrict__ sh,
                                                  int applyBN,
                                                  ushort* __restrict__ H) {
    __shared__ ushort xs[128 * 128];   // [row][k] bf16, swizzled
    __shared__ ushort ws[128 * 128];   // [n][k]  bf16, swizzled
    const int tid = threadIdx.x;
    const int row0 = blockIdx.x * 128;

    for (int c = tid; c < 2048; c += 256) {
        int r = c >> 4, k8 = (c & 15) * 8;
        int gr = row0 + r;
        float v[8];
        if (applyBN) {
            uint4 g = (gr < NN) ? *(const uint4*)&Xb[(size_t)gr * DD + k8]
                                : make_uint4(0u, 0u, 0u, 0u);
            v[0] = __uint_as_float(g.x << 16);
            v[1] = __uint_as_float(g.x & 0xffff0000u);
            v[2] = __uint_as_float(g.y << 16);
            v[3] = __uint_as_float(g.y & 0xffff0000u);
            v[4] = __uint_as_float(g.z << 16);
            v[5] = __uint_as_float(g.z & 0xffff0000u);
            v[6] = __uint_as_float(g.w << 16);
            v[7] = __uint_as_float(g.w & 0xffff0000u);
#pragma unroll
            for (int i = 0; i < 8; ++i)
                v[i] = fmaxf(fmaf(v[i], sc[k8 + i], sh[k8 + i]), 0.f);
        } else {
            if (gr < NN) {
                float4 a = *(const float4*)&X[(size_t)gr * DD + k8];
                float4 b = *(const float4*)&X[(size_t)gr * DD + k8 + 4];
                v[0] = a.x; v[1] = a.y; v[2] = a.z; v[3] = a.w;
                v[4] = b.x; v[5] = b.y; v[6] = b.z; v[7] = b.w;
            } else {
#pragma unroll
                for (int i = 0; i < 8; ++i) v[i] = 0.f;
            }
        }
        uint4 st;
        st.x = (uint)f2bf(v[0]) | ((uint)f2bf(v[1]) << 16);
        st.y = (uint)f2bf(v[2]) | ((uint)f2bf(v[3]) << 16);
        st.z = (uint)f2bf(v[4]) | ((uint)f2bf(v[5]) << 16);
        st.w = (uint)f2bf(v[6]) | ((uint)f2bf(v[7]) << 16);
        int idx = r * 128 + (((k8 * 2) ^ ((r & 7) << 4)) >> 1);
        *(uint4*)&xs[idx] = st;
    }
    for (int c = tid; c < 2048; c += 256) {
        int n = c >> 4, k8 = (c & 15) * 8;
        uint4 w = *(const uint4*)&Wt[n * DD + k8];
        int idx = n * 128 + (((k8 * 2) ^ ((n & 7) << 4)) >> 1);
        *(uint4*)&ws[idx] = w;
    }
    __syncthreads();

    const int wid = tid >> 6, lane = tid & 63;
    const int wm = wid >> 1, wn = wid & 1;       // 2x2 waves of 64x64
    const int lrow = lane & 15, lk = lane >> 4;
    float4v acc[4][4];
#pragma unroll
    for (int i = 0; i < 4; ++i)
#pragma unroll
        for (int j = 0; j < 4; ++j) acc[i][j] = (float4v){0.f, 0.f, 0.f, 0.f};

#pragma unroll
    for (int ks = 0; ks < 4; ++ks) {
        int kbyte = ks * 64 + lk * 16;
        short8v a[4], b[4];
#pragma unroll
        for (int mg = 0; mg < 4; ++mg) {
            int r = wm * 64 + mg * 16 + lrow;
            a[mg] = *(const short8v*)&xs[r * 128 + ((kbyte ^ ((r & 7) << 4)) >> 1)];
        }
#pragma unroll
        for (int ng = 0; ng < 4; ++ng) {
            int n = wn * 64 + ng * 16 + lrow;
            b[ng] = *(const short8v*)&ws[n * 128 + ((kbyte ^ ((n & 7) << 4)) >> 1)];
        }
#pragma unroll
        for (int mg = 0; mg < 4; ++mg)
#pragma unroll
            for (int ng = 0; ng < 4; ++ng)
                acc[mg][ng] = __builtin_amdgcn_mfma_f32_16x16x32_bf16(
                    a[mg], b[ng], acc[mg][ng], 0, 0, 0);
    }

    // C/D layout: col = lane&15, row = (lane>>4)*4 + reg  [m89]
#pragma unroll
    for (int mg = 0; mg < 4; ++mg) {
        int rbase = row0 + wm * 64 + mg * 16 + lk * 4;
#pragma unroll
        for (int j = 0; j < 4; ++j) {
            int gr = rbase + j;
            if (gr < NN) {
#pragma unroll
                for (int ng = 0; ng < 4; ++ng) {
                    int col = wn * 64 + ng * 16 + lrow;
                    H[(size_t)gr * DD + col] = f2bf(acc[mg][ng][j]);
                }
            }
        }
    }
}

// ---------------- aggregation + fused BN partial stats --------------------
// 16 lanes/node, 8 cols/lane; unroll 8; A written bf16
__global__ __launch_bounds__(256) void k_agg3(const int2* __restrict__ csr,
                                              const int* __restrict__ row_off,
                                              const float* __restrict__ dinv,
                                              const ushort* __restrict__ H,
                                              ushort* __restrict__ Ab,
                                              float* __restrict__ partial) {
    __shared__ float sbv[16][128];
    __shared__ float sbq[16][128];
    const int tid = threadIdx.x;
    int node = blockIdx.x * 16 + (tid >> 4);
    int h = tid & 15;
    int beg = row_off[node], end = row_off[node + 1];
    float dv = dinv[node];
    size_t cb = (size_t)node * DD + h * 8;   // ushort index
    float acc[8];
    {
        uint4 v = *(const uint4*)&H[cb];
        float sl = dv * dv;
        acc[0] = sl * __uint_as_float(v.x << 16);
        acc[1] = sl * __uint_as_float(v.x & 0xffff0000u);
        acc[2] = sl * __uint_as_float(v.y << 16);
        acc[3] = sl * __uint_as_float(v.y & 0xffff0000u);
        acc[4] = sl * __uint_as_float(v.z << 16);
        acc[5] = sl * __uint_as_float(v.z & 0xffff0000u);
        acc[6] = sl * __uint_as_float(v.w << 16);
        acc[7] = sl * __uint_as_float(v.w & 0xffff0000u);
    }

    int j = beg;
    for (; j + 8 <= end; j += 8) {
        int2 e0 = csr[j], e1 = csr[j + 1], e2 = csr[j + 2], e3 = csr[j + 3];
        int2 e4 = csr[j + 4], e5 = csr[j + 5], e6 = csr[j + 6], e7 = csr[j + 7];
        uint4 g0 = *(const uint4*)&H[(size_t)e0.x * DD + h * 8];
        uint4 g1 = *(const uint4*)&H[(size_t)e1.x * DD + h * 8];
        uint4 g2 = *(const uint4*)&H[(size_t)e2.x * DD + h * 8];
        uint4 g3 = *(const uint4*)&H[(size_t)e3.x * DD + h * 8];
        uint4 g4 = *(const uint4*)&H[(size_t)e4.x * DD + h * 8];
        uint4 g5 = *(const uint4*)&H[(size_t)e5.x * DD + h * 8];
        uint4 g6 = *(const uint4*)&H[(size_t)e6.x * DD + h * 8];
        uint4 g7 = *(const uint4*)&H[(size_t)e7.x * DD + h * 8];
        acc8(acc, g0, __int_as_float(e0.y));
        acc8(acc, g1, __int_as_float(e1.y));
        acc8(acc, g2, __int_as_float(e2.y));
        acc8(acc, g3, __int_as_float(e3.y));
        acc8(acc, g4, __int_as_float(e4.y));
        acc8(acc, g5, __int_as_float(e5.y));
        acc8(acc, g6, __int_as_float(e6.y));
        acc8(acc, g7, __int_as_float(e7.y));
    }
    for (; j + 4 <= end; j += 4) {
        int2 e0 = csr[j], e1 = csr[j + 1], e2 = csr[j + 2], e3 = csr[j + 3];
        uint4 g0 = *(const uint4*)&H[(size_t)e0.x * DD + h * 8];
        uint4 g1 = *(const uint4*)&H[(size_t)e1.x * DD + h * 8];
        uint4 g2 = *(const uint4*)&H[(size_t)e2.x * DD + h * 8];
        uint4 g3 = *(const uint4*)&H[(size_t)e3.x * DD + h * 8];
        acc8(acc, g0, __int_as_float(e0.y));
        acc8(acc, g1, __int_as_float(e1.y));
        acc8(acc, g2, __int_as_float(e2.y));
        acc8(acc, g3, __int_as_float(e3.y));
    }
    for (; j < end; ++j) {
        int2 e = csr[j];
        uint4 g = *(const uint4*)&H[(size_t)e.x * DD + h * 8];
        acc8(acc, g, __int_as_float(e.y));
    }

    // write A in bf16
    uint4 st;
    st.x = (uint)f2bf(acc[0]) | ((uint)f2bf(acc[1]) << 16);
    st.y = (uint)f2bf(acc[2]) | ((uint)f2bf(acc[3]) << 16);
    st.z = (uint)f2bf(acc[4]) | ((uint)f2bf(acc[5]) << 16);
    st.w = (uint)f2bf(acc[6]) | ((uint)f2bf(acc[7]) << 16);
    *(uint4*)&Ab[cb] = st;

    // fused BN partial stats from fp32 accumulators
    int n = tid >> 4, c0 = h * 8;
#pragma unroll
    for (int i = 0; i < 8; ++i) {
        float a = acc[i];
        sbv[n][c0 + i] = a;
        sbq[n][c0 + i] = a * a;
    }
    __syncthreads();
    float s = 0.f;
    if (tid < 128) {
#pragma unroll
        for (int k = 0; k < 16; ++k) s += sbv[k][tid];
    } else {
        int c = tid - 128;
#pragma unroll
        for (int k = 0; k < 16; ++k) s += sbq[k][c];
    }
    partial[(size_t)blockIdx.x * 256 + tid] = s;
}

// ---------------- reduce partials -> stats (low-contention atomics) -------
__global__ __launch_bounds__(256) void k_bn_red(const float* __restrict__ partial,
                                                float* __restrict__ stats) {
    int r0 = blockIdx.x * 25;
    int r1 = min(r0 + 25, NAGG);
    int t = threadIdx.x;
    float s = 0.f;
    for (int r = r0; r < r1; ++r) s += partial[(size_t)r * 256 + t];
    atomAddF(&stats[t], s);
}

__global__ void k_bn_final(const float* __restrict__ stats,
                           const float* __restrict__ gamma,
                           const float* __restrict__ beta,
                           float* __restrict__ sc, float* __restrict__ sh) {
    int c = threadIdx.x;
    if (c < DD) {
        float mu = stats[c] * (1.0f / NN);
        float var = stats[DD + c] * (1.0f / NN) - mu * mu;
        float inv = rsqrtf(var + EPSBN);
        float s = gamma[c] * inv;
        sc[c] = s;
        sh[c] = beta[c] - mu * s;  // conv bias b cancels in BN exactly
    }
}

// ---------------- pooling (fused final BN+ReLU), reads bf16 A -------------
__global__ __launch_bounds__(256) void k_pool(const ushort* __restrict__ Ab,
                                              const int* __restrict__ batch,
                                              const float* __restrict__ sc,
                                              const float* __restrict__ sh,
                                              float* __restrict__ out) {
    const int tid = threadIdx.x;
    const int col = tid & 127, half = tid >> 7;
    const float s = sc[col], t = sh[col];
    int v0 = blockIdx.x * 196;
    int v1 = v0 + 196;
    if (v1 > NN) v1 = NN;
    float acc = 0.f;
    int g = -1;
    for (int v = v0 + half; v < v1; v += 2) {
        int bg = batch[v];
        if (bg != g) {
            if (g >= 0) atomAddF(&out[(size_t)g * DD + col], acc);
            g = bg;
            acc = 0.f;
        }
        float a = __uint_as_float((uint)Ab[(size_t)v * DD + col] << 16);
        acc += fmaxf(fmaf(a, s, t), 0.f);
    }
    if (g >= 0) atomAddF(&out[(size_t)g * DD + col], acc);
}

extern "C" void kernel_launch(void* const* d_in, const int* in_sizes, int n_in,
                              void* d_out, int out_size, void* d_ws, size_t ws_size,
                              hipStream_t stream) {
    const float* x     = (const float*)d_in[0];
    const int*   ei    = (const int*)d_in[1];
    const float* ew    = (const float*)d_in[2];
    const int*   batch = (const int*)d_in[3];
    const float* W     = (const float*)d_in[4];
    // d_in[5] = b — cancels exactly in training-mode BatchNorm, unused
    const float* gamma = (const float*)d_in[6];
    const float* beta  = (const float*)d_in[7];
    float* out = (float*)d_out;

    float* wsp   = (float*)d_ws;
    float* dinv  = wsp;                            // N
    float* stats = dinv + NN;                      // 768
    float* scl   = stats + 768;                    // 3 x 128
    float* shl   = scl + 3 * DD;                   // 3 x 128
    ushort* Wt   = (ushort*)(shl + 3 * DD);        // 3 x D x D bf16
    ushort* H    = Wt + (size_t)NL * DD * DD;      // N*D bf16
    ushort* Ab   = H + (size_t)NN * DD;            // N*D bf16
    int2*  srcw  = (int2*)(Ab + (size_t)NN * DD);  // E packed records
    float* partial = (float*)(srcw + NE);          // NAGG x 256
    int*   row_off = (int*)(partial + (size_t)NAGG * 256);  // N+4
    int*   gbcnt = row_off + NN + 4;               // NBUCK
    int*   boff  = gbcnt + NBUCK;                  // NBUCK+4 (padded)
    int*   gcur  = boff + NBUCK + 4;               // NBUCK
    int2*  csr   = (int2*)(gcur + NBUCK);          // E * 8B
    // total ≈ 84 MiB

    k_zero_fo<<<(NG * DD + 768 + NBUCK + 255) / 256, 256, 0, stream>>>(out, stats, gbcnt);

    // bucket-staged CSR build
    k_bcnt<<<256, 256, 0, stream>>>(ei, gbcnt);
    k_bscan<<<1, 256, 0, stream>>>(gbcnt, boff, gcur);
    k_bscatter<<<256, 256, 0, stream>>>(ei, ew, gcur, srcw);
    k_bsort<<<NBUCK, 256, 0, stream>>>(srcw, boff, row_off, csr);

    // degrees + norms from CSR (atomic-free)
    k_degdinv<<<(NN + 255) / 256, 256, 0, stream>>>(csr, row_off, dinv);
    k_nrm2<<<(NN + 255) / 256, 256, 0, stream>>>(csr, row_off, dinv);

    // W -> bf16 transposed [n][k]
    k_wprep<<<(NL * DD * DD + 255) / 256, 256, 0, stream>>>(W, Wt);

    for (int l = 0; l < NL; ++l) {
        const float* sc_prev = (l > 0) ? scl + (l - 1) * DD : scl;
        const float* sh_prev = (l > 0) ? shl + (l - 1) * DD : shl;
        k_gemm3<<<(NN + 127) / 128, 256, 0, stream>>>(
            x, Ab, Wt + (size_t)l * DD * DD, sc_prev, sh_prev, l > 0 ? 1 : 0, H);
        k_agg3<<<NAGG, 256, 0, stream>>>(csr, row_off, dinv, H, Ab, partial);
        k_bn_red<<<(NAGG + 24) / 25, 256, 0, stream>>>(partial, stats + l * 256);
        k_bn_final<<<1, 128, 0, stream>>>(stats + l * 256, gamma + (size_t)l * DD,
                                          beta + (size_t)l * DD,
                                          scl + l * DD, shl + l * DD);
    }

    k_pool<<<512, 256, 0, stream>>>(Ab, batch, scl + 2 * DD, shl + 2 * DD, out);
}

// Round 12
// 363.133 us; speedup vs baseline: 23.9423x; 1.2230x over previous
//
#include <hip/hip_runtime.h>

#define NN 100000   // nodes
#define NE 1600000  // edges
#define DD 128      // feature dim
#define NL 3        // layers
#define NG 64       // graphs
#define EPSBN 1e-5f
#define NBUCK 196               // ceil(NN/512) buckets of 512 nodes
#define NAGG (NN / 16)          // 6250 agg blocks (16 nodes each)

typedef __attribute__((ext_vector_type(8))) short short8v;   // 8 bf16 (4 VGPR)
typedef __attribute__((ext_vector_type(4))) float float4v;   // MFMA C/D
typedef __attribute__((ext_vector_type(2))) float float2v;   // fp8 cvt result

// ---- fp32 atomic add (HW global_atomic_add_f32, no CAS loop) ----
__device__ inline void atomAddF(float* p, float v) {
#if defined(__AMDGCN__)
    unsafeAtomicAdd(p, v);
#else
    atomicAdd(p, v);
#endif
}

// ---- fp32 -> bf16 round-to-nearest-even ----
__device__ inline ushort f2bf(float f) {
    uint u = __float_as_uint(f);
    uint r = ((u >> 16) & 1u) + 0x7fffu;
    return (ushort)((u + r) >> 16);
}

// ---- fp32 -> fp8 e4m3 (OCP, HW convert) ----
__device__ inline uint f2fp8(float f) {
    return (uint)__builtin_amdgcn_cvt_pk_fp8_f32(f, f, 0, false) & 0xffu;
}

// ---- accumulate 8 fp8 lanes (packed in uint2) scaled by wgt into acc[8] ----
__device__ inline void accf8(float (&acc)[8], uint2 g, float wgt) {
    float2v p0 = __builtin_amdgcn_cvt_pk_f32_fp8(g.x, false);
    float2v p1 = __builtin_amdgcn_cvt_pk_f32_fp8(g.x, true);
    float2v p2 = __builtin_amdgcn_cvt_pk_f32_fp8(g.y, false);
    float2v p3 = __builtin_amdgcn_cvt_pk_f32_fp8(g.y, true);
    acc[0] = fmaf(wgt, p0[0], acc[0]);
    acc[1] = fmaf(wgt, p0[1], acc[1]);
    acc[2] = fmaf(wgt, p1[0], acc[2]);
    acc[3] = fmaf(wgt, p1[1], acc[3]);
    acc[4] = fmaf(wgt, p2[0], acc[4]);
    acc[5] = fmaf(wgt, p2[1], acc[5]);
    acc[6] = fmaf(wgt, p3[0], acc[6]);
    acc[7] = fmaf(wgt, p3[1], acc[7]);
}

// ---------------- init: out, stats, bucket counters ----------------
__global__ __launch_bounds__(256) void k_zero_fo(float* __restrict__ out,
                                                 float* __restrict__ stats,
                                                 int* __restrict__ gbcnt) {
    int i = blockIdx.x * 256 + threadIdx.x;
    if (i < NG * DD) out[i] = 0.f;
    int j = i - NG * DD;
    if (j >= 0 && j < 768) stats[j] = 0.f;
    int k = j - 768;
    if (k >= 0 && k < NBUCK) gbcnt[k] = 0;
}

// ---------------- bucket histogram over dst ----------------
__global__ __launch_bounds__(256) void k_bcnt(const int* __restrict__ ei,
                                              int* __restrict__ gbcnt) {
    __shared__ int lh[NBUCK];
    int tid = threadIdx.x;
    if (tid < NBUCK) lh[tid] = 0;
    __syncthreads();
    for (int e = blockIdx.x * 256 + tid; e < NE; e += 256 * 256)
        atomicAdd(&lh[ei[NE + e] >> 9], 1);
    __syncthreads();
    if (tid < NBUCK) atomicAdd(&gbcnt[tid], lh[tid]);
}

// ---------------- bucket scan: boff (exclusive) + cursor init -------------
__global__ __launch_bounds__(256) void k_bscan(const int* __restrict__ gbcnt,
                                               int* __restrict__ boff,
                                               int* __restrict__ gcur) {
    __shared__ int s[256];
    int t = threadIdx.x;
    int v = (t < NBUCK) ? gbcnt[t] : 0;
    s[t] = v;
    __syncthreads();
    for (int off = 1; off < 256; off <<= 1) {
        int add = (t >= off) ? s[t - off] : 0;
        __syncthreads();
        s[t] += add;
        __syncthreads();
    }
    if (t < NBUCK) {
        int ex = s[t] - v;
        boff[t] = ex;
        gcur[t] = ex;
    }
    if (t == NBUCK - 1) boff[NBUCK] = s[t];  // = NE
}

// ---------------- scatter edges into bucket regions (run-staged) ----------
// 256 blocks x 6250 edges; record packs src (17b) | dst-local (9b) + ew
__global__ __launch_bounds__(256) void k_bscatter(const int* __restrict__ ei,
                                                  const float* __restrict__ ew,
                                                  int* __restrict__ gcur,
                                                  int2* __restrict__ srcw) {
    __shared__ int hist[NBUCK], base[NBUCK], cur[NBUCK];
    const int tid = threadIdx.x;
    const int e0 = blockIdx.x * 6250, e1 = e0 + 6250;
    if (tid < NBUCK) hist[tid] = 0;
    __syncthreads();
    for (int e = e0 + tid; e < e1; e += 256)
        atomicAdd(&hist[ei[NE + e] >> 9], 1);
    __syncthreads();
    if (tid < NBUCK) {
        base[tid] = atomicAdd(&gcur[tid], hist[tid]);
        cur[tid] = 0;
    }
    __syncthreads();
    for (int e = e0 + tid; e < e1; e += 256) {
        int d = ei[NE + e];
        int b = d >> 9;
        int p = base[b] + atomicAdd(&cur[b], 1);
        int2 sw;
        sw.x = ei[e] | ((d & 511) << 17);
        sw.y = __float_as_int(ew[e]);
        srcw[p] = sw;
    }
}

// ---------------- per-bucket counting sort -> CSR + row_off ---------------
__global__ __launch_bounds__(256) void k_bsort(const int2* __restrict__ srcw,
                                               const int* __restrict__ boff,
                                               int* __restrict__ row_off,
                                               int2* __restrict__ csr) {
    __shared__ int h0[512], h1[512], exc[512], cur[512];
    const int tid = threadIdx.x;
    const int b = blockIdx.x;
    const int p0 = boff[b], p1 = boff[b + 1];
    const int nbn = min(512, NN - (b << 9));

    for (int i = tid; i < 512; i += 256) h0[i] = 0;
    __syncthreads();
    for (int p = p0 + tid; p < p1; p += 256)
        atomicAdd(&h0[(srcw[p].x >> 17) & 511], 1);
    __syncthreads();

    int* sA = h0;
    int* sB = h1;
    for (int off = 1; off < 512; off <<= 1) {
        for (int i = tid; i < 512; i += 256) {
            int v = sA[i];
            if (i >= off) v += sA[i - off];
            sB[i] = v;
        }
        __syncthreads();
        int* tp = sA; sA = sB; sB = tp;
    }
    for (int i = tid; i < 512; i += 256) {
        exc[i] = (i == 0) ? 0 : sA[i - 1];
        cur[i] = 0;
    }
    __syncthreads();

    for (int n = tid; n < nbn; n += 256)
        row_off[(b << 9) + n] = p0 + exc[n];
    if (b == NBUCK - 1 && tid == 0) row_off[NN] = NE;

    for (int p = p0 + tid; p < p1; p += 256) {
        int2 sw = srcw[p];
        int dl = (sw.x >> 17) & 511;
        int q = p0 + exc[dl] + atomicAdd(&cur[dl], 1);
        int2 outv;
        outv.x = sw.x & 0x1FFFF;   // clean src
        outv.y = sw.y;             // raw ew
        csr[q] = outv;
    }
}

// deg[node] = 1 + sum of row's ew (contiguous, no atomics); dinv = rsqrt
__global__ __launch_bounds__(256) void k_degdinv(const int2* __restrict__ csr,
                                                 const int* __restrict__ row_off,
                                                 float* __restrict__ dinv) {
    int node = blockIdx.x * 256 + threadIdx.x;
    if (node >= NN) return;
    int beg = row_off[node], end = row_off[node + 1];
    float s = 1.0f;  // self-loop
    for (int j = beg; j < end; ++j) s += __int_as_float(csr[j].y);
    dinv[node] = rsqrtf(s);  // s >= 1 > 0 always
}

// csr[j].y <- dinv[dst] * ew * dinv[src]  (in place)
__global__ __launch_bounds__(256) void k_nrm2(int2* __restrict__ csr,
                                              const int* __restrict__ row_off,
                                              const float* __restrict__ dinv) {
    int node = blockIdx.x * 256 + threadIdx.x;
    if (node >= NN) return;
    int beg = row_off[node], end = row_off[node + 1];
    float dv = dinv[node];
    int* y = (int*)csr;
    for (int j = beg; j < end; ++j) {
        int2 e = csr[j];
        float nw = dv * __int_as_float(e.y) * dinv[e.x];
        y[2 * (size_t)j + 1] = __float_as_int(nw);
    }
}

// ---------------- W prep: fp32 [k][n] -> bf16 [n][k], all 3 layers ----------
__global__ __launch_bounds__(256) void k_wprep(const float* __restrict__ W,
                                               ushort* __restrict__ Wt) {
    int idx = blockIdx.x * 256 + threadIdx.x;   // 0 .. 3*16384
    if (idx < NL * DD * DD) {
        int l = idx >> 14, i = idx & 16383;
        int k = i >> 7, n = i & 127;
        Wt[(size_t)l * DD * DD + n * DD + k] = f2bf(W[idx]);
    }
}

// ---------------- MFMA GEMM: H = act(X) @ W, H stored fp8 e4m3 -------------
// Layer 0: X fp32, no BN. Layers 1+: Xb bf16 with fused BN+ReLU.
__global__ __launch_bounds__(256, 2) void k_gemm3(const float* __restrict__ X,
                                                  const ushort* __restrict__ Xb,
                                                  const ushort* __restrict__ Wt,
                                                  const float* __restrict__ sc,
                                                  const float* __restrict__ sh,
                                                  int applyBN,
                                                  unsigned char* __restrict__ H) {
    __shared__ ushort xs[128 * 128];   // [row][k] bf16, swizzled
    __shared__ ushort ws[128 * 128];   // [n][k]  bf16, swizzled
    const int tid = threadIdx.x;
    const int row0 = blockIdx.x * 128;

    for (int c = tid; c < 2048; c += 256) {
        int r = c >> 4, k8 = (c & 15) * 8;
        int gr = row0 + r;
        float v[8];
        if (applyBN) {
            uint4 g = (gr < NN) ? *(const uint4*)&Xb[(size_t)gr * DD + k8]
                                : make_uint4(0u, 0u, 0u, 0u);
            v[0] = __uint_as_float(g.x << 16);
            v[1] = __uint_as_float(g.x & 0xffff0000u);
            v[2] = __uint_as_float(g.y << 16);
            v[3] = __uint_as_float(g.y & 0xffff0000u);
            v[4] = __uint_as_float(g.z << 16);
            v[5] = __uint_as_float(g.z & 0xffff0000u);
            v[6] = __uint_as_float(g.w << 16);
            v[7] = __uint_as_float(g.w & 0xffff0000u);
#pragma unroll
            for (int i = 0; i < 8; ++i)
                v[i] = fmaxf(fmaf(v[i], sc[k8 + i], sh[k8 + i]), 0.f);
        } else {
            if (gr < NN) {
                float4 a = *(const float4*)&X[(size_t)gr * DD + k8];
                float4 b = *(const float4*)&X[(size_t)gr * DD + k8 + 4];
                v[0] = a.x; v[1] = a.y; v[2] = a.z; v[3] = a.w;
                v[4] = b.x; v[5] = b.y; v[6] = b.z; v[7] = b.w;
            } else {
#pragma unroll
                for (int i = 0; i < 8; ++i) v[i] = 0.f;
            }
        }
        uint4 st;
        st.x = (uint)f2bf(v[0]) | ((uint)f2bf(v[1]) << 16);
        st.y = (uint)f2bf(v[2]) | ((uint)f2bf(v[3]) << 16);
        st.z = (uint)f2bf(v[4]) | ((uint)f2bf(v[5]) << 16);
        st.w = (uint)f2bf(v[6]) | ((uint)f2bf(v[7]) << 16);
        int idx = r * 128 + (((k8 * 2) ^ ((r & 7) << 4)) >> 1);
        *(uint4*)&xs[idx] = st;
    }
    for (int c = tid; c < 2048; c += 256) {
        int n = c >> 4, k8 = (c & 15) * 8;
        uint4 w = *(const uint4*)&Wt[n * DD + k8];
        int idx = n * 128 + (((k8 * 2) ^ ((n & 7) << 4)) >> 1);
        *(uint4*)&ws[idx] = w;
    }
    __syncthreads();

    const int wid = tid >> 6, lane = tid & 63;
    const int wm = wid >> 1, wn = wid & 1;       // 2x2 waves of 64x64
    const int lrow = lane & 15, lk = lane >> 4;
    float4v acc[4][4];
#pragma unroll
    for (int i = 0; i < 4; ++i)
#pragma unroll
        for (int j = 0; j < 4; ++j) acc[i][j] = (float4v){0.f, 0.f, 0.f, 0.f};

#pragma unroll
    for (int ks = 0; ks < 4; ++ks) {
        int kbyte = ks * 64 + lk * 16;
        short8v a[4], b[4];
#pragma unroll
        for (int mg = 0; mg < 4; ++mg) {
            int r = wm * 64 + mg * 16 + lrow;
            a[mg] = *(const short8v*)&xs[r * 128 + ((kbyte ^ ((r & 7) << 4)) >> 1)];
        }
#pragma unroll
        for (int ng = 0; ng < 4; ++ng) {
            int n = wn * 64 + ng * 16 + lrow;
            b[ng] = *(const short8v*)&ws[n * 128 + ((kbyte ^ ((n & 7) << 4)) >> 1)];
        }
#pragma unroll
        for (int mg = 0; mg < 4; ++mg)
#pragma unroll
            for (int ng = 0; ng < 4; ++ng)
                acc[mg][ng] = __builtin_amdgcn_mfma_f32_16x16x32_bf16(
                    a[mg], b[ng], acc[mg][ng], 0, 0, 0);
    }

    // C/D layout: col = lane&15, row = (lane>>4)*4 + reg  [m89]
#pragma unroll
    for (int mg = 0; mg < 4; ++mg) {
        int rbase = row0 + wm * 64 + mg * 16 + lk * 4;
#pragma unroll
        for (int j = 0; j < 4; ++j) {
            int gr = rbase + j;
            if (gr < NN) {
#pragma unroll
                for (int ng = 0; ng < 4; ++ng) {
                    int col = wn * 64 + ng * 16 + lrow;
                    H[(size_t)gr * DD + col] = (unsigned char)f2fp8(acc[mg][ng][j]);
                }
            }
        }
    }
}

// ---------------- aggregation + fused BN partial stats --------------------
// fp8 H: 16 lanes/node, 8 cols/lane (uint2 = 8 fp8); unroll 8; A bf16
__global__ __launch_bounds__(256) void k_agg3(const int2* __restrict__ csr,
                                              const int* __restrict__ row_off,
                                              const float* __restrict__ dinv,
                                              const unsigned char* __restrict__ H,
                                              ushort* __restrict__ Ab,
                                              float* __restrict__ partial) {
    __shared__ float sbv[16][128];
    __shared__ float sbq[16][128];
    const int tid = threadIdx.x;
    int node = blockIdx.x * 16 + (tid >> 4);
    int h = tid & 15;
    int beg = row_off[node], end = row_off[node + 1];
    float dv = dinv[node];
    size_t cb = (size_t)node * DD + h * 8;   // byte index
    float acc[8] = {0.f, 0.f, 0.f, 0.f, 0.f, 0.f, 0.f, 0.f};
    {
        uint2 v = *(const uint2*)&H[cb];
        accf8(acc, v, dv * dv);  // self-loop term
    }

    int j = beg;
    for (; j + 8 <= end; j += 8) {
        int2 e0 = csr[j], e1 = csr[j + 1], e2 = csr[j + 2], e3 = csr[j + 3];
        int2 e4 = csr[j + 4], e5 = csr[j + 5], e6 = csr[j + 6], e7 = csr[j + 7];
        uint2 g0 = *(const uint2*)&H[(size_t)e0.x * DD + h * 8];
        uint2 g1 = *(const uint2*)&H[(size_t)e1.x * DD + h * 8];
        uint2 g2 = *(const uint2*)&H[(size_t)e2.x * DD + h * 8];
        uint2 g3 = *(const uint2*)&H[(size_t)e3.x * DD + h * 8];
        uint2 g4 = *(const uint2*)&H[(size_t)e4.x * DD + h * 8];
        uint2 g5 = *(const uint2*)&H[(size_t)e5.x * DD + h * 8];
        uint2 g6 = *(const uint2*)&H[(size_t)e6.x * DD + h * 8];
        uint2 g7 = *(const uint2*)&H[(size_t)e7.x * DD + h * 8];
        accf8(acc, g0, __int_as_float(e0.y));
        accf8(acc, g1, __int_as_float(e1.y));
        accf8(acc, g2, __int_as_float(e2.y));
        accf8(acc, g3, __int_as_float(e3.y));
        accf8(acc, g4, __int_as_float(e4.y));
        accf8(acc, g5, __int_as_float(e5.y));
        accf8(acc, g6, __int_as_float(e6.y));
        accf8(acc, g7, __int_as_float(e7.y));
    }
    for (; j + 4 <= end; j += 4) {
        int2 e0 = csr[j], e1 = csr[j + 1], e2 = csr[j + 2], e3 = csr[j + 3];
        uint2 g0 = *(const uint2*)&H[(size_t)e0.x * DD + h * 8];
        uint2 g1 = *(const uint2*)&H[(size_t)e1.x * DD + h * 8];
        uint2 g2 = *(const uint2*)&H[(size_t)e2.x * DD + h * 8];
        uint2 g3 = *(const uint2*)&H[(size_t)e3.x * DD + h * 8];
        accf8(acc, g0, __int_as_float(e0.y));
        accf8(acc, g1, __int_as_float(e1.y));
        accf8(acc, g2, __int_as_float(e2.y));
        accf8(acc, g3, __int_as_float(e3.y));
    }
    for (; j < end; ++j) {
        int2 e = csr[j];
        uint2 g = *(const uint2*)&H[(size_t)e.x * DD + h * 8];
        accf8(acc, g, __int_as_float(e.y));
    }

    // write A in bf16 (ushort index = byte index of fp8 layout)
    uint4 st;
    st.x = (uint)f2bf(acc[0]) | ((uint)f2bf(acc[1]) << 16);
    st.y = (uint)f2bf(acc[2]) | ((uint)f2bf(acc[3]) << 16);
    st.z = (uint)f2bf(acc[4]) | ((uint)f2bf(acc[5]) << 16);
    st.w = (uint)f2bf(acc[6]) | ((uint)f2bf(acc[7]) << 16);
    *(uint4*)&Ab[cb] = st;

    // fused BN partial stats from fp32 accumulators
    int n = tid >> 4, c0 = h * 8;
#pragma unroll
    for (int i = 0; i < 8; ++i) {
        float a = acc[i];
        sbv[n][c0 + i] = a;
        sbq[n][c0 + i] = a * a;
    }
    __syncthreads();
    float s = 0.f;
    if (tid < 128) {
#pragma unroll
        for (int k = 0; k < 16; ++k) s += sbv[k][tid];
    } else {
        int c = tid - 128;
#pragma unroll
        for (int k = 0; k < 16; ++k) s += sbq[k][c];
    }
    partial[(size_t)blockIdx.x * 256 + tid] = s;
}

// ---------------- reduce partials -> stats (low-contention atomics) -------
__global__ __launch_bounds__(256) void k_bn_red(const float* __restrict__ partial,
                                                float* __restrict__ stats) {
    int r0 = blockIdx.x * 25;
    int r1 = min(r0 + 25, NAGG);
    int t = threadIdx.x;
    float s = 0.f;
    for (int r = r0; r < r1; ++r) s += partial[(size_t)r * 256 + t];
    atomAddF(&stats[t], s);
}

__global__ void k_bn_final(const float* __restrict__ stats,
                           const float* __restrict__ gamma,
                           const float* __restrict__ beta,
                           float* __restrict__ sc, float* __restrict__ sh) {
    int c = threadIdx.x;
    if (c < DD) {
        float mu = stats[c] * (1.0f / NN);
        float var = stats[DD + c] * (1.0f / NN) - mu * mu;
        float inv = rsqrtf(var + EPSBN);
        float s = gamma[c] * inv;
        sc[c] = s;
        sh[c] = beta[c] - mu * s;  // conv bias b cancels in BN exactly
    }
}

// ---------------- pooling (fused final BN+ReLU), reads bf16 A -------------
__global__ __launch_bounds__(256) void k_pool(const ushort* __restrict__ Ab,
                                              const int* __restrict__ batch,
                                              const float* __restrict__ sc,
                                              const float* __restrict__ sh,
                                              float* __restrict__ out) {
    const int tid = threadIdx.x;
    const int col = tid & 127, half = tid >> 7;
    const float s = sc[col], t = sh[col];
    int v0 = blockIdx.x * 196;
    int v1 = v0 + 196;
    if (v1 > NN) v1 = NN;
    float acc = 0.f;
    int g = -1;
    for (int v = v0 + half; v < v1; v += 2) {
        int bg = batch[v];
        if (bg != g) {
            if (g >= 0) atomAddF(&out[(size_t)g * DD + col], acc);
            g = bg;
            acc = 0.f;
        }
        float a = __uint_as_float((uint)Ab[(size_t)v * DD + col] << 16);
        acc += fmaxf(fmaf(a, s, t), 0.f);
    }
    if (g >= 0) atomAddF(&out[(size_t)g * DD + col], acc);
}

extern "C" void kernel_launch(void* const* d_in, const int* in_sizes, int n_in,
                              void* d_out, int out_size, void* d_ws, size_t ws_size,
                              hipStream_t stream) {
    const float* x     = (const float*)d_in[0];
    const int*   ei    = (const int*)d_in[1];
    const float* ew    = (const float*)d_in[2];
    const int*   batch = (const int*)d_in[3];
    const float* W     = (const float*)d_in[4];
    // d_in[5] = b — cancels exactly in training-mode BatchNorm, unused
    const float* gamma = (const float*)d_in[6];
    const float* beta  = (const float*)d_in[7];
    float* out = (float*)d_out;

    float* wsp   = (float*)d_ws;
    float* dinv  = wsp;                            // N
    float* stats = dinv + NN;                      // 768
    float* scl   = stats + 768;                    // 3 x 128
    float* shl   = scl + 3 * DD;                   // 3 x 128
    ushort* Wt   = (ushort*)(shl + 3 * DD);        // 3 x D x D bf16
    unsigned char* H = (unsigned char*)(Wt + (size_t)NL * DD * DD);  // N*D fp8
    ushort* Ab   = (ushort*)(H + (size_t)NN * DD); // N*D bf16
    int2*  srcw  = (int2*)(Ab + (size_t)NN * DD);  // E packed records
    float* partial = (float*)(srcw + NE);          // NAGG x 256
    int*   row_off = (int*)(partial + (size_t)NAGG * 256);  // N+4
    int*   gbcnt = row_off + NN + 4;               // NBUCK
    int*   boff  = gbcnt + NBUCK;                  // NBUCK+4 (padded)
    int*   gcur  = boff + NBUCK + 4;               // NBUCK
    int2*  csr   = (int2*)(gcur + NBUCK);          // E * 8B
    // total ≈ 71 MiB

    k_zero_fo<<<(NG * DD + 768 + NBUCK + 255) / 256, 256, 0, stream>>>(out, stats, gbcnt);

    // bucket-staged CSR build
    k_bcnt<<<256, 256, 0, stream>>>(ei, gbcnt);
    k_bscan<<<1, 256, 0, stream>>>(gbcnt, boff, gcur);
    k_bscatter<<<256, 256, 0, stream>>>(ei, ew, gcur, srcw);
    k_bsort<<<NBUCK, 256, 0, stream>>>(srcw, boff, row_off, csr);

    // degrees + norms from CSR (atomic-free)
    k_degdinv<<<(NN + 255) / 256, 256, 0, stream>>>(csr, row_off, dinv);
    k_nrm2<<<(NN + 255) / 256, 256, 0, stream>>>(csr, row_off, dinv);

    // W -> bf16 transposed [n][k]
    k_wprep<<<(NL * DD * DD + 255) / 256, 256, 0, stream>>>(W, Wt);

    for (int l = 0; l < NL; ++l) {
        const float* sc_prev = (l > 0) ? scl + (l - 1) * DD : scl;
        const float* sh_prev = (l > 0) ? shl + (l - 1) * DD : shl;
        k_gemm3<<<(NN + 127) / 128, 256, 0, stream>>>(
            x, Ab, Wt + (size_t)l * DD * DD, sc_prev, sh_prev, l > 0 ? 1 : 0, H);
        k_agg3<<<NAGG, 256, 0, stream>>>(csr, row_off, dinv, H, Ab, partial);
        k_bn_red<<<(NAGG + 24) / 25, 256, 0, stream>>>(partial, stats + l * 256);
        k_bn_final<<<1, 128, 0, stream>>>(stats + l * 256, gamma + (size_t)l * DD,
                                          beta + (size_t)l * DD,
                                          scl + l * DD, shl + l * DD);
    }

    k_pool<<<512, 256, 0, stream>>>(Ab, batch, scl + 2 * DD, shl + 2 * DD, out);
}

// Round 13
// 353.675 us; speedup vs baseline: 24.5826x; 1.0267x over previous
//
#include <hip/hip_runtime.h>

#define NN 100000   // nodes
#define NE 1600000  // edges
#define DD 128      // feature dim
#define NL 3        // layers
#define NG 64       // graphs
#define EPSBN 1e-5f
#define NBUCK 196               // ceil(NN/512) buckets of 512 nodes
#define NAGG (NN / 16)          // 6250 agg blocks (16 nodes each)

typedef __attribute__((ext_vector_type(8))) short short8v;   // 8 bf16 (4 VGPR)
typedef __attribute__((ext_vector_type(4))) float float4v;   // MFMA C/D
typedef __attribute__((ext_vector_type(2))) float float2v;   // fp8 cvt result

// ---- fp32 atomic add (HW global_atomic_add_f32, no CAS loop) ----
__device__ inline void atomAddF(float* p, float v) {
#if defined(__AMDGCN__)
    unsafeAtomicAdd(p, v);
#else
    atomicAdd(p, v);
#endif
}

// ---- fp32 -> bf16 round-to-nearest-even ----
__device__ inline ushort f2bf(float f) {
    uint u = __float_as_uint(f);
    uint r = ((u >> 16) & 1u) + 0x7fffu;
    return (ushort)((u + r) >> 16);
}

// ---- fp32 -> fp8 e4m3 (OCP, HW convert) ----
__device__ inline uint f2fp8(float f) {
    return (uint)__builtin_amdgcn_cvt_pk_fp8_f32(f, f, 0, false) & 0xffu;
}

// ---- accumulate 8 fp8 lanes (packed in uint2) scaled by wgt into acc[8] ----
__device__ inline void accf8(float (&acc)[8], uint2 g, float wgt) {
    float2v p0 = __builtin_amdgcn_cvt_pk_f32_fp8(g.x, false);
    float2v p1 = __builtin_amdgcn_cvt_pk_f32_fp8(g.x, true);
    float2v p2 = __builtin_amdgcn_cvt_pk_f32_fp8(g.y, false);
    float2v p3 = __builtin_amdgcn_cvt_pk_f32_fp8(g.y, true);
    acc[0] = fmaf(wgt, p0[0], acc[0]);
    acc[1] = fmaf(wgt, p0[1], acc[1]);
    acc[2] = fmaf(wgt, p1[0], acc[2]);
    acc[3] = fmaf(wgt, p1[1], acc[3]);
    acc[4] = fmaf(wgt, p2[0], acc[4]);
    acc[5] = fmaf(wgt, p2[1], acc[5]);
    acc[6] = fmaf(wgt, p3[0], acc[6]);
    acc[7] = fmaf(wgt, p3[1], acc[7]);
}

// ---------------- init: out, stats, bucket counters ----------------
__global__ __launch_bounds__(256) void k_zero_fo(float* __restrict__ out,
                                                 float* __restrict__ stats,
                                                 int* __restrict__ gbcnt) {
    int i = blockIdx.x * 256 + threadIdx.x;
    if (i < NG * DD) out[i] = 0.f;
    int j = i - NG * DD;
    if (j >= 0 && j < 768) stats[j] = 0.f;
    int k = j - 768;
    if (k >= 0 && k < NBUCK) gbcnt[k] = 0;
}

// ---------------- bucket histogram over dst ----------------
__global__ __launch_bounds__(256) void k_bcnt(const int* __restrict__ ei,
                                              int* __restrict__ gbcnt) {
    __shared__ int lh[NBUCK];
    int tid = threadIdx.x;
    if (tid < NBUCK) lh[tid] = 0;
    __syncthreads();
    for (int e = blockIdx.x * 256 + tid; e < NE; e += 256 * 256)
        atomicAdd(&lh[ei[NE + e] >> 9], 1);
    __syncthreads();
    if (tid < NBUCK) atomicAdd(&gbcnt[tid], lh[tid]);
}

// ---------------- bucket scan: boff (exclusive) + cursor init -------------
__global__ __launch_bounds__(256) void k_bscan(const int* __restrict__ gbcnt,
                                               int* __restrict__ boff,
                                               int* __restrict__ gcur) {
    __shared__ int s[256];
    int t = threadIdx.x;
    int v = (t < NBUCK) ? gbcnt[t] : 0;
    s[t] = v;
    __syncthreads();
    for (int off = 1; off < 256; off <<= 1) {
        int add = (t >= off) ? s[t - off] : 0;
        __syncthreads();
        s[t] += add;
        __syncthreads();
    }
    if (t < NBUCK) {
        int ex = s[t] - v;
        boff[t] = ex;
        gcur[t] = ex;
    }
    if (t == NBUCK - 1) boff[NBUCK] = s[t];  // = NE
}

// ---------------- scatter edges into bucket regions (run-staged) ----------
// 256 blocks x 6250 edges; record packs src (17b) | dst-local (9b) + ew
__global__ __launch_bounds__(256) void k_bscatter(const int* __restrict__ ei,
                                                  const float* __restrict__ ew,
                                                  int* __restrict__ gcur,
                                                  int2* __restrict__ srcw) {
    __shared__ int hist[NBUCK], base[NBUCK], cur[NBUCK];
    const int tid = threadIdx.x;
    const int e0 = blockIdx.x * 6250, e1 = e0 + 6250;
    if (tid < NBUCK) hist[tid] = 0;
    __syncthreads();
    for (int e = e0 + tid; e < e1; e += 256)
        atomicAdd(&hist[ei[NE + e] >> 9], 1);
    __syncthreads();
    if (tid < NBUCK) {
        base[tid] = atomicAdd(&gcur[tid], hist[tid]);
        cur[tid] = 0;
    }
    __syncthreads();
    for (int e = e0 + tid; e < e1; e += 256) {
        int d = ei[NE + e];
        int b = d >> 9;
        int p = base[b] + atomicAdd(&cur[b], 1);
        int2 sw;
        sw.x = ei[e] | ((d & 511) << 17);
        sw.y = __float_as_int(ew[e]);
        srcw[p] = sw;
    }
}

// ---------------- per-bucket counting sort -> CSR + row_off ---------------
__global__ __launch_bounds__(256) void k_bsort(const int2* __restrict__ srcw,
                                               const int* __restrict__ boff,
                                               int* __restrict__ row_off,
                                               int2* __restrict__ csr) {
    __shared__ int h0[512], h1[512], exc[512], cur[512];
    const int tid = threadIdx.x;
    const int b = blockIdx.x;
    const int p0 = boff[b], p1 = boff[b + 1];
    const int nbn = min(512, NN - (b << 9));

    for (int i = tid; i < 512; i += 256) h0[i] = 0;
    __syncthreads();
    for (int p = p0 + tid; p < p1; p += 256)
        atomicAdd(&h0[(srcw[p].x >> 17) & 511], 1);
    __syncthreads();

    int* sA = h0;
    int* sB = h1;
    for (int off = 1; off < 512; off <<= 1) {
        for (int i = tid; i < 512; i += 256) {
            int v = sA[i];
            if (i >= off) v += sA[i - off];
            sB[i] = v;
        }
        __syncthreads();
        int* tp = sA; sA = sB; sB = tp;
    }
    for (int i = tid; i < 512; i += 256) {
        exc[i] = (i == 0) ? 0 : sA[i - 1];
        cur[i] = 0;
    }
    __syncthreads();

    for (int n = tid; n < nbn; n += 256)
        row_off[(b << 9) + n] = p0 + exc[n];
    if (b == NBUCK - 1 && tid == 0) row_off[NN] = NE;

    for (int p = p0 + tid; p < p1; p += 256) {
        int2 sw = srcw[p];
        int dl = (sw.x >> 17) & 511;
        int q = p0 + exc[dl] + atomicAdd(&cur[dl], 1);
        int2 outv;
        outv.x = sw.x & 0x1FFFF;   // clean src
        outv.y = sw.y;             // raw ew
        csr[q] = outv;
    }
}

// deg[node] = 1 + sum of row's ew (contiguous, no atomics); dinv = rsqrt
__global__ __launch_bounds__(256) void k_degdinv(const int2* __restrict__ csr,
                                                 const int* __restrict__ row_off,
                                                 float* __restrict__ dinv) {
    int node = blockIdx.x * 256 + threadIdx.x;
    if (node >= NN) return;
    int beg = row_off[node], end = row_off[node + 1];
    float s = 1.0f;  // self-loop
    for (int j = beg; j < end; ++j) s += __int_as_float(csr[j].y);
    dinv[node] = rsqrtf(s);  // s >= 1 > 0 always
}

// csr[j].y <- dinv[dst] * ew * dinv[src]  (in place)
__global__ __launch_bounds__(256) void k_nrm2(int2* __restrict__ csr,
                                              const int* __restrict__ row_off,
                                              const float* __restrict__ dinv) {
    int node = blockIdx.x * 256 + threadIdx.x;
    if (node >= NN) return;
    int beg = row_off[node], end = row_off[node + 1];
    float dv = dinv[node];
    int* y = (int*)csr;
    for (int j = beg; j < end; ++j) {
        int2 e = csr[j];
        float nw = dv * __int_as_float(e.y) * dinv[e.x];
        y[2 * (size_t)j + 1] = __float_as_int(nw);
    }
}

// ---------------- W prep: fp32 [k][n] -> bf16 [n][k], all 3 layers ----------
__global__ __launch_bounds__(256) void k_wprep(const float* __restrict__ W,
                                               ushort* __restrict__ Wt) {
    int idx = blockIdx.x * 256 + threadIdx.x;   // 0 .. 3*16384
    if (idx < NL * DD * DD) {
        int l = idx >> 14, i = idx & 16383;
        int k = i >> 7, n = i & 127;
        Wt[(size_t)l * DD * DD + n * DD + k] = f2bf(W[idx]);
    }
}

// ---------------- MFMA GEMM: H = act(X) @ W, H stored fp8 e4m3 -------------
// Layer 0: X fp32, no BN. Layers 1+: Xb bf16 with fused BN+ReLU.
__global__ __launch_bounds__(256, 2) void k_gemm3(const float* __restrict__ X,
                                                  const ushort* __restrict__ Xb,
                                                  const ushort* __restrict__ Wt,
                                                  const float* __restrict__ sc,
                                                  const float* __restrict__ sh,
                                                  int applyBN,
                                                  unsigned char* __restrict__ H) {
    __shared__ ushort xs[128 * 128];   // [row][k] bf16, swizzled
    __shared__ ushort ws[128 * 128];   // [n][k]  bf16, swizzled
    const int tid = threadIdx.x;
    const int row0 = blockIdx.x * 128;

    for (int c = tid; c < 2048; c += 256) {
        int r = c >> 4, k8 = (c & 15) * 8;
        int gr = row0 + r;
        float v[8];
        if (applyBN) {
            uint4 g = (gr < NN) ? *(const uint4*)&Xb[(size_t)gr * DD + k8]
                                : make_uint4(0u, 0u, 0u, 0u);
            v[0] = __uint_as_float(g.x << 16);
            v[1] = __uint_as_float(g.x & 0xffff0000u);
            v[2] = __uint_as_float(g.y << 16);
            v[3] = __uint_as_float(g.y & 0xffff0000u);
            v[4] = __uint_as_float(g.z << 16);
            v[5] = __uint_as_float(g.z & 0xffff0000u);
            v[6] = __uint_as_float(g.w << 16);
            v[7] = __uint_as_float(g.w & 0xffff0000u);
#pragma unroll
            for (int i = 0; i < 8; ++i)
                v[i] = fmaxf(fmaf(v[i], sc[k8 + i], sh[k8 + i]), 0.f);
        } else {
            if (gr < NN) {
                float4 a = *(const float4*)&X[(size_t)gr * DD + k8];
                float4 b = *(const float4*)&X[(size_t)gr * DD + k8 + 4];
                v[0] = a.x; v[1] = a.y; v[2] = a.z; v[3] = a.w;
                v[4] = b.x; v[5] = b.y; v[6] = b.z; v[7] = b.w;
            } else {
#pragma unroll
                for (int i = 0; i < 8; ++i) v[i] = 0.f;
            }
        }
        uint4 st;
        st.x = (uint)f2bf(v[0]) | ((uint)f2bf(v[1]) << 16);
        st.y = (uint)f2bf(v[2]) | ((uint)f2bf(v[3]) << 16);
        st.z = (uint)f2bf(v[4]) | ((uint)f2bf(v[5]) << 16);
        st.w = (uint)f2bf(v[6]) | ((uint)f2bf(v[7]) << 16);
        int idx = r * 128 + (((k8 * 2) ^ ((r & 7) << 4)) >> 1);
        *(uint4*)&xs[idx] = st;
    }
    for (int c = tid; c < 2048; c += 256) {
        int n = c >> 4, k8 = (c & 15) * 8;
        uint4 w = *(const uint4*)&Wt[n * DD + k8];
        int idx = n * 128 + (((k8 * 2) ^ ((n & 7) << 4)) >> 1);
        *(uint4*)&ws[idx] = w;
    }
    __syncthreads();

    const int wid = tid >> 6, lane = tid & 63;
    const int wm = wid >> 1, wn = wid & 1;       // 2x2 waves of 64x64
    const int lrow = lane & 15, lk = lane >> 4;
    float4v acc[4][4];
#pragma unroll
    for (int i = 0; i < 4; ++i)
#pragma unroll
        for (int j = 0; j < 4; ++j) acc[i][j] = (float4v){0.f, 0.f, 0.f, 0.f};

#pragma unroll
    for (int ks = 0; ks < 4; ++ks) {
        int kbyte = ks * 64 + lk * 16;
        short8v a[4], b[4];
#pragma unroll
        for (int mg = 0; mg < 4; ++mg) {
            int r = wm * 64 + mg * 16 + lrow;
            a[mg] = *(const short8v*)&xs[r * 128 + ((kbyte ^ ((r & 7) << 4)) >> 1)];
        }
#pragma unroll
        for (int ng = 0; ng < 4; ++ng) {
            int n = wn * 64 + ng * 16 + lrow;
            b[ng] = *(const short8v*)&ws[n * 128 + ((kbyte ^ ((n & 7) << 4)) >> 1)];
        }
#pragma unroll
        for (int mg = 0; mg < 4; ++mg)
#pragma unroll
            for (int ng = 0; ng < 4; ++ng)
                acc[mg][ng] = __builtin_amdgcn_mfma_f32_16x16x32_bf16(
                    a[mg], b[ng], acc[mg][ng], 0, 0, 0);
    }

    // C/D layout: col = lane&15, row = (lane>>4)*4 + reg  [m89]
#pragma unroll
    for (int mg = 0; mg < 4; ++mg) {
        int rbase = row0 + wm * 64 + mg * 16 + lk * 4;
#pragma unroll
        for (int j = 0; j < 4; ++j) {
            int gr = rbase + j;
            if (gr < NN) {
#pragma unroll
                for (int ng = 0; ng < 4; ++ng) {
                    int col = wn * 64 + ng * 16 + lrow;
                    H[(size_t)gr * DD + col] = (unsigned char)f2fp8(acc[mg][ng][j]);
                }
            }
        }
    }
}

// ---------------- aggregation + fused BN partial stats --------------------
// fp8 H: 16 lanes/node, 8 cols/lane (uint2 = 8 fp8); unroll 8; A bf16
__global__ __launch_bounds__(256) void k_agg3(const int2* __restrict__ csr,
                                              const int* __restrict__ row_off,
                                              const float* __restrict__ dinv,
                                              const unsigned char* __restrict__ H,
                                              ushort* __restrict__ Ab,
                                              float* __restrict__ partial) {
    __shared__ float sbv[16][128];
    __shared__ float sbq[16][128];
    const int tid = threadIdx.x;
    int node = blockIdx.x * 16 + (tid >> 4);
    int h = tid & 15;
    int beg = row_off[node], end = row_off[node + 1];
    float dv = dinv[node];
    size_t cb = (size_t)node * DD + h * 8;   // byte index
    float acc[8] = {0.f, 0.f, 0.f, 0.f, 0.f, 0.f, 0.f, 0.f};
    {
        uint2 v = *(const uint2*)&H[cb];
        accf8(acc, v, dv * dv);  // self-loop term
    }

    int j = beg;
    for (; j + 8 <= end; j += 8) {
        int2 e0 = csr[j], e1 = csr[j + 1], e2 = csr[j + 2], e3 = csr[j + 3];
        int2 e4 = csr[j + 4], e5 = csr[j + 5], e6 = csr[j + 6], e7 = csr[j + 7];
        uint2 g0 = *(const uint2*)&H[(size_t)e0.x * DD + h * 8];
        uint2 g1 = *(const uint2*)&H[(size_t)e1.x * DD + h * 8];
        uint2 g2 = *(const uint2*)&H[(size_t)e2.x * DD + h * 8];
        uint2 g3 = *(const uint2*)&H[(size_t)e3.x * DD + h * 8];
        uint2 g4 = *(const uint2*)&H[(size_t)e4.x * DD + h * 8];
        uint2 g5 = *(const uint2*)&H[(size_t)e5.x * DD + h * 8];
        uint2 g6 = *(const uint2*)&H[(size_t)e6.x * DD + h * 8];
        uint2 g7 = *(const uint2*)&H[(size_t)e7.x * DD + h * 8];
        accf8(acc, g0, __int_as_float(e0.y));
        accf8(acc, g1, __int_as_float(e1.y));
        accf8(acc, g2, __int_as_float(e2.y));
        accf8(acc, g3, __int_as_float(e3.y));
        accf8(acc, g4, __int_as_float(e4.y));
        accf8(acc, g5, __int_as_float(e5.y));
        accf8(acc, g6, __int_as_float(e6.y));
        accf8(acc, g7, __int_as_float(e7.y));
    }
    for (; j + 4 <= end; j += 4) {
        int2 e0 = csr[j], e1 = csr[j + 1], e2 = csr[j + 2], e3 = csr[j + 3];
        uint2 g0 = *(const uint2*)&H[(size_t)e0.x * DD + h * 8];
        uint2 g1 = *(const uint2*)&H[(size_t)e1.x * DD + h * 8];
        uint2 g2 = *(const uint2*)&H[(size_t)e2.x * DD + h * 8];
        uint2 g3 = *(const uint2*)&H[(size_t)e3.x * DD + h * 8];
        accf8(acc, g0, __int_as_float(e0.y));
        accf8(acc, g1, __int_as_float(e1.y));
        accf8(acc, g2, __int_as_float(e2.y));
        accf8(acc, g3, __int_as_float(e3.y));
    }
    for (; j < end; ++j) {
        int2 e = csr[j];
        uint2 g = *(const uint2*)&H[(size_t)e.x * DD + h * 8];
        accf8(acc, g, __int_as_float(e.y));
    }

    // write A in bf16 (ushort index = byte index of fp8 layout)
    uint4 st;
    st.x = (uint)f2bf(acc[0]) | ((uint)f2bf(acc[1]) << 16);
    st.y = (uint)f2bf(acc[2]) | ((uint)f2bf(acc[3]) << 16);
    st.z = (uint)f2bf(acc[4]) | ((uint)f2bf(acc[5]) << 16);
    st.w = (uint)f2bf(acc[6]) | ((uint)f2bf(acc[7]) << 16);
    *(uint4*)&Ab[cb] = st;

    // fused BN partial stats from fp32 accumulators
    int n = tid >> 4, c0 = h * 8;
#pragma unroll
    for (int i = 0; i < 8; ++i) {
        float a = acc[i];
        sbv[n][c0 + i] = a;
        sbq[n][c0 + i] = a * a;
    }
    __syncthreads();
    float s = 0.f;
    if (tid < 128) {
#pragma unroll
        for (int k = 0; k < 16; ++k) s += sbv[k][tid];
    } else {
        int c = tid - 128;
#pragma unroll
        for (int k = 0; k < 16; ++k) s += sbq[k][c];
    }
    partial[(size_t)blockIdx.x * 256 + tid] = s;
}

// ---------------- reduce partials -> stats (low-contention atomics) -------
__global__ __launch_bounds__(256) void k_bn_red(const float* __restrict__ partial,
                                                float* __restrict__ stats) {
    int r0 = blockIdx.x * 25;
    int r1 = min(r0 + 25, NAGG);
    int t = threadIdx.x;
    float s = 0.f;
    for (int r = r0; r < r1; ++r) s += partial[(size_t)r * 256 + t];
    atomAddF(&stats[t], s);
}

__global__ void k_bn_final(const float* __restrict__ stats,
                           const float* __restrict__ gamma,
                           const float* __restrict__ beta,
                           float* __restrict__ sc, float* __restrict__ sh) {
    int c = threadIdx.x;
    if (c < DD) {
        float mu = stats[c] * (1.0f / NN);
        float var = stats[DD + c] * (1.0f / NN) - mu * mu;
        float inv = rsqrtf(var + EPSBN);
        float s = gamma[c] * inv;
        sc[c] = s;
        sh[c] = beta[c] - mu * s;  // conv bias b cancels in BN exactly
    }
}

// ---------------- pooling (fused final BN+ReLU), vectorized ---------------
// 196 blocks x 512 nodes; thread = (rowgroup tid>>4, lane tid&15);
// each thread: 8 cols via one uint4/row, ~32 rows, run-length + atomic flush
__global__ __launch_bounds__(256) void k_pool(const ushort* __restrict__ Ab,
                                              const int* __restrict__ batch,
                                              const float* __restrict__ sc,
                                              const float* __restrict__ sh,
                                              float* __restrict__ out) {
    __shared__ int bsh[512];
    const int tid = threadIdx.x;
    const int lane = tid & 15, rg = tid >> 4;
    const int c0 = lane * 8;
    const int v0 = blockIdx.x * 512;
    const int v1 = min(v0 + 512, NN);
    for (int i = tid; i < v1 - v0; i += 256) bsh[i] = batch[v0 + i];
    __syncthreads();

    float s[8], t[8];
#pragma unroll
    for (int i = 0; i < 8; ++i) {
        s[i] = sc[c0 + i];
        t[i] = sh[c0 + i];
    }
    float acc[8] = {0.f, 0.f, 0.f, 0.f, 0.f, 0.f, 0.f, 0.f};
    int g = -1;
    for (int v = v0 + rg; v < v1; v += 16) {
        int bg = bsh[v - v0];
        if (bg != g) {
            if (g >= 0) {
                float* op = &out[(size_t)g * DD + c0];
#pragma unroll
                for (int i = 0; i < 8; ++i) atomAddF(op + i, acc[i]);
            }
            g = bg;
#pragma unroll
            for (int i = 0; i < 8; ++i) acc[i] = 0.f;
        }
        uint4 a = *(const uint4*)&Ab[(size_t)v * DD + c0];
        float x0 = __uint_as_float(a.x << 16);
        float x1 = __uint_as_float(a.x & 0xffff0000u);
        float x2 = __uint_as_float(a.y << 16);
        float x3 = __uint_as_float(a.y & 0xffff0000u);
        float x4 = __uint_as_float(a.z << 16);
        float x5 = __uint_as_float(a.z & 0xffff0000u);
        float x6 = __uint_as_float(a.w << 16);
        float x7 = __uint_as_float(a.w & 0xffff0000u);
        acc[0] += fmaxf(fmaf(x0, s[0], t[0]), 0.f);
        acc[1] += fmaxf(fmaf(x1, s[1], t[1]), 0.f);
        acc[2] += fmaxf(fmaf(x2, s[2], t[2]), 0.f);
        acc[3] += fmaxf(fmaf(x3, s[3], t[3]), 0.f);
        acc[4] += fmaxf(fmaf(x4, s[4], t[4]), 0.f);
        acc[5] += fmaxf(fmaf(x5, s[5], t[5]), 0.f);
        acc[6] += fmaxf(fmaf(x6, s[6], t[6]), 0.f);
        acc[7] += fmaxf(fmaf(x7, s[7], t[7]), 0.f);
    }
    if (g >= 0) {
        float* op = &out[(size_t)g * DD + c0];
#pragma unroll
        for (int i = 0; i < 8; ++i) atomAddF(op + i, acc[i]);
    }
}

extern "C" void kernel_launch(void* const* d_in, const int* in_sizes, int n_in,
                              void* d_out, int out_size, void* d_ws, size_t ws_size,
                              hipStream_t stream) {
    const float* x     = (const float*)d_in[0];
    const int*   ei    = (const int*)d_in[1];
    const float* ew    = (const float*)d_in[2];
    const int*   batch = (const int*)d_in[3];
    const float* W     = (const float*)d_in[4];
    // d_in[5] = b — cancels exactly in training-mode BatchNorm, unused
    const float* gamma = (const float*)d_in[6];
    const float* beta  = (const float*)d_in[7];
    float* out = (float*)d_out;

    float* wsp   = (float*)d_ws;
    float* dinv  = wsp;                            // N
    float* stats = dinv + NN;                      // 768
    float* scl   = stats + 768;                    // 3 x 128
    float* shl   = scl + 3 * DD;                   // 3 x 128
    ushort* Wt   = (ushort*)(shl + 3 * DD);        // 3 x D x D bf16
    unsigned char* H = (unsigned char*)(Wt + (size_t)NL * DD * DD);  // N*D fp8
    ushort* Ab   = (ushort*)(H + (size_t)NN * DD); // N*D bf16
    int2*  srcw  = (int2*)(Ab + (size_t)NN * DD);  // E packed records
    float* partial = (float*)(srcw + NE);          // NAGG x 256
    int*   row_off = (int*)(partial + (size_t)NAGG * 256);  // N+4
    int*   gbcnt = row_off + NN + 4;               // NBUCK
    int*   boff  = gbcnt + NBUCK;                  // NBUCK+4 (padded)
    int*   gcur  = boff + NBUCK + 4;               // NBUCK
    int2*  csr   = (int2*)(gcur + NBUCK);          // E * 8B
    // total ≈ 71 MiB

    k_zero_fo<<<(NG * DD + 768 + NBUCK + 255) / 256, 256, 0, stream>>>(out, stats, gbcnt);

    // bucket-staged CSR build
    k_bcnt<<<256, 256, 0, stream>>>(ei, gbcnt);
    k_bscan<<<1, 256, 0, stream>>>(gbcnt, boff, gcur);
    k_bscatter<<<256, 256, 0, stream>>>(ei, ew, gcur, srcw);
    k_bsort<<<NBUCK, 256, 0, stream>>>(srcw, boff, row_off, csr);

    // degrees + norms from CSR (atomic-free)
    k_degdinv<<<(NN + 255) / 256, 256, 0, stream>>>(csr, row_off, dinv);
    k_nrm2<<<(NN + 255) / 256, 256, 0, stream>>>(csr, row_off, dinv);

    // W -> bf16 transposed [n][k]
    k_wprep<<<(NL * DD * DD + 255) / 256, 256, 0, stream>>>(W, Wt);

    for (int l = 0; l < NL; ++l) {
        const float* sc_prev = (l > 0) ? scl + (l - 1) * DD : scl;
        const float* sh_prev = (l > 0) ? shl + (l - 1) * DD : shl;
        k_gemm3<<<(NN + 127) / 128, 256, 0, stream>>>(
            x, Ab, Wt + (size_t)l * DD * DD, sc_prev, sh_prev, l > 0 ? 1 : 0, H);
        k_agg3<<<NAGG, 256, 0, stream>>>(csr, row_off, dinv, H, Ab, partial);
        k_bn_red<<<(NAGG + 24) / 25, 256, 0, stream>>>(partial, stats + l * 256);
        k_bn_final<<<1, 128, 0, stream>>>(stats + l * 256, gamma + (size_t)l * DD,
                                          beta + (size_t)l * DD,
                                          scl + l * DD, shl + l * DD);
    }

    k_pool<<<NBUCK, 256, 0, stream>>>(Ab, batch, scl + 2 * DD, shl + 2 * DD, out);
}

// Round 14
// 342.998 us; speedup vs baseline: 25.3478x; 1.0311x over previous
//
#include <hip/hip_runtime.h>

#define NN 100000   // nodes
#define NE 1600000  // edges
#define DD 128      // feature dim
#define NL 3        // layers
#define NG 64       // graphs
#define EPSBN 1e-5f
#define NBUCK 196               // ceil(NN/512) buckets of 512 nodes
#define NAGG (NN / 16)          // 6250 agg blocks (16 nodes each)

typedef __attribute__((ext_vector_type(8))) short short8v;   // 8 bf16 (4 VGPR)
typedef __attribute__((ext_vector_type(4))) float float4v;   // MFMA C/D
typedef __attribute__((ext_vector_type(2))) float float2v;   // fp8 cvt result

// ---- fp32 atomic add (HW global_atomic_add_f32, no CAS loop) ----
__device__ inline void atomAddF(float* p, float v) {
#if defined(__AMDGCN__)
    unsafeAtomicAdd(p, v);
#else
    atomicAdd(p, v);
#endif
}

// ---- fp32 -> bf16 round-to-nearest-even ----
__device__ inline ushort f2bf(float f) {
    uint u = __float_as_uint(f);
    uint r = ((u >> 16) & 1u) + 0x7fffu;
    return (ushort)((u + r) >> 16);
}

// ---- fp32 -> fp8 e4m3 (OCP, HW convert) ----
__device__ inline uint f2fp8(float f) {
    return (uint)__builtin_amdgcn_cvt_pk_fp8_f32(f, f, 0, false) & 0xffu;
}

// ---- accumulate 8 fp8 lanes (packed in uint2) scaled by wgt into acc[8] ----
__device__ inline void accf8(float (&acc)[8], uint2 g, float wgt) {
    float2v p0 = __builtin_amdgcn_cvt_pk_f32_fp8(g.x, false);
    float2v p1 = __builtin_amdgcn_cvt_pk_f32_fp8(g.x, true);
    float2v p2 = __builtin_amdgcn_cvt_pk_f32_fp8(g.y, false);
    float2v p3 = __builtin_amdgcn_cvt_pk_f32_fp8(g.y, true);
    acc[0] = fmaf(wgt, p0[0], acc[0]);
    acc[1] = fmaf(wgt, p0[1], acc[1]);
    acc[2] = fmaf(wgt, p1[0], acc[2]);
    acc[3] = fmaf(wgt, p1[1], acc[3]);
    acc[4] = fmaf(wgt, p2[0], acc[4]);
    acc[5] = fmaf(wgt, p2[1], acc[5]);
    acc[6] = fmaf(wgt, p3[0], acc[6]);
    acc[7] = fmaf(wgt, p3[1], acc[7]);
}

// ---------------- init (out, stats, bucket counters) + W prep --------------
// index space: [0,49152) Wt bf16-transpose; then out, stats, gbcnt
__global__ __launch_bounds__(256) void k_zero_fo(const float* __restrict__ W,
                                                 ushort* __restrict__ Wt,
                                                 float* __restrict__ out,
                                                 float* __restrict__ stats,
                                                 int* __restrict__ gbcnt) {
    int i = blockIdx.x * 256 + threadIdx.x;
    if (i < NL * DD * DD) {
        int l = i >> 14, r = i & 16383;
        int k = r >> 7, n = r & 127;
        Wt[(size_t)l * DD * DD + n * DD + k] = f2bf(W[i]);
        return;
    }
    int j = i - NL * DD * DD;
    if (j < NG * DD) { out[j] = 0.f; return; }
    j -= NG * DD;
    if (j < 768) { stats[j] = 0.f; return; }
    j -= 768;
    if (j < NBUCK) gbcnt[j] = 0;
}

// ---------------- bucket histogram over dst ----------------
__global__ __launch_bounds__(256) void k_bcnt(const int* __restrict__ ei,
                                              int* __restrict__ gbcnt) {
    __shared__ int lh[NBUCK];
    int tid = threadIdx.x;
    if (tid < NBUCK) lh[tid] = 0;
    __syncthreads();
    for (int e = blockIdx.x * 256 + tid; e < NE; e += 256 * 256)
        atomicAdd(&lh[ei[NE + e] >> 9], 1);
    __syncthreads();
    if (tid < NBUCK) atomicAdd(&gbcnt[tid], lh[tid]);
}

// ---------------- bucket scan: boff (exclusive) + cursor init -------------
__global__ __launch_bounds__(256) void k_bscan(const int* __restrict__ gbcnt,
                                               int* __restrict__ boff,
                                               int* __restrict__ gcur) {
    __shared__ int s[256];
    int t = threadIdx.x;
    int v = (t < NBUCK) ? gbcnt[t] : 0;
    s[t] = v;
    __syncthreads();
    for (int off = 1; off < 256; off <<= 1) {
        int add = (t >= off) ? s[t - off] : 0;
        __syncthreads();
        s[t] += add;
        __syncthreads();
    }
    if (t < NBUCK) {
        int ex = s[t] - v;
        boff[t] = ex;
        gcur[t] = ex;
    }
    if (t == NBUCK - 1) boff[NBUCK] = s[t];  // = NE
}

// ---------------- scatter edges into bucket regions (run-staged) ----------
// 256 blocks x 6250 edges; record packs src (17b) | dst-local (9b) + ew
__global__ __launch_bounds__(256) void k_bscatter(const int* __restrict__ ei,
                                                  const float* __restrict__ ew,
                                                  int* __restrict__ gcur,
                                                  int2* __restrict__ srcw) {
    __shared__ int hist[NBUCK], base[NBUCK], cur[NBUCK];
    const int tid = threadIdx.x;
    const int e0 = blockIdx.x * 6250, e1 = e0 + 6250;
    if (tid < NBUCK) hist[tid] = 0;
    __syncthreads();
    for (int e = e0 + tid; e < e1; e += 256)
        atomicAdd(&hist[ei[NE + e] >> 9], 1);
    __syncthreads();
    if (tid < NBUCK) {
        base[tid] = atomicAdd(&gcur[tid], hist[tid]);
        cur[tid] = 0;
    }
    __syncthreads();
    for (int e = e0 + tid; e < e1; e += 256) {
        int d = ei[NE + e];
        int b = d >> 9;
        int p = base[b] + atomicAdd(&cur[b], 1);
        int2 sw;
        sw.x = ei[e] | ((d & 511) << 17);
        sw.y = __float_as_int(ew[e]);
        srcw[p] = sw;
    }
}

// ---------------- per-bucket counting sort -> CSR + row_off + dinv --------
// fused degree accumulation (LDS float atomics) kills the k_degdinv pass
__global__ __launch_bounds__(256) void k_bsort(const int2* __restrict__ srcw,
                                               const int* __restrict__ boff,
                                               int* __restrict__ row_off,
                                               int2* __restrict__ csr,
                                               float* __restrict__ dinv) {
    __shared__ int h0[512], h1[512], exc[512], cur[512];
    __shared__ float degacc[512];
    const int tid = threadIdx.x;
    const int b = blockIdx.x;
    const int p0 = boff[b], p1 = boff[b + 1];
    const int nbn = min(512, NN - (b << 9));

    for (int i = tid; i < 512; i += 256) {
        h0[i] = 0;
        degacc[i] = 0.f;
    }
    __syncthreads();
    for (int p = p0 + tid; p < p1; p += 256)
        atomicAdd(&h0[(srcw[p].x >> 17) & 511], 1);
    __syncthreads();

    int* sA = h0;
    int* sB = h1;
    for (int off = 1; off < 512; off <<= 1) {
        for (int i = tid; i < 512; i += 256) {
            int v = sA[i];
            if (i >= off) v += sA[i - off];
            sB[i] = v;
        }
        __syncthreads();
        int* tp = sA; sA = sB; sB = tp;
    }
    for (int i = tid; i < 512; i += 256) {
        exc[i] = (i == 0) ? 0 : sA[i - 1];
        cur[i] = 0;
    }
    __syncthreads();

    for (int n = tid; n < nbn; n += 256)
        row_off[(b << 9) + n] = p0 + exc[n];
    if (b == NBUCK - 1 && tid == 0) row_off[NN] = NE;

    for (int p = p0 + tid; p < p1; p += 256) {
        int2 sw = srcw[p];
        int dl = (sw.x >> 17) & 511;
        int q = p0 + exc[dl] + atomicAdd(&cur[dl], 1);
        int2 outv;
        outv.x = sw.x & 0x1FFFF;   // clean src
        outv.y = sw.y;             // raw ew
        csr[q] = outv;
        atomicAdd(&degacc[dl], __int_as_float(sw.y));
    }
    __syncthreads();
    for (int n = tid; n < nbn; n += 256)
        dinv[(b << 9) + n] = rsqrtf(1.0f + degacc[n]);  // 1 = self-loop
}

// csr[j].y <- dinv[dst] * ew * dinv[src]  (in place)
__global__ __launch_bounds__(256) void k_nrm2(int2* __restrict__ csr,
                                              const int* __restrict__ row_off,
                                              const float* __restrict__ dinv) {
    int node = blockIdx.x * 256 + threadIdx.x;
    if (node >= NN) return;
    int beg = row_off[node], end = row_off[node + 1];
    float dv = dinv[node];
    int* y = (int*)csr;
    for (int j = beg; j < end; ++j) {
        int2 e = csr[j];
        float nw = dv * __int_as_float(e.y) * dinv[e.x];
        y[2 * (size_t)j + 1] = __float_as_int(nw);
    }
}

// ---------------- MFMA GEMM: H = act(X) @ W, H stored fp8 e4m3 -------------
// 2x 64-row sub-tiles per block (W staged once), 49KB LDS -> 3 blocks/CU.
// BN coefs computed in-kernel from stats (no separate bn_final).
__global__ __launch_bounds__(256, 3) void k_gemm4(const float* __restrict__ X,
                                                  const ushort* __restrict__ Xb,
                                                  const ushort* __restrict__ Wt,
                                                  const float* __restrict__ stats,
                                                  const float* __restrict__ gamma,
                                                  const float* __restrict__ beta,
                                                  int applyBN,
                                                  unsigned char* __restrict__ H) {
    __shared__ ushort ws[128 * 128];   // 32KB [n][k] bf16, swizzled
    __shared__ ushort xs[64 * 128];    // 16KB [row][k] bf16, swizzled
    __shared__ float scs[DD], shs[DD];
    const int tid = threadIdx.x;

    // stage W (2048 chunks of 8 bf16)
    for (int c = tid; c < 2048; c += 256) {
        int n = c >> 4, k8 = (c & 15) * 8;
        uint4 w = *(const uint4*)&Wt[n * DD + k8];
        int idx = n * 128 + (((k8 * 2) ^ ((n & 7) << 4)) >> 1);
        *(uint4*)&ws[idx] = w;
    }
    // BN coefficients of the previous layer (identical formula to old bn_final)
    if (applyBN && tid < DD) {
        float mu = stats[tid] * (1.0f / NN);
        float var = stats[DD + tid] * (1.0f / NN) - mu * mu;
        float inv = rsqrtf(var + EPSBN);
        float s = gamma[tid] * inv;
        scs[tid] = s;
        shs[tid] = beta[tid] - mu * s;
    }

    const int wid = tid >> 6, lane = tid & 63;
    const int wm = wid >> 1, wn = wid & 1;       // 2x2 waves: 32 rows x 64 cols
    const int lrow = lane & 15, lk = lane >> 4;

#pragma unroll
    for (int t = 0; t < 2; ++t) {
        int row0 = (blockIdx.x * 2 + t) * 64;
        if (row0 >= NN) break;
        __syncthreads();   // ws/coefs ready (t=0); xs free of readers (t=1)

        // stage X sub-tile: 64 rows x 16 chunks
        for (int c = tid; c < 1024; c += 256) {
            int r = c >> 4, k8 = (c & 15) * 8;
            int gr = row0 + r;
            float v[8];
            if (applyBN) {
                uint4 g = (gr < NN) ? *(const uint4*)&Xb[(size_t)gr * DD + k8]
                                    : make_uint4(0u, 0u, 0u, 0u);
                v[0] = __uint_as_float(g.x << 16);
                v[1] = __uint_as_float(g.x & 0xffff0000u);
                v[2] = __uint_as_float(g.y << 16);
                v[3] = __uint_as_float(g.y & 0xffff0000u);
                v[4] = __uint_as_float(g.z << 16);
                v[5] = __uint_as_float(g.z & 0xffff0000u);
                v[6] = __uint_as_float(g.w << 16);
                v[7] = __uint_as_float(g.w & 0xffff0000u);
#pragma unroll
                for (int i = 0; i < 8; ++i)
                    v[i] = fmaxf(fmaf(v[i], scs[k8 + i], shs[k8 + i]), 0.f);
            } else {
                if (gr < NN) {
                    float4 a = *(const float4*)&X[(size_t)gr * DD + k8];
                    float4 b = *(const float4*)&X[(size_t)gr * DD + k8 + 4];
                    v[0] = a.x; v[1] = a.y; v[2] = a.z; v[3] = a.w;
                    v[4] = b.x; v[5] = b.y; v[6] = b.z; v[7] = b.w;
                } else {
#pragma unroll
                    for (int i = 0; i < 8; ++i) v[i] = 0.f;
                }
            }
            uint4 st;
            st.x = (uint)f2bf(v[0]) | ((uint)f2bf(v[1]) << 16);
            st.y = (uint)f2bf(v[2]) | ((uint)f2bf(v[3]) << 16);
            st.z = (uint)f2bf(v[4]) | ((uint)f2bf(v[5]) << 16);
            st.w = (uint)f2bf(v[6]) | ((uint)f2bf(v[7]) << 16);
            int idx = r * 128 + (((k8 * 2) ^ ((r & 7) << 4)) >> 1);
            *(uint4*)&xs[idx] = st;
        }
        __syncthreads();

        float4v acc[2][4];
#pragma unroll
        for (int i = 0; i < 2; ++i)
#pragma unroll
            for (int j = 0; j < 4; ++j) acc[i][j] = (float4v){0.f, 0.f, 0.f, 0.f};

#pragma unroll
        for (int ks = 0; ks < 4; ++ks) {
            int kbyte = ks * 64 + lk * 16;
            short8v a[2], b[4];
#pragma unroll
            for (int mg = 0; mg < 2; ++mg) {
                int r = wm * 32 + mg * 16 + lrow;
                a[mg] = *(const short8v*)&xs[r * 128 + ((kbyte ^ ((r & 7) << 4)) >> 1)];
            }
#pragma unroll
            for (int ng = 0; ng < 4; ++ng) {
                int n = wn * 64 + ng * 16 + lrow;
                b[ng] = *(const short8v*)&ws[n * 128 + ((kbyte ^ ((n & 7) << 4)) >> 1)];
            }
#pragma unroll
            for (int mg = 0; mg < 2; ++mg)
#pragma unroll
                for (int ng = 0; ng < 4; ++ng)
                    acc[mg][ng] = __builtin_amdgcn_mfma_f32_16x16x32_bf16(
                        a[mg], b[ng], acc[mg][ng], 0, 0, 0);
        }

        // C/D layout: col = lane&15, row = (lane>>4)*4 + reg  [m89]
#pragma unroll
        for (int mg = 0; mg < 2; ++mg) {
            int rbase = row0 + wm * 32 + mg * 16 + lk * 4;
#pragma unroll
            for (int j = 0; j < 4; ++j) {
                int gr = rbase + j;
                if (gr < NN) {
#pragma unroll
                    for (int ng = 0; ng < 4; ++ng) {
                        int col = wn * 64 + ng * 16 + lrow;
                        H[(size_t)gr * DD + col] = (unsigned char)f2fp8(acc[mg][ng][j]);
                    }
                }
            }
        }
    }
}

// ---------------- aggregation + fused BN partial stats --------------------
// fp8 H: 16 lanes/node, 8 cols/lane (uint2 = 8 fp8); unroll 8; A bf16
__global__ __launch_bounds__(256) void k_agg3(const int2* __restrict__ csr,
                                              const int* __restrict__ row_off,
                                              const float* __restrict__ dinv,
                                              const unsigned char* __restrict__ H,
                                              ushort* __restrict__ Ab,
                                              float* __restrict__ partial) {
    __shared__ float sbv[16][128];
    __shared__ float sbq[16][128];
    const int tid = threadIdx.x;
    int node = blockIdx.x * 16 + (tid >> 4);
    int h = tid & 15;
    int beg = row_off[node], end = row_off[node + 1];
    float dv = dinv[node];
    size_t cb = (size_t)node * DD + h * 8;   // byte index
    float acc[8] = {0.f, 0.f, 0.f, 0.f, 0.f, 0.f, 0.f, 0.f};
    {
        uint2 v = *(const uint2*)&H[cb];
        accf8(acc, v, dv * dv);  // self-loop term
    }

    int j = beg;
    for (; j + 8 <= end; j += 8) {
        int2 e0 = csr[j], e1 = csr[j + 1], e2 = csr[j + 2], e3 = csr[j + 3];
        int2 e4 = csr[j + 4], e5 = csr[j + 5], e6 = csr[j + 6], e7 = csr[j + 7];
        uint2 g0 = *(const uint2*)&H[(size_t)e0.x * DD + h * 8];
        uint2 g1 = *(const uint2*)&H[(size_t)e1.x * DD + h * 8];
        uint2 g2 = *(const uint2*)&H[(size_t)e2.x * DD + h * 8];
        uint2 g3 = *(const uint2*)&H[(size_t)e3.x * DD + h * 8];
        uint2 g4 = *(const uint2*)&H[(size_t)e4.x * DD + h * 8];
        uint2 g5 = *(const uint2*)&H[(size_t)e5.x * DD + h * 8];
        uint2 g6 = *(const uint2*)&H[(size_t)e6.x * DD + h * 8];
        uint2 g7 = *(const uint2*)&H[(size_t)e7.x * DD + h * 8];
        accf8(acc, g0, __int_as_float(e0.y));
        accf8(acc, g1, __int_as_float(e1.y));
        accf8(acc, g2, __int_as_float(e2.y));
        accf8(acc, g3, __int_as_float(e3.y));
        accf8(acc, g4, __int_as_float(e4.y));
        accf8(acc, g5, __int_as_float(e5.y));
        accf8(acc, g6, __int_as_float(e6.y));
        accf8(acc, g7, __int_as_float(e7.y));
    }
    for (; j + 4 <= end; j += 4) {
        int2 e0 = csr[j], e1 = csr[j + 1], e2 = csr[j + 2], e3 = csr[j + 3];
        uint2 g0 = *(const uint2*)&H[(size_t)e0.x * DD + h * 8];
        uint2 g1 = *(const uint2*)&H[(size_t)e1.x * DD + h * 8];
        uint2 g2 = *(const uint2*)&H[(size_t)e2.x * DD + h * 8];
        uint2 g3 = *(const uint2*)&H[(size_t)e3.x * DD + h * 8];
        accf8(acc, g0, __int_as_float(e0.y));
        accf8(acc, g1, __int_as_float(e1.y));
        accf8(acc, g2, __int_as_float(e2.y));
        accf8(acc, g3, __int_as_float(e3.y));
    }
    for (; j < end; ++j) {
        int2 e = csr[j];
        uint2 g = *(const uint2*)&H[(size_t)e.x * DD + h * 8];
        accf8(acc, g, __int_as_float(e.y));
    }

    // write A in bf16 (ushort index = byte index of fp8 layout)
    uint4 st;
    st.x = (uint)f2bf(acc[0]) | ((uint)f2bf(acc[1]) << 16);
    st.y = (uint)f2bf(acc[2]) | ((uint)f2bf(acc[3]) << 16);
    st.z = (uint)f2bf(acc[4]) | ((uint)f2bf(acc[5]) << 16);
    st.w = (uint)f2bf(acc[6]) | ((uint)f2bf(acc[7]) << 16);
    *(uint4*)&Ab[cb] = st;

    // fused BN partial stats from fp32 accumulators
    int n = tid >> 4, c0 = h * 8;
#pragma unroll
    for (int i = 0; i < 8; ++i) {
        float a = acc[i];
        sbv[n][c0 + i] = a;
        sbq[n][c0 + i] = a * a;
    }
    __syncthreads();
    float s = 0.f;
    if (tid < 128) {
#pragma unroll
        for (int k = 0; k < 16; ++k) s += sbv[k][tid];
    } else {
        int c = tid - 128;
#pragma unroll
        for (int k = 0; k < 16; ++k) s += sbq[k][c];
    }
    partial[(size_t)blockIdx.x * 256 + tid] = s;
}

// ---------------- reduce partials -> stats (low-contention atomics) -------
__global__ __launch_bounds__(256) void k_bn_red(const float* __restrict__ partial,
                                                float* __restrict__ stats) {
    int r0 = blockIdx.x * 25;
    int r1 = min(r0 + 25, NAGG);
    int t = threadIdx.x;
    float s = 0.f;
    for (int r = r0; r < r1; ++r) s += partial[(size_t)r * 256 + t];
    atomAddF(&stats[t], s);
}

// ---------------- pooling (fused final BN+ReLU), vectorized ---------------
// BN coefs computed in-kernel from stats
__global__ __launch_bounds__(256) void k_pool(const ushort* __restrict__ Ab,
                                              const int* __restrict__ batch,
                                              const float* __restrict__ stats,
                                              const float* __restrict__ gamma,
                                              const float* __restrict__ beta,
                                              float* __restrict__ out) {
    __shared__ int bsh[512];
    __shared__ float scs[DD], shs[DD];
    const int tid = threadIdx.x;
    const int lane = tid & 15, rg = tid >> 4;
    const int c0 = lane * 8;
    const int v0 = blockIdx.x * 512;
    const int v1 = min(v0 + 512, NN);
    for (int i = tid; i < v1 - v0; i += 256) bsh[i] = batch[v0 + i];
    if (tid < DD) {
        float mu = stats[tid] * (1.0f / NN);
        float var = stats[DD + tid] * (1.0f / NN) - mu * mu;
        float inv = rsqrtf(var + EPSBN);
        float s = gamma[tid] * inv;
        scs[tid] = s;
        shs[tid] = beta[tid] - mu * s;
    }
    __syncthreads();

    float s[8], t[8];
#pragma unroll
    for (int i = 0; i < 8; ++i) {
        s[i] = scs[c0 + i];
        t[i] = shs[c0 + i];
    }
    float acc[8] = {0.f, 0.f, 0.f, 0.f, 0.f, 0.f, 0.f, 0.f};
    int g = -1;
    for (int v = v0 + rg; v < v1; v += 16) {
        int bg = bsh[v - v0];
        if (bg != g) {
            if (g >= 0) {
                float* op = &out[(size_t)g * DD + c0];
#pragma unroll
                for (int i = 0; i < 8; ++i) atomAddF(op + i, acc[i]);
            }
            g = bg;
#pragma unroll
            for (int i = 0; i < 8; ++i) acc[i] = 0.f;
        }
        uint4 a = *(const uint4*)&Ab[(size_t)v * DD + c0];
        float x0 = __uint_as_float(a.x << 16);
        float x1 = __uint_as_float(a.x & 0xffff0000u);
        float x2 = __uint_as_float(a.y << 16);
        float x3 = __uint_as_float(a.y & 0xffff0000u);
        float x4 = __uint_as_float(a.z << 16);
        float x5 = __uint_as_float(a.z & 0xffff0000u);
        float x6 = __uint_as_float(a.w << 16);
        float x7 = __uint_as_float(a.w & 0xffff0000u);
        acc[0] += fmaxf(fmaf(x0, s[0], t[0]), 0.f);
        acc[1] += fmaxf(fmaf(x1, s[1], t[1]), 0.f);
        acc[2] += fmaxf(fmaf(x2, s[2], t[2]), 0.f);
        acc[3] += fmaxf(fmaf(x3, s[3], t[3]), 0.f);
        acc[4] += fmaxf(fmaf(x4, s[4], t[4]), 0.f);
        acc[5] += fmaxf(fmaf(x5, s[5], t[5]), 0.f);
        acc[6] += fmaxf(fmaf(x6, s[6], t[6]), 0.f);
        acc[7] += fmaxf(fmaf(x7, s[7], t[7]), 0.f);
    }
    if (g >= 0) {
        float* op = &out[(size_t)g * DD + c0];
#pragma unroll
        for (int i = 0; i < 8; ++i) atomAddF(op + i, acc[i]);
    }
}

extern "C" void kernel_launch(void* const* d_in, const int* in_sizes, int n_in,
                              void* d_out, int out_size, void* d_ws, size_t ws_size,
                              hipStream_t stream) {
    const float* x     = (const float*)d_in[0];
    const int*   ei    = (const int*)d_in[1];
    const float* ew    = (const float*)d_in[2];
    const int*   batch = (const int*)d_in[3];
    const float* W     = (const float*)d_in[4];
    // d_in[5] = b — cancels exactly in training-mode BatchNorm, unused
    const float* gamma = (const float*)d_in[6];
    const float* beta  = (const float*)d_in[7];
    float* out = (float*)d_out;

    float* wsp   = (float*)d_ws;
    float* dinv  = wsp;                            // N
    float* stats = dinv + NN;                      // 768
    ushort* Wt   = (ushort*)(stats + 768);         // 3 x D x D bf16
    unsigned char* H = (unsigned char*)(Wt + (size_t)NL * DD * DD);  // N*D fp8
    ushort* Ab   = (ushort*)(H + (size_t)NN * DD); // N*D bf16
    int2*  srcw  = (int2*)(Ab + (size_t)NN * DD);  // E packed records
    float* partial = (float*)(srcw + NE);          // NAGG x 256
    int*   row_off = (int*)(partial + (size_t)NAGG * 256);  // N+4
    int*   gbcnt = row_off + NN + 4;               // NBUCK
    int*   boff  = gbcnt + NBUCK;                  // NBUCK+4 (padded)
    int*   gcur  = boff + NBUCK + 4;               // NBUCK
    int2*  csr   = (int2*)(gcur + NBUCK);          // E * 8B
    // total ≈ 71 MiB

    // init + W prep (one kernel): 49152 + 8192 + 768 + 196 threads
    k_zero_fo<<<(NL * DD * DD + NG * DD + 768 + NBUCK + 255) / 256, 256, 0,
                stream>>>(W, Wt, out, stats, gbcnt);

    // bucket-staged CSR build (bsort also emits dinv)
    k_bcnt<<<256, 256, 0, stream>>>(ei, gbcnt);
    k_bscan<<<1, 256, 0, stream>>>(gbcnt, boff, gcur);
    k_bscatter<<<256, 256, 0, stream>>>(ei, ew, gcur, srcw);
    k_bsort<<<NBUCK, 256, 0, stream>>>(srcw, boff, row_off, csr, dinv);
    k_nrm2<<<(NN + 255) / 256, 256, 0, stream>>>(csr, row_off, dinv);

    for (int l = 0; l < NL; ++l) {
        const float* st_prev = stats + (l - 1) * 256;   // unused when l==0
        const float* ga_prev = gamma + (size_t)(l > 0 ? l - 1 : 0) * DD;
        const float* be_prev = beta + (size_t)(l > 0 ? l - 1 : 0) * DD;
        k_gemm4<<<(NN + 127) / 128, 256, 0, stream>>>(
            x, Ab, Wt + (size_t)l * DD * DD, l > 0 ? st_prev : stats,
            ga_prev, be_prev, l > 0 ? 1 : 0, H);
        k_agg3<<<NAGG, 256, 0, stream>>>(csr, row_off, dinv, H, Ab, partial);
        k_bn_red<<<(NAGG + 24) / 25, 256, 0, stream>>>(partial, stats + l * 256);
    }

    k_pool<<<NBUCK, 256, 0, stream>>>(Ab, batch, stats + 2 * 256,
                                      gamma + 2 * DD, beta + 2 * DD, out);
}

// Round 15
// 316.047 us; speedup vs baseline: 27.5093x; 1.0853x over previous
//
#include <hip/hip_runtime.h>

#define NN 100000   // nodes
#define NE 1600000  // edges
#define DD 128      // feature dim
#define NL 3        // layers
#define NG 64       // graphs
#define EPSBN 1e-5f
#define NBUCK 196               // ceil(NN/512) buckets of 512 nodes
#define NAGG (NN / 16)          // 6250 agg blocks (16 nodes each)

typedef __attribute__((ext_vector_type(8))) short short8v;   // 8 bf16 (4 VGPR)
typedef __attribute__((ext_vector_type(4))) float float4v;   // MFMA C/D
typedef __attribute__((ext_vector_type(2))) float float2v;   // fp8 cvt result

// ---- fp32 atomic add (HW global_atomic_add_f32, no CAS loop) ----
__device__ inline void atomAddF(float* p, float v) {
#if defined(__AMDGCN__)
    unsafeAtomicAdd(p, v);
#else
    atomicAdd(p, v);
#endif
}

// ---- fp32 -> bf16 round-to-nearest-even ----
__device__ inline ushort f2bf(float f) {
    uint u = __float_as_uint(f);
    uint r = ((u >> 16) & 1u) + 0x7fffu;
    return (ushort)((u + r) >> 16);
}

// ---- fp32 -> fp8 e4m3 (OCP, HW convert) ----
__device__ inline uint f2fp8(float f) {
    return (uint)__builtin_amdgcn_cvt_pk_fp8_f32(f, f, 0, false) & 0xffu;
}

// ---- accumulate 8 fp8 lanes (packed in uint2) scaled by wgt into acc[8] ----
__device__ inline void accf8(float (&acc)[8], uint2 g, float wgt) {
    float2v p0 = __builtin_amdgcn_cvt_pk_f32_fp8(g.x, false);
    float2v p1 = __builtin_amdgcn_cvt_pk_f32_fp8(g.x, true);
    float2v p2 = __builtin_amdgcn_cvt_pk_f32_fp8(g.y, false);
    float2v p3 = __builtin_amdgcn_cvt_pk_f32_fp8(g.y, true);
    acc[0] = fmaf(wgt, p0[0], acc[0]);
    acc[1] = fmaf(wgt, p0[1], acc[1]);
    acc[2] = fmaf(wgt, p1[0], acc[2]);
    acc[3] = fmaf(wgt, p1[1], acc[3]);
    acc[4] = fmaf(wgt, p2[0], acc[4]);
    acc[5] = fmaf(wgt, p2[1], acc[5]);
    acc[6] = fmaf(wgt, p3[0], acc[6]);
    acc[7] = fmaf(wgt, p3[1], acc[7]);
}

// ---------------- init (out, stats, bucket counters) + W prep --------------
__global__ __launch_bounds__(256) void k_zero_fo(const float* __restrict__ W,
                                                 ushort* __restrict__ Wt,
                                                 float* __restrict__ out,
                                                 float* __restrict__ stats,
                                                 int* __restrict__ gbcnt) {
    int i = blockIdx.x * 256 + threadIdx.x;
    if (i < NL * DD * DD) {
        int l = i >> 14, r = i & 16383;
        int k = r >> 7, n = r & 127;
        Wt[(size_t)l * DD * DD + n * DD + k] = f2bf(W[i]);
        return;
    }
    int j = i - NL * DD * DD;
    if (j < NG * DD) { out[j] = 0.f; return; }
    j -= NG * DD;
    if (j < 768) { stats[j] = 0.f; return; }
    j -= 768;
    if (j < NBUCK) gbcnt[j] = 0;
}

// ---------------- bucket histogram over dst ----------------
__global__ __launch_bounds__(256) void k_bcnt(const int* __restrict__ ei,
                                              int* __restrict__ gbcnt) {
    __shared__ int lh[NBUCK];
    int tid = threadIdx.x;
    if (tid < NBUCK) lh[tid] = 0;
    __syncthreads();
    for (int e = blockIdx.x * 256 + tid; e < NE; e += 256 * 256)
        atomicAdd(&lh[ei[NE + e] >> 9], 1);
    __syncthreads();
    if (tid < NBUCK) atomicAdd(&gbcnt[tid], lh[tid]);
}

// ---------------- bucket scan: boff (exclusive) + cursor init -------------
__global__ __launch_bounds__(256) void k_bscan(const int* __restrict__ gbcnt,
                                               int* __restrict__ boff,
                                               int* __restrict__ gcur) {
    __shared__ int s[256];
    int t = threadIdx.x;
    int v = (t < NBUCK) ? gbcnt[t] : 0;
    s[t] = v;
    __syncthreads();
    for (int off = 1; off < 256; off <<= 1) {
        int add = (t >= off) ? s[t - off] : 0;
        __syncthreads();
        s[t] += add;
        __syncthreads();
    }
    if (t < NBUCK) {
        int ex = s[t] - v;
        boff[t] = ex;
        gcur[t] = ex;
    }
    if (t == NBUCK - 1) boff[NBUCK] = s[t];  // = NE
}

// ---------------- scatter edges into bucket regions (run-staged) ----------
__global__ __launch_bounds__(256) void k_bscatter(const int* __restrict__ ei,
                                                  const float* __restrict__ ew,
                                                  int* __restrict__ gcur,
                                                  int2* __restrict__ srcw) {
    __shared__ int hist[NBUCK], base[NBUCK], cur[NBUCK];
    const int tid = threadIdx.x;
    const int e0 = blockIdx.x * 6250, e1 = e0 + 6250;
    if (tid < NBUCK) hist[tid] = 0;
    __syncthreads();
    for (int e = e0 + tid; e < e1; e += 256)
        atomicAdd(&hist[ei[NE + e] >> 9], 1);
    __syncthreads();
    if (tid < NBUCK) {
        base[tid] = atomicAdd(&gcur[tid], hist[tid]);
        cur[tid] = 0;
    }
    __syncthreads();
    for (int e = e0 + tid; e < e1; e += 256) {
        int d = ei[NE + e];
        int b = d >> 9;
        int p = base[b] + atomicAdd(&cur[b], 1);
        int2 sw;
        sw.x = ei[e] | ((d & 511) << 17);
        sw.y = __float_as_int(ew[e]);
        srcw[p] = sw;
    }
}

// ---------------- per-bucket counting sort -> CSR + row_off + dinv --------
__global__ __launch_bounds__(256) void k_bsort(const int2* __restrict__ srcw,
                                               const int* __restrict__ boff,
                                               int* __restrict__ row_off,
                                               int2* __restrict__ csr,
                                               float* __restrict__ dinv) {
    __shared__ int h0[512], h1[512], exc[512], cur[512];
    __shared__ float degacc[512];
    const int tid = threadIdx.x;
    const int b = blockIdx.x;
    const int p0 = boff[b], p1 = boff[b + 1];
    const int nbn = min(512, NN - (b << 9));

    for (int i = tid; i < 512; i += 256) {
        h0[i] = 0;
        degacc[i] = 0.f;
    }
    __syncthreads();
    for (int p = p0 + tid; p < p1; p += 256)
        atomicAdd(&h0[(srcw[p].x >> 17) & 511], 1);
    __syncthreads();

    int* sA = h0;
    int* sB = h1;
    for (int off = 1; off < 512; off <<= 1) {
        for (int i = tid; i < 512; i += 256) {
            int v = sA[i];
            if (i >= off) v += sA[i - off];
            sB[i] = v;
        }
        __syncthreads();
        int* tp = sA; sA = sB; sB = tp;
    }
    for (int i = tid; i < 512; i += 256) {
        exc[i] = (i == 0) ? 0 : sA[i - 1];
        cur[i] = 0;
    }
    __syncthreads();

    for (int n = tid; n < nbn; n += 256)
        row_off[(b << 9) + n] = p0 + exc[n];
    if (b == NBUCK - 1 && tid == 0) row_off[NN] = NE;

    for (int p = p0 + tid; p < p1; p += 256) {
        int2 sw = srcw[p];
        int dl = (sw.x >> 17) & 511;
        int q = p0 + exc[dl] + atomicAdd(&cur[dl], 1);
        int2 outv;
        outv.x = sw.x & 0x1FFFF;   // clean src
        outv.y = sw.y;             // raw ew (normalized on the fly in agg)
        csr[q] = outv;
        atomicAdd(&degacc[dl], __int_as_float(sw.y));
    }
    __syncthreads();
    for (int n = tid; n < nbn; n += 256)
        dinv[(b << 9) + n] = rsqrtf(1.0f + degacc[n]);  // 1 = self-loop
}

// ---------------- MFMA GEMM: H = act(X) @ W, H stored fp8 e4m3 -------------
// 64 rows x 128 cols per block, 4 waves (16 rows each). A-fragments loaded
// DIRECTLY from global (BN+ReLU+bf16 in registers); only W in LDS (33KB)
// -> 4 blocks/CU, single __syncthreads.
__global__ __launch_bounds__(256, 4) void k_gemm5(const float* __restrict__ X,
                                                  const ushort* __restrict__ Xb,
                                                  const ushort* __restrict__ Wt,
                                                  const float* __restrict__ stats,
                                                  const float* __restrict__ gamma,
                                                  const float* __restrict__ beta,
                                                  int applyBN,
                                                  unsigned char* __restrict__ H) {
    __shared__ ushort ws[128 * 128];   // 32KB [n][k] bf16, swizzled
    __shared__ float scs[DD], shs[DD];
    const int tid = threadIdx.x;

    for (int c = tid; c < 2048; c += 256) {
        int n = c >> 4, k8 = (c & 15) * 8;
        uint4 w = *(const uint4*)&Wt[n * DD + k8];
        int idx = n * 128 + (((k8 * 2) ^ ((n & 7) << 4)) >> 1);
        *(uint4*)&ws[idx] = w;
    }
    if (applyBN && tid < DD) {
        float mu = stats[tid] * (1.0f / NN);
        float var = stats[DD + tid] * (1.0f / NN) - mu * mu;
        float inv = rsqrtf(var + EPSBN);
        float s = gamma[tid] * inv;
        scs[tid] = s;
        shs[tid] = beta[tid] - mu * s;
    }
    __syncthreads();

    const int wid = tid >> 6, lane = tid & 63;
    const int lrow = lane & 15, lk = lane >> 4;
    const int gr_a = blockIdx.x * 64 + wid * 16 + lrow;  // A row for this lane

    float4v acc[8];
#pragma unroll
    for (int i = 0; i < 8; ++i) acc[i] = (float4v){0.f, 0.f, 0.f, 0.f};

#pragma unroll
    for (int ks = 0; ks < 4; ++ks) {
        const int k8 = ks * 32 + lk * 8;   // this lane's 8 k-elements
        // A-fragment: load 8 values from global, BN+ReLU, pack bf16
        float v[8];
        if (applyBN) {
            uint4 g = (gr_a < NN) ? *(const uint4*)&Xb[(size_t)gr_a * DD + k8]
                                  : make_uint4(0u, 0u, 0u, 0u);
            v[0] = __uint_as_float(g.x << 16);
            v[1] = __uint_as_float(g.x & 0xffff0000u);
            v[2] = __uint_as_float(g.y << 16);
            v[3] = __uint_as_float(g.y & 0xffff0000u);
            v[4] = __uint_as_float(g.z << 16);
            v[5] = __uint_as_float(g.z & 0xffff0000u);
            v[6] = __uint_as_float(g.w << 16);
            v[7] = __uint_as_float(g.w & 0xffff0000u);
#pragma unroll
            for (int i = 0; i < 8; ++i)
                v[i] = fmaxf(fmaf(v[i], scs[k8 + i], shs[k8 + i]), 0.f);
        } else {
            if (gr_a < NN) {
                float4 a0 = *(const float4*)&X[(size_t)gr_a * DD + k8];
                float4 a1 = *(const float4*)&X[(size_t)gr_a * DD + k8 + 4];
                v[0] = a0.x; v[1] = a0.y; v[2] = a0.z; v[3] = a0.w;
                v[4] = a1.x; v[5] = a1.y; v[6] = a1.z; v[7] = a1.w;
            } else {
#pragma unroll
                for (int i = 0; i < 8; ++i) v[i] = 0.f;
            }
        }
        uint4 ap;
        ap.x = (uint)f2bf(v[0]) | ((uint)f2bf(v[1]) << 16);
        ap.y = (uint)f2bf(v[2]) | ((uint)f2bf(v[3]) << 16);
        ap.z = (uint)f2bf(v[4]) | ((uint)f2bf(v[5]) << 16);
        ap.w = (uint)f2bf(v[6]) | ((uint)f2bf(v[7]) << 16);
        short8v a = *(short8v*)&ap;

        const int kbyte = ks * 64 + lk * 16;
#pragma unroll
        for (int ng = 0; ng < 8; ++ng) {
            int n = ng * 16 + lrow;
            short8v b = *(const short8v*)&ws[n * 128 + ((kbyte ^ ((n & 7) << 4)) >> 1)];
            acc[ng] = __builtin_amdgcn_mfma_f32_16x16x32_bf16(a, b, acc[ng], 0, 0, 0);
        }
    }

    // C/D layout: col = lane&15, row = (lane>>4)*4 + reg  [m89]
    const int rbase = blockIdx.x * 64 + wid * 16 + lk * 4;
#pragma unroll
    for (int ng = 0; ng < 8; ++ng) {
        int col = ng * 16 + lrow;
#pragma unroll
        for (int j = 0; j < 4; ++j) {
            int gr = rbase + j;
            if (gr < NN)
                H[(size_t)gr * DD + col] = (unsigned char)f2fp8(acc[ng][j]);
        }
    }
}

// ---------------- aggregation + fused BN stats + on-the-fly norm ----------
// fp8 H; csr.y = RAW ew; w = ew*dinv[src] (broadcast load), final scale by dv
__global__ __launch_bounds__(256) void k_agg3(const int2* __restrict__ csr,
                                              const int* __restrict__ row_off,
                                              const float* __restrict__ dinv,
                                              const unsigned char* __restrict__ H,
                                              ushort* __restrict__ Ab,
                                              float* __restrict__ partial) {
    __shared__ float sbv[16][128];
    __shared__ float sbq[16][128];
    const int tid = threadIdx.x;
    int node = blockIdx.x * 16 + (tid >> 4);
    int h = tid & 15;
    int beg = row_off[node], end = row_off[node + 1];
    float dv = dinv[node];
    size_t cb = (size_t)node * DD + h * 8;   // byte index
    float acc[8] = {0.f, 0.f, 0.f, 0.f, 0.f, 0.f, 0.f, 0.f};
    {
        uint2 v = *(const uint2*)&H[cb];
        accf8(acc, v, dv);  // self-loop seed: dv*H[node]; final *dv gives dv^2
    }

    int j = beg;
    for (; j + 8 <= end; j += 8) {
        int2 e0 = csr[j], e1 = csr[j + 1], e2 = csr[j + 2], e3 = csr[j + 3];
        int2 e4 = csr[j + 4], e5 = csr[j + 5], e6 = csr[j + 6], e7 = csr[j + 7];
        float w0 = __int_as_float(e0.y) * dinv[e0.x];
        float w1 = __int_as_float(e1.y) * dinv[e1.x];
        float w2 = __int_as_float(e2.y) * dinv[e2.x];
        float w3 = __int_as_float(e3.y) * dinv[e3.x];
        float w4 = __int_as_float(e4.y) * dinv[e4.x];
        float w5 = __int_as_float(e5.y) * dinv[e5.x];
        float w6 = __int_as_float(e6.y) * dinv[e6.x];
        float w7 = __int_as_float(e7.y) * dinv[e7.x];
        uint2 g0 = *(const uint2*)&H[(size_t)e0.x * DD + h * 8];
        uint2 g1 = *(const uint2*)&H[(size_t)e1.x * DD + h * 8];
        uint2 g2 = *(const uint2*)&H[(size_t)e2.x * DD + h * 8];
        uint2 g3 = *(const uint2*)&H[(size_t)e3.x * DD + h * 8];
        uint2 g4 = *(const uint2*)&H[(size_t)e4.x * DD + h * 8];
        uint2 g5 = *(const uint2*)&H[(size_t)e5.x * DD + h * 8];
        uint2 g6 = *(const uint2*)&H[(size_t)e6.x * DD + h * 8];
        uint2 g7 = *(const uint2*)&H[(size_t)e7.x * DD + h * 8];
        accf8(acc, g0, w0);
        accf8(acc, g1, w1);
        accf8(acc, g2, w2);
        accf8(acc, g3, w3);
        accf8(acc, g4, w4);
        accf8(acc, g5, w5);
        accf8(acc, g6, w6);
        accf8(acc, g7, w7);
    }
    for (; j + 4 <= end; j += 4) {
        int2 e0 = csr[j], e1 = csr[j + 1], e2 = csr[j + 2], e3 = csr[j + 3];
        float w0 = __int_as_float(e0.y) * dinv[e0.x];
        float w1 = __int_as_float(e1.y) * dinv[e1.x];
        float w2 = __int_as_float(e2.y) * dinv[e2.x];
        float w3 = __int_as_float(e3.y) * dinv[e3.x];
        uint2 g0 = *(const uint2*)&H[(size_t)e0.x * DD + h * 8];
        uint2 g1 = *(const uint2*)&H[(size_t)e1.x * DD + h * 8];
        uint2 g2 = *(const uint2*)&H[(size_t)e2.x * DD + h * 8];
        uint2 g3 = *(const uint2*)&H[(size_t)e3.x * DD + h * 8];
        accf8(acc, g0, w0);
        accf8(acc, g1, w1);
        accf8(acc, g2, w2);
        accf8(acc, g3, w3);
    }
    for (; j < end; ++j) {
        int2 e = csr[j];
        float w = __int_as_float(e.y) * dinv[e.x];
        uint2 g = *(const uint2*)&H[(size_t)e.x * DD + h * 8];
        accf8(acc, g, w);
    }

    // final dv scale (factored out of every term)
#pragma unroll
    for (int i = 0; i < 8; ++i) acc[i] *= dv;

    // write A in bf16
    uint4 st;
    st.x = (uint)f2bf(acc[0]) | ((uint)f2bf(acc[1]) << 16);
    st.y = (uint)f2bf(acc[2]) | ((uint)f2bf(acc[3]) << 16);
    st.z = (uint)f2bf(acc[4]) | ((uint)f2bf(acc[5]) << 16);
    st.w = (uint)f2bf(acc[6]) | ((uint)f2bf(acc[7]) << 16);
    *(uint4*)&Ab[cb] = st;

    // fused BN partial stats from fp32 accumulators
    int n = tid >> 4, c0 = h * 8;
#pragma unroll
    for (int i = 0; i < 8; ++i) {
        float a = acc[i];
        sbv[n][c0 + i] = a;
        sbq[n][c0 + i] = a * a;
    }
    __syncthreads();
    float s = 0.f;
    if (tid < 128) {
#pragma unroll
        for (int k = 0; k < 16; ++k) s += sbv[k][tid];
    } else {
        int c = tid - 128;
#pragma unroll
        for (int k = 0; k < 16; ++k) s += sbq[k][c];
    }
    partial[(size_t)blockIdx.x * 256 + tid] = s;
}

// ---------------- reduce partials -> stats (low-contention atomics) -------
__global__ __launch_bounds__(256) void k_bn_red(const float* __restrict__ partial,
                                                float* __restrict__ stats) {
    int r0 = blockIdx.x * 25;
    int r1 = min(r0 + 25, NAGG);
    int t = threadIdx.x;
    float s = 0.f;
    for (int r = r0; r < r1; ++r) s += partial[(size_t)r * 256 + t];
    atomAddF(&stats[t], s);
}

// ---------------- pooling (fused final BN+ReLU), vectorized ---------------
__global__ __launch_bounds__(256) void k_pool(const ushort* __restrict__ Ab,
                                              const int* __restrict__ batch,
                                              const float* __restrict__ stats,
                                              const float* __restrict__ gamma,
                                              const float* __restrict__ beta,
                                              float* __restrict__ out) {
    __shared__ int bsh[512];
    __shared__ float scs[DD], shs[DD];
    const int tid = threadIdx.x;
    const int lane = tid & 15, rg = tid >> 4;
    const int c0 = lane * 8;
    const int v0 = blockIdx.x * 512;
    const int v1 = min(v0 + 512, NN);
    for (int i = tid; i < v1 - v0; i += 256) bsh[i] = batch[v0 + i];
    if (tid < DD) {
        float mu = stats[tid] * (1.0f / NN);
        float var = stats[DD + tid] * (1.0f / NN) - mu * mu;
        float inv = rsqrtf(var + EPSBN);
        float s = gamma[tid] * inv;
        scs[tid] = s;
        shs[tid] = beta[tid] - mu * s;
    }
    __syncthreads();

    float s[8], t[8];
#pragma unroll
    for (int i = 0; i < 8; ++i) {
        s[i] = scs[c0 + i];
        t[i] = shs[c0 + i];
    }
    float acc[8] = {0.f, 0.f, 0.f, 0.f, 0.f, 0.f, 0.f, 0.f};
    int g = -1;
    for (int v = v0 + rg; v < v1; v += 16) {
        int bg = bsh[v - v0];
        if (bg != g) {
            if (g >= 0) {
                float* op = &out[(size_t)g * DD + c0];
#pragma unroll
                for (int i = 0; i < 8; ++i) atomAddF(op + i, acc[i]);
            }
            g = bg;
#pragma unroll
            for (int i = 0; i < 8; ++i) acc[i] = 0.f;
        }
        uint4 a = *(const uint4*)&Ab[(size_t)v * DD + c0];
        float x0 = __uint_as_float(a.x << 16);
        float x1 = __uint_as_float(a.x & 0xffff0000u);
        float x2 = __uint_as_float(a.y << 16);
        float x3 = __uint_as_float(a.y & 0xffff0000u);
        float x4 = __uint_as_float(a.z << 16);
        float x5 = __uint_as_float(a.z & 0xffff0000u);
        float x6 = __uint_as_float(a.w << 16);
        float x7 = __uint_as_float(a.w & 0xffff0000u);
        acc[0] += fmaxf(fmaf(x0, s[0], t[0]), 0.f);
        acc[1] += fmaxf(fmaf(x1, s[1], t[1]), 0.f);
        acc[2] += fmaxf(fmaf(x2, s[2], t[2]), 0.f);
        acc[3] += fmaxf(fmaf(x3, s[3], t[3]), 0.f);
        acc[4] += fmaxf(fmaf(x4, s[4], t[4]), 0.f);
        acc[5] += fmaxf(fmaf(x5, s[5], t[5]), 0.f);
        acc[6] += fmaxf(fmaf(x6, s[6], t[6]), 0.f);
        acc[7] += fmaxf(fmaf(x7, s[7], t[7]), 0.f);
    }
    if (g >= 0) {
        float* op = &out[(size_t)g * DD + c0];
#pragma unroll
        for (int i = 0; i < 8; ++i) atomAddF(op + i, acc[i]);
    }
}

extern "C" void kernel_launch(void* const* d_in, const int* in_sizes, int n_in,
                              void* d_out, int out_size, void* d_ws, size_t ws_size,
                              hipStream_t stream) {
    const float* x     = (const float*)d_in[0];
    const int*   ei    = (const int*)d_in[1];
    const float* ew    = (const float*)d_in[2];
    const int*   batch = (const int*)d_in[3];
    const float* W     = (const float*)d_in[4];
    // d_in[5] = b — cancels exactly in training-mode BatchNorm, unused
    const float* gamma = (const float*)d_in[6];
    const float* beta  = (const float*)d_in[7];
    float* out = (float*)d_out;

    float* wsp   = (float*)d_ws;
    float* dinv  = wsp;                            // N
    float* stats = dinv + NN;                      // 768
    ushort* Wt   = (ushort*)(stats + 768);         // 3 x D x D bf16
    unsigned char* H = (unsigned char*)(Wt + (size_t)NL * DD * DD);  // N*D fp8
    ushort* Ab   = (ushort*)(H + (size_t)NN * DD); // N*D bf16
    int2*  srcw  = (int2*)(Ab + (size_t)NN * DD);  // E packed records
    float* partial = (float*)(srcw + NE);          // NAGG x 256
    int*   row_off = (int*)(partial + (size_t)NAGG * 256);  // N+4
    int*   gbcnt = row_off + NN + 4;               // NBUCK
    int*   boff  = gbcnt + NBUCK;                  // NBUCK+4 (padded)
    int*   gcur  = boff + NBUCK + 4;               // NBUCK
    int2*  csr   = (int2*)(gcur + NBUCK);          // E * 8B
    // total ≈ 71 MiB

    k_zero_fo<<<(NL * DD * DD + NG * DD + 768 + NBUCK + 255) / 256, 256, 0,
                stream>>>(W, Wt, out, stats, gbcnt);

    // bucket-staged CSR build (bsort emits dinv; csr keeps raw ew)
    k_bcnt<<<256, 256, 0, stream>>>(ei, gbcnt);
    k_bscan<<<1, 256, 0, stream>>>(gbcnt, boff, gcur);
    k_bscatter<<<256, 256, 0, stream>>>(ei, ew, gcur, srcw);
    k_bsort<<<NBUCK, 256, 0, stream>>>(srcw, boff, row_off, csr, dinv);

    for (int l = 0; l < NL; ++l) {
        const float* st_prev = stats + (l - 1) * 256;   // unused when l==0
        const float* ga_prev = gamma + (size_t)(l > 0 ? l - 1 : 0) * DD;
        const float* be_prev = beta + (size_t)(l > 0 ? l - 1 : 0) * DD;
        k_gemm5<<<(NN + 63) / 64, 256, 0, stream>>>(
            x, Ab, Wt + (size_t)l * DD * DD, l > 0 ? st_prev : stats,
            ga_prev, be_prev, l > 0 ? 1 : 0, H);
        k_agg3<<<NAGG, 256, 0, stream>>>(csr, row_off, dinv, H, Ab, partial);
        k_bn_red<<<(NAGG + 24) / 25, 256, 0, stream>>>(partial, stats + l * 256);
    }

    k_pool<<<NBUCK, 256, 0, stream>>>(Ab, batch, stats + 2 * 256,
                                      gamma + 2 * DD, beta + 2 * DD, out);
}

// Round 18
// 312.242 us; speedup vs baseline: 27.8446x; 1.0122x over previous
//
#include <hip/hip_runtime.h>

#define NN 100000   // nodes
#define NE 1600000  // edges
#define DD 128      // feature dim
#define NL 3        // layers
#define NG 64       // graphs
#define EPSBN 1e-5f
#define NBUCK 196               // ceil(NN/512) buckets of 512 nodes
#define NAGG (NN / 16)          // 6250 agg blocks (16 nodes each)
#define NSCAT 256               // scatter blocks (NE = 256*6250)

typedef __attribute__((ext_vector_type(8))) short short8v;   // 8 bf16 (4 VGPR)
typedef __attribute__((ext_vector_type(4))) float float4v;   // MFMA C/D
typedef __attribute__((ext_vector_type(2))) float float2v;   // fp8 cvt result

// ---- fp32 atomic add (HW global_atomic_add_f32, no CAS loop) ----
__device__ inline void atomAddF(float* p, float v) {
#if defined(__AMDGCN__)
    unsafeAtomicAdd(p, v);
#else
    atomicAdd(p, v);
#endif
}

// ---- fp32 -> bf16 round-to-nearest-even ----
__device__ inline ushort f2bf(float f) {
    uint u = __float_as_uint(f);
    uint r = ((u >> 16) & 1u) + 0x7fffu;
    return (ushort)((u + r) >> 16);
}

// ---- fp32 -> fp8 e4m3 (OCP, HW convert) ----
__device__ inline uint f2fp8(float f) {
    return (uint)__builtin_amdgcn_cvt_pk_fp8_f32(f, f, 0, false) & 0xffu;
}

// ---- accumulate 8 fp8 lanes (packed in uint2) scaled by wgt into acc[8] ----
__device__ inline void accf8(float (&acc)[8], uint2 g, float wgt) {
    float2v p0 = __builtin_amdgcn_cvt_pk_f32_fp8(g.x, false);
    float2v p1 = __builtin_amdgcn_cvt_pk_f32_fp8(g.x, true);
    float2v p2 = __builtin_amdgcn_cvt_pk_f32_fp8(g.y, false);
    float2v p3 = __builtin_amdgcn_cvt_pk_f32_fp8(g.y, true);
    acc[0] = fmaf(wgt, p0[0], acc[0]);
    acc[1] = fmaf(wgt, p0[1], acc[1]);
    acc[2] = fmaf(wgt, p1[0], acc[2]);
    acc[3] = fmaf(wgt, p1[1], acc[3]);
    acc[4] = fmaf(wgt, p2[0], acc[4]);
    acc[5] = fmaf(wgt, p2[1], acc[5]);
    acc[6] = fmaf(wgt, p3[0], acc[6]);
    acc[7] = fmaf(wgt, p3[1], acc[7]);
}

// ---------------- bcnt + init fused ----------------
// 256 blocks; each block: per-block bucket histogram of its 6250-edge range
// (LDS, plain global stores -> hist[blk][b]); threads also do init work
// (Wt bf16-transpose, out/stats zero) on disjoint arrays.
__global__ __launch_bounds__(256) void k_bcnt2(const int* __restrict__ ei,
                                               const float* __restrict__ W,
                                               ushort* __restrict__ Wt,
                                               float* __restrict__ out,
                                               float* __restrict__ stats,
                                               int* __restrict__ hist) {
    __shared__ int lh[NBUCK];
    const int tid = threadIdx.x;
    if (tid < NBUCK) lh[tid] = 0;
    __syncthreads();

    // init work interleaved (index space 58112 < 65536)
    int gi = blockIdx.x * 256 + tid;
    if (gi < NL * DD * DD) {
        int l = gi >> 14, r = gi & 16383;
        int k = r >> 7, n = r & 127;
        Wt[(size_t)l * DD * DD + n * DD + k] = f2bf(W[gi]);
    } else {
        int j = gi - NL * DD * DD;
        if (j < NG * DD) out[j] = 0.f;
        else if (j - NG * DD < 768) stats[j - NG * DD] = 0.f;
    }

    const int e0 = blockIdx.x * 6250, e1 = e0 + 6250;
    for (int e = e0 + tid; e < e1; e += 256)
        atomicAdd(&lh[ei[NE + e] >> 9], 1);
    __syncthreads();
    if (tid < NBUCK) hist[blockIdx.x * NBUCK + tid] = lh[tid];
}

// ---------------- scan: boff (exclusive) + per-block prefix matrix --------
__global__ __launch_bounds__(256) void k_bscan2(const int* __restrict__ hist,
                                                int* __restrict__ prefix,
                                                int* __restrict__ boff) {
    __shared__ int s[256];
    int t = threadIdx.x;
    int cum = 0;
    if (t < NBUCK) {
        for (int blk = 0; blk < NSCAT; ++blk) {
            int v = hist[blk * NBUCK + t];
            prefix[blk * NBUCK + t] = cum;
            cum += v;
        }
    }
    s[t] = (t < NBUCK) ? cum : 0;
    __syncthreads();
    int v = s[t];
    for (int off = 1; off < 256; off <<= 1) {
        int add = (t >= off) ? s[t - off] : 0;
        __syncthreads();
        s[t] += add;
        __syncthreads();
    }
    if (t < NBUCK) boff[t] = s[t] - v;  // exclusive
    if (t == NBUCK - 1) boff[NBUCK] = s[t];  // = NE
}

// ---------------- scatter (single pass, no global atomics) ----------------
__global__ __launch_bounds__(256) void k_bscatter2(const int* __restrict__ ei,
                                                   const float* __restrict__ ew,
                                                   const int* __restrict__ prefix,
                                                   const int* __restrict__ boff,
                                                   int2* __restrict__ srcw) {
    __shared__ int base[NBUCK], cur[NBUCK];
    const int tid = threadIdx.x;
    if (tid < NBUCK) {
        base[tid] = boff[tid] + prefix[blockIdx.x * NBUCK + tid];
        cur[tid] = 0;
    }
    __syncthreads();
    const int e0 = blockIdx.x * 6250, e1 = e0 + 6250;
    for (int e = e0 + tid; e < e1; e += 256) {
        int d = ei[NE + e];
        int b = d >> 9;
        int p = base[b] + atomicAdd(&cur[b], 1);
        int2 sw;
        sw.x = ei[e] | ((d & 511) << 17);
        sw.y = __float_as_int(ew[e]);
        srcw[p] = sw;
    }
}

// ---------------- per-bucket counting sort -> CSR + row_off + dinv --------
__global__ __launch_bounds__(256) void k_bsort(const int2* __restrict__ srcw,
                                               const int* __restrict__ boff,
                                               int* __restrict__ row_off,
                                               int2* __restrict__ csr,
                                               float* __restrict__ dinv) {
    __shared__ int h0[512], h1[512], exc[512], cur[512];
    __shared__ float degacc[512];
    const int tid = threadIdx.x;
    const int b = blockIdx.x;
    const int p0 = boff[b], p1 = boff[b + 1];
    const int nbn = min(512, NN - (b << 9));

    for (int i = tid; i < 512; i += 256) {
        h0[i] = 0;
        degacc[i] = 0.f;
    }
    __syncthreads();
    for (int p = p0 + tid; p < p1; p += 256)
        atomicAdd(&h0[(srcw[p].x >> 17) & 511], 1);
    __syncthreads();

    int* sA = h0;
    int* sB = h1;
    for (int off = 1; off < 512; off <<= 1) {
        for (int i = tid; i < 512; i += 256) {
            int v = sA[i];
            if (i >= off) v += sA[i - off];
            sB[i] = v;
        }
        __syncthreads();
        int* tp = sA; sA = sB; sB = tp;
    }
    for (int i = tid; i < 512; i += 256) {
        exc[i] = (i == 0) ? 0 : sA[i - 1];
        cur[i] = 0;
    }
    __syncthreads();

    for (int n = tid; n < nbn; n += 256)
        row_off[(b << 9) + n] = p0 + exc[n];
    if (b == NBUCK - 1 && tid == 0) row_off[NN] = NE;

    for (int p = p0 + tid; p < p1; p += 256) {
        int2 sw = srcw[p];
        int dl = (sw.x >> 17) & 511;
        int q = p0 + exc[dl] + atomicAdd(&cur[dl], 1);
        int2 outv;
        outv.x = sw.x & 0x1FFFF;   // clean src
        outv.y = sw.y;             // raw ew (normalized on the fly in agg)
        csr[q] = outv;
        atomicAdd(&degacc[dl], __int_as_float(sw.y));
    }
    __syncthreads();
    for (int n = tid; n < nbn; n += 256)
        dinv[(b << 9) + n] = rsqrtf(1.0f + degacc[n]);  // 1 = self-loop
}

// ---------------- MFMA GEMM: H = act(X) @ W, H stored fp8 e4m3 -------------
// 64 rows x 128 cols per block, 4 waves. A-fragments loaded directly from
// global; only W in LDS (33KB) -> 4 blocks/CU, single __syncthreads.
__global__ __launch_bounds__(256, 4) void k_gemm5(const float* __restrict__ X,
                                                  const ushort* __restrict__ Xb,
                                                  const ushort* __restrict__ Wt,
                                                  const float* __restrict__ stats,
                                                  const float* __restrict__ gamma,
                                                  const float* __restrict__ beta,
                                                  int applyBN,
                                                  unsigned char* __restrict__ H) {
    __shared__ ushort ws[128 * 128];   // 32KB [n][k] bf16, swizzled
    __shared__ float scs[DD], shs[DD];
    const int tid = threadIdx.x;

    for (int c = tid; c < 2048; c += 256) {
        int n = c >> 4, k8 = (c & 15) * 8;
        uint4 w = *(const uint4*)&Wt[n * DD + k8];
        int idx = n * 128 + (((k8 * 2) ^ ((n & 7) << 4)) >> 1);
        *(uint4*)&ws[idx] = w;
    }
    if (applyBN && tid < DD) {
        float mu = stats[tid] * (1.0f / NN);
        float var = stats[DD + tid] * (1.0f / NN) - mu * mu;
        float inv = rsqrtf(var + EPSBN);
        float s = gamma[tid] * inv;
        scs[tid] = s;
        shs[tid] = beta[tid] - mu * s;
    }
    __syncthreads();

    const int wid = tid >> 6, lane = tid & 63;
    const int lrow = lane & 15, lk = lane >> 4;
    const int gr_a = blockIdx.x * 64 + wid * 16 + lrow;  // A row for this lane

    float4v acc[8];
#pragma unroll
    for (int i = 0; i < 8; ++i) acc[i] = (float4v){0.f, 0.f, 0.f, 0.f};

#pragma unroll
    for (int ks = 0; ks < 4; ++ks) {
        const int k8 = ks * 32 + lk * 8;   // this lane's 8 k-elements
        float v[8];
        if (applyBN) {
            uint4 g = (gr_a < NN) ? *(const uint4*)&Xb[(size_t)gr_a * DD + k8]
                                  : make_uint4(0u, 0u, 0u, 0u);
            v[0] = __uint_as_float(g.x << 16);
            v[1] = __uint_as_float(g.x & 0xffff0000u);
            v[2] = __uint_as_float(g.y << 16);
            v[3] = __uint_as_float(g.y & 0xffff0000u);
            v[4] = __uint_as_float(g.z << 16);
            v[5] = __uint_as_float(g.z & 0xffff0000u);
            v[6] = __uint_as_float(g.w << 16);
            v[7] = __uint_as_float(g.w & 0xffff0000u);
#pragma unroll
            for (int i = 0; i < 8; ++i)
                v[i] = fmaxf(fmaf(v[i], scs[k8 + i], shs[k8 + i]), 0.f);
        } else {
            if (gr_a < NN) {
                float4 a0 = *(const float4*)&X[(size_t)gr_a * DD + k8];
                float4 a1 = *(const float4*)&X[(size_t)gr_a * DD + k8 + 4];
                v[0] = a0.x; v[1] = a0.y; v[2] = a0.z; v[3] = a0.w;
                v[4] = a1.x; v[5] = a1.y; v[6] = a1.z; v[7] = a1.w;
            } else {
#pragma unroll
                for (int i = 0; i < 8; ++i) v[i] = 0.f;
            }
        }
        uint4 ap;
        ap.x = (uint)f2bf(v[0]) | ((uint)f2bf(v[1]) << 16);
        ap.y = (uint)f2bf(v[2]) | ((uint)f2bf(v[3]) << 16);
        ap.z = (uint)f2bf(v[4]) | ((uint)f2bf(v[5]) << 16);
        ap.w = (uint)f2bf(v[6]) | ((uint)f2bf(v[7]) << 16);
        short8v a = *(short8v*)&ap;

        const int kbyte = ks * 64 + lk * 16;
#pragma unroll
        for (int ng = 0; ng < 8; ++ng) {
            int n = ng * 16 + lrow;
            short8v b = *(const short8v*)&ws[n * 128 + ((kbyte ^ ((n & 7) << 4)) >> 1)];
            acc[ng] = __builtin_amdgcn_mfma_f32_16x16x32_bf16(a, b, acc[ng], 0, 0, 0);
        }
    }

    // C/D layout: col = lane&15, row = (lane>>4)*4 + reg  [m89]
    const int rbase = blockIdx.x * 64 + wid * 16 + lk * 4;
#pragma unroll
    for (int ng = 0; ng < 8; ++ng) {
        int col = ng * 16 + lrow;
#pragma unroll
        for (int j = 0; j < 4; ++j) {
            int gr = rbase + j;
            if (gr < NN)
                H[(size_t)gr * DD + col] = (unsigned char)f2fp8(acc[ng][j]);
        }
    }
}

// ---------------- aggregation + fused BN stats + on-the-fly norm ----------
__global__ __launch_bounds__(256) void k_agg3(const int2* __restrict__ csr,
                                              const int* __restrict__ row_off,
                                              const float* __restrict__ dinv,
                                              const unsigned char* __restrict__ H,
                                              ushort* __restrict__ Ab,
                                              float* __restrict__ partial) {
    __shared__ float sbv[16][128];
    __shared__ float sbq[16][128];
    const int tid = threadIdx.x;
    int node = blockIdx.x * 16 + (tid >> 4);
    int h = tid & 15;
    int beg = row_off[node], end = row_off[node + 1];
    float dv = dinv[node];
    size_t cb = (size_t)node * DD + h * 8;   // byte index
    float acc[8] = {0.f, 0.f, 0.f, 0.f, 0.f, 0.f, 0.f, 0.f};
    {
        uint2 v = *(const uint2*)&H[cb];
        accf8(acc, v, dv);  // self-loop seed: dv*H[node]; final *dv gives dv^2
    }

    int j = beg;
    for (; j + 8 <= end; j += 8) {
        int2 e0 = csr[j], e1 = csr[j + 1], e2 = csr[j + 2], e3 = csr[j + 3];
        int2 e4 = csr[j + 4], e5 = csr[j + 5], e6 = csr[j + 6], e7 = csr[j + 7];
        float w0 = __int_as_float(e0.y) * dinv[e0.x];
        float w1 = __int_as_float(e1.y) * dinv[e1.x];
        float w2 = __int_as_float(e2.y) * dinv[e2.x];
        float w3 = __int_as_float(e3.y) * dinv[e3.x];
        float w4 = __int_as_float(e4.y) * dinv[e4.x];
        float w5 = __int_as_float(e5.y) * dinv[e5.x];
        float w6 = __int_as_float(e6.y) * dinv[e6.x];
        float w7 = __int_as_float(e7.y) * dinv[e7.x];
        uint2 g0 = *(const uint2*)&H[(size_t)e0.x * DD + h * 8];
        uint2 g1 = *(const uint2*)&H[(size_t)e1.x * DD + h * 8];
        uint2 g2 = *(const uint2*)&H[(size_t)e2.x * DD + h * 8];
        uint2 g3 = *(const uint2*)&H[(size_t)e3.x * DD + h * 8];
        uint2 g4 = *(const uint2*)&H[(size_t)e4.x * DD + h * 8];
        uint2 g5 = *(const uint2*)&H[(size_t)e5.x * DD + h * 8];
        uint2 g6 = *(const uint2*)&H[(size_t)e6.x * DD + h * 8];
        uint2 g7 = *(const uint2*)&H[(size_t)e7.x * DD + h * 8];
        accf8(acc, g0, w0);
        accf8(acc, g1, w1);
        accf8(acc, g2, w2);
        accf8(acc, g3, w3);
        accf8(acc, g4, w4);
        accf8(acc, g5, w5);
        accf8(acc, g6, w6);
        accf8(acc, g7, w7);
    }
    for (; j + 4 <= end; j += 4) {
        int2 e0 = csr[j], e1 = csr[j + 1], e2 = csr[j + 2], e3 = csr[j + 3];
        float w0 = __int_as_float(e0.y) * dinv[e0.x];
        float w1 = __int_as_float(e1.y) * dinv[e1.x];
        float w2 = __int_as_float(e2.y) * dinv[e2.x];
        float w3 = __int_as_float(e3.y) * dinv[e3.x];
        uint2 g0 = *(const uint2*)&H[(size_t)e0.x * DD + h * 8];
        uint2 g1 = *(const uint2*)&H[(size_t)e1.x * DD + h * 8];
        uint2 g2 = *(const uint2*)&H[(size_t)e2.x * DD + h * 8];
        uint2 g3 = *(const uint2*)&H[(size_t)e3.x * DD + h * 8];
        accf8(acc, g0, w0);
        accf8(acc, g1, w1);
        accf8(acc, g2, w2);
        accf8(acc, g3, w3);
    }
    for (; j < end; ++j) {
        int2 e = csr[j];
        float w = __int_as_float(e.y) * dinv[e.x];
        uint2 g = *(const uint2*)&H[(size_t)e.x * DD + h * 8];
        accf8(acc, g, w);
    }

#pragma unroll
    for (int i = 0; i < 8; ++i) acc[i] *= dv;

    uint4 st;
    st.x = (uint)f2bf(acc[0]) | ((uint)f2bf(acc[1]) << 16);
    st.y = (uint)f2bf(acc[2]) | ((uint)f2bf(acc[3]) << 16);
    st.z = (uint)f2bf(acc[4]) | ((uint)f2bf(acc[5]) << 16);
    st.w = (uint)f2bf(acc[6]) | ((uint)f2bf(acc[7]) << 16);
    *(uint4*)&Ab[cb] = st;

    int n = tid >> 4, c0 = h * 8;
#pragma unroll
    for (int i = 0; i < 8; ++i) {
        float a = acc[i];
        sbv[n][c0 + i] = a;
        sbq[n][c0 + i] = a * a;
    }
    __syncthreads();
    float s = 0.f;
    if (tid < 128) {
#pragma unroll
        for (int k = 0; k < 16; ++k) s += sbv[k][tid];
    } else {
        int c = tid - 128;
#pragma unroll
        for (int k = 0; k < 16; ++k) s += sbq[k][c];
    }
    partial[(size_t)blockIdx.x * 256 + tid] = s;
}

// ---------------- reduce partials -> stats (low-contention atomics) -------
__global__ __launch_bounds__(256) void k_bn_red(const float* __restrict__ partial,
                                                float* __restrict__ stats) {
    int r0 = blockIdx.x * 25;
    int r1 = min(r0 + 25, NAGG);
    int t = threadIdx.x;
    float s = 0.f;
    for (int r = r0; r < r1; ++r) s += partial[(size_t)r * 256 + t];
    atomAddF(&stats[t], s);
}

// ---------------- pooling (fused final BN+ReLU), vectorized ---------------
__global__ __launch_bounds__(256) void k_pool(const ushort* __restrict__ Ab,
                                              const int* __restrict__ batch,
                                              const float* __restrict__ stats,
                                              const float* __restrict__ gamma,
                                              const float* __restrict__ beta,
                                              float* __restrict__ out) {
    __shared__ int bsh[512];
    __shared__ float scs[DD], shs[DD];
    const int tid = threadIdx.x;
    const int lane = tid & 15, rg = tid >> 4;
    const int c0 = lane * 8;
    const int v0 = blockIdx.x * 512;
    const int v1 = min(v0 + 512, NN);
    for (int i = tid; i < v1 - v0; i += 256) bsh[i] = batch[v0 + i];
    if (tid < DD) {
        float mu = stats[tid] * (1.0f / NN);
        float var = stats[DD + tid] * (1.0f / NN) - mu * mu;
        float inv = rsqrtf(var + EPSBN);
        float s = gamma[tid] * inv;
        scs[tid] = s;
        shs[tid] = beta[tid] - mu * s;
    }
    __syncthreads();

    float s[8], t[8];
#pragma unroll
    for (int i = 0; i < 8; ++i) {
        s[i] = scs[c0 + i];
        t[i] = shs[c0 + i];
    }
    float acc[8] = {0.f, 0.f, 0.f, 0.f, 0.f, 0.f, 0.f, 0.f};
    int g = -1;
    for (int v = v0 + rg; v < v1; v += 16) {
        int bg = bsh[v - v0];
        if (bg != g) {
            if (g >= 0) {
                float* op = &out[(size_t)g * DD + c0];
#pragma unroll
                for (int i = 0; i < 8; ++i) atomAddF(op + i, acc[i]);
            }
            g = bg;
#pragma unroll
            for (int i = 0; i < 8; ++i) acc[i] = 0.f;
        }
        uint4 a = *(const uint4*)&Ab[(size_t)v * DD + c0];
        float x0 = __uint_as_float(a.x << 16);
        float x1 = __uint_as_float(a.x & 0xffff0000u);
        float x2 = __uint_as_float(a.y << 16);
        float x3 = __uint_as_float(a.y & 0xffff0000u);
        float x4 = __uint_as_float(a.z << 16);
        float x5 = __uint_as_float(a.z & 0xffff0000u);
        float x6 = __uint_as_float(a.w << 16);
        float x7 = __uint_as_float(a.w & 0xffff0000u);
        acc[0] += fmaxf(fmaf(x0, s[0], t[0]), 0.f);
        acc[1] += fmaxf(fmaf(x1, s[1], t[1]), 0.f);
        acc[2] += fmaxf(fmaf(x2, s[2], t[2]), 0.f);
        acc[3] += fmaxf(fmaf(x3, s[3], t[3]), 0.f);
        acc[4] += fmaxf(fmaf(x4, s[4], t[4]), 0.f);
        acc[5] += fmaxf(fmaf(x5, s[5], t[5]), 0.f);
        acc[6] += fmaxf(fmaf(x6, s[6], t[6]), 0.f);
        acc[7] += fmaxf(fmaf(x7, s[7], t[7]), 0.f);
    }
    if (g >= 0) {
        float* op = &out[(size_t)g * DD + c0];
#pragma unroll
        for (int i = 0; i < 8; ++i) atomAddF(op + i, acc[i]);
    }
}

extern "C" void kernel_launch(void* const* d_in, const int* in_sizes, int n_in,
                              void* d_out, int out_size, void* d_ws, size_t ws_size,
                              hipStream_t stream) {
    const float* x     = (const float*)d_in[0];
    const int*   ei    = (const int*)d_in[1];
    const float* ew    = (const float*)d_in[2];
    const int*   batch = (const int*)d_in[3];
    const float* W     = (const float*)d_in[4];
    // d_in[5] = b — cancels exactly in training-mode BatchNorm, unused
    const float* gamma = (const float*)d_in[6];
    const float* beta  = (const float*)d_in[7];
    float* out = (float*)d_out;

    float* wsp   = (float*)d_ws;
    float* dinv  = wsp;                            // N
    float* stats = dinv + NN;                      // 768
    ushort* Wt   = (ushort*)(stats + 768);         // 3 x D x D bf16
    unsigned char* H = (unsigned char*)(Wt + (size_t)NL * DD * DD);  // N*D fp8
    ushort* Ab   = (ushort*)(H + (size_t)NN * DD); // N*D bf16
    int2*  srcw  = (int2*)(Ab + (size_t)NN * DD);  // E packed records
    float* partial = (float*)(srcw + NE);          // NAGG x 256
    int*   row_off = (int*)(partial + (size_t)NAGG * 256);  // N+4
    int*   hist  = row_off + NN + 4;               // NSCAT x NBUCK
    int*   prefix = hist + NSCAT * NBUCK;          // NSCAT x NBUCK
    int*   boff  = prefix + NSCAT * NBUCK;         // NBUCK+4 (padded)
    int2*  csr   = (int2*)(boff + NBUCK + 4);      // E * 8B
    // total ≈ 71 MiB

    // build chain: per-block histograms (+init) -> scan -> scatter -> sort
    k_bcnt2<<<NSCAT, 256, 0, stream>>>(ei, W, Wt, out, stats, hist);
    k_bscan2<<<1, 256, 0, stream>>>(hist, prefix, boff);
    k_bscatter2<<<NSCAT, 256, 0, stream>>>(ei, ew, prefix, boff, srcw);
    k_bsort<<<NBUCK, 256, 0, stream>>>(srcw, boff, row_off, csr, dinv);

    for (int l = 0; l < NL; ++l) {
        const float* st_prev = stats + (l - 1) * 256;   // unused when l==0
        const float* ga_prev = gamma + (size_t)(l > 0 ? l - 1 : 0) * DD;
        const float* be_prev = beta + (size_t)(l > 0 ? l - 1 : 0) * DD;
        k_gemm5<<<(NN + 63) / 64, 256, 0, stream>>>(
            x, Ab, Wt + (size_t)l * DD * DD, l > 0 ? st_prev : stats,
            ga_prev, be_prev, l > 0 ? 1 : 0, H);
        k_agg3<<<NAGG, 256, 0, stream>>>(csr, row_off, dinv, H, Ab, partial);
        k_bn_red<<<(NAGG + 24) / 25, 256, 0, stream>>>(partial, stats + l * 256);
    }

    k_pool<<<NBUCK, 256, 0, stream>>>(Ab, batch, stats + 2 * 256,
                                      gamma + 2 * DD, beta + 2 * DD, out);
}